// Round 1
// baseline (3635.567 us; speedup 1.0000x reference)
//
#include <hip/hip_runtime.h>
#include <math.h>

#define B_    32
#define DIN   64
#define LSEQ  4096
#define H_    256
#define N2_   32
#define NL_   4
#define DOUT  2
#define LN_EPSF 1e-5f

// ---------------------------------------------------------------------------
// Encoder: h[b,d,l] = sum_c x[b,c,l]*ew[c,d] + eb[d]
// grid: B * (LSEQ/32), block 256. K-chunked LDS staging (<=64KB).
// ---------------------------------------------------------------------------
__global__ __launch_bounds__(256) void k_encoder(
    const float* __restrict__ x, const float* __restrict__ ew,
    const float* __restrict__ eb, float* __restrict__ h)
{
  __shared__ __align__(16) float Wl[32][256];  // 32KB: W chunk [k][d]
  __shared__ __align__(16) float Xl[32][32];   // 4KB:  X chunk [k][l]
  int tid = threadIdx.x;
  int blk = blockIdx.x;
  int b  = blk >> 7;             // 128 l-tiles per batch
  int l0 = (blk & 127) << 5;
  int ty = tid >> 3;             // 0..31 -> d0 = ty*8
  int tx = tid & 7;              // 0..7  -> c0 = tx*4
  float acc[8][4];
#pragma unroll
  for (int i = 0; i < 8; ++i)
#pragma unroll
    for (int j = 0; j < 4; ++j) acc[i][j] = 0.f;

  for (int kc = 0; kc < DIN; kc += 32) {
    const float4* ew4 = (const float4*)(ew + kc * H_);
#pragma unroll
    for (int it = 0; it < 8; ++it) {
      int idx = tid + (it << 8);           // 0..2047 float4s
      ((float4*)&Wl[0][0])[idx] = ew4[idx];
    }
    {
      int c = tid >> 3, p = (tid & 7) << 2;
      *(float4*)&Xl[c][p] =
          *(const float4*)(x + ((size_t)(b * DIN + kc + c)) * LSEQ + l0 + p);
    }
    __syncthreads();
#pragma unroll
    for (int k = 0; k < 32; ++k) {
      float4 w0 = *(float4*)&Wl[k][ty * 8];
      float4 w1 = *(float4*)&Wl[k][ty * 8 + 4];
      float4 xv = *(float4*)&Xl[k][tx * 4];
      float wvv[8] = {w0.x, w0.y, w0.z, w0.w, w1.x, w1.y, w1.z, w1.w};
      float xs[4]  = {xv.x, xv.y, xv.z, xv.w};
#pragma unroll
      for (int i = 0; i < 8; ++i)
#pragma unroll
        for (int j = 0; j < 4; ++j) acc[i][j] = fmaf(wvv[i], xs[j], acc[i][j]);
    }
    __syncthreads();
  }
#pragma unroll
  for (int i = 0; i < 8; ++i) {
    int d = ty * 8 + i;
    float bia = eb[d];
    float4 o = make_float4(acc[i][0] + bia, acc[i][1] + bia,
                           acc[i][2] + bia, acc[i][3] + bia);
    *(float4*)(h + ((size_t)(b * H_ + d)) * LSEQ + l0 + tx * 4) = o;
  }
}

// ---------------------------------------------------------------------------
// S4D scan: per wave one (b,h) row. 16 chunk-groups x 4 lanes x 8 modes.
// Pass1: chunk-local end-state; Hillis-Steele chunk scan (exact jump mults);
// Pass2: recurrence with correct incoming state, y = Re(ct.s)+D*u, GELU.
// grid: B*H/4, block 256 (4 waves).
// ---------------------------------------------------------------------------
__global__ __launch_bounds__(256) void k_scan(
    const float* __restrict__ hin, float* __restrict__ G,
    const float* __restrict__ log_dt, const float* __restrict__ Cri,
    const float* __restrict__ lAr, const float* __restrict__ Aim,
    const float* __restrict__ Dsk, int layer)
{
  int tid = threadIdx.x;
  int wv   = tid >> 6;
  int lane = tid & 63;
  int row  = blockIdx.x * 4 + wv;     // b*H + h
  int hh   = row & (H_ - 1);
  int g = lane >> 2;                  // chunk 0..15
  int j = lane & 3;                   // mode group 0..3
  const float* U = hin + (size_t)row * LSEQ;
  float* Gr = G + (size_t)row * LSEQ;

  float dt  = expf(log_dt[layer * H_ + hh]);
  float dsk = Dsk[layer * H_ + hh];
  int pbase = (layer * H_ + hh) * N2_ + j * 8;

  float ar[8], ai[8], ctr[8], cti[8], dAr[8], dAi[8];
#pragma unroll
  for (int k = 0; k < 8; ++k) {
    int n = pbase + k;
    float Are  = -expf(lAr[n]);
    float Aimv = Aim[n];
    float dr = Are * dt, di = Aimv * dt;
    dAr[k] = dr; dAi[k] = di;
    float er = expf(dr), sn, cs;
    sincosf(di, &sn, &cs);
    ar[k] = er * cs; ai[k] = er * sn;
    // q = (a-1)/A ; ct = 2*Cc*q
    float nr = ar[k] - 1.f, ni = ai[k];
    float inv = 1.f / (Are * Are + Aimv * Aimv);
    float qr = (nr * Are + ni * Aimv) * inv;
    float qi = (ni * Are - nr * Aimv) * inv;
    float Cr = Cri[2 * n], Ci = Cri[2 * n + 1];
    ctr[k] = 2.f * (Cr * qr - Ci * qi);
    cti[k] = 2.f * (Cr * qi + Ci * qr);
  }

  int cb = g << 8;                    // chunk base
  float sr[8], si[8];
#pragma unroll
  for (int k = 0; k < 8; ++k) { sr[k] = 0.f; si[k] = 0.f; }

  // ---- pass 1: local end-state with zero init ----
  for (int t4 = 0; t4 < 64; ++t4) {
    float4 u4 = *(const float4*)(U + cb + t4 * 4);
    float us[4] = {u4.x, u4.y, u4.z, u4.w};
#pragma unroll
    for (int tt = 0; tt < 4; ++tt) {
      float u = us[tt];
#pragma unroll
      for (int k = 0; k < 8; ++k) {
        float nsr = fmaf(ar[k], sr[k], fmaf(-ai[k], si[k], u));
        si[k] = fmaf(ar[k], si[k], ai[k] * sr[k]);
        sr[k] = nsr;
      }
    }
  }

  // ---- chunk scan (Hillis-Steele over 16 groups, lanes 4 apart) ----
  for (int dd = 0; dd < 4; ++dd) {
    int d = 1 << dd;
    float fac = (float)(256 * d);
#pragma unroll
    for (int k = 0; k < 8; ++k) {
      float er = expf(dAr[k] * fac), sn, cs;
      sincosf(dAi[k] * fac, &sn, &cs);
      float mr = er * cs, mi = er * sn;
      float pr = __shfl_up(sr[k], (unsigned)(d * 4));
      float pi = __shfl_up(si[k], (unsigned)(d * 4));
      if (g >= d) {
        sr[k] = fmaf(mr, pr, fmaf(-mi, pi, sr[k]));
        si[k] = fmaf(mr, pi, fmaf(mi, pr, si[k]));
      }
    }
  }
  // shift: incoming state for chunk g is S_{g-1} (0 for g=0)
#pragma unroll
  for (int k = 0; k < 8; ++k) {
    float pr = __shfl_up(sr[k], 4u);
    float pi = __shfl_up(si[k], 4u);
    sr[k] = (g == 0) ? 0.f : pr;
    si[k] = (g == 0) ? 0.f : pi;
  }

  // ---- pass 2: full recurrence + output ----
  for (int t16 = 0; t16 < 16; ++t16) {
    float yb[4] = {0.f, 0.f, 0.f, 0.f};
#pragma unroll
    for (int q4 = 0; q4 < 4; ++q4) {
      float4 u4 = *(const float4*)(U + cb + t16 * 16 + q4 * 4);
      float us[4] = {u4.x, u4.y, u4.z, u4.w};
#pragma unroll
      for (int tt = 0; tt < 4; ++tt) {
        float u = us[tt];
        float yp = 0.f;
#pragma unroll
        for (int k = 0; k < 8; ++k) {
          float nsr = fmaf(ar[k], sr[k], fmaf(-ai[k], si[k], u));
          si[k] = fmaf(ar[k], si[k], ai[k] * sr[k]);
          sr[k] = nsr;
          yp = fmaf(ctr[k], sr[k], yp);
          yp = fmaf(-cti[k], si[k], yp);
        }
        yp += __shfl_xor(yp, 1);
        yp += __shfl_xor(yp, 2);
        float yv = fmaf(dsk, u, yp);
        float ge = 0.5f * yv * (1.f + erff(yv * 0.70710678118f));
        int step = q4 * 4 + tt;
        if (j == (step >> 2)) yb[step & 3] = ge;
      }
    }
    *(float4*)(Gr + cb + t16 * 16 + j * 4) =
        make_float4(yb[0], yb[1], yb[2], yb[3]);
  }
}

// ---------------------------------------------------------------------------
// GLU: z = W(512x256) @ G_col + b ; out = z_a * sigmoid(z_g) + residual h
// In-place h update. grid (B*L/64, 4 Mt), block 256. Each Mt covers 64 output
// channels (both a-row and paired g-row staged so GLU pairs stay in-thread).
// ---------------------------------------------------------------------------
__global__ __launch_bounds__(256) void k_glu(
    const float* __restrict__ G, float* __restrict__ h,
    const float* __restrict__ gw, const float* __restrict__ gb, int layer)
{
  __shared__ __align__(16) float Wl[32][132];  // [k][r], r<64: a-rows, r>=64: g-rows (+pad)
  __shared__ __align__(16) float Gl[32][64];   // [k][col]
  int tid = threadIdx.x;
  int ct = blockIdx.x;
  int Mt = blockIdx.y;
  int b  = ct >> 6;                 // 64 col-tiles per batch (L/64)
  int l0 = (ct & 63) << 6;
  const float* gwL = gw + (size_t)layer * 2 * H_ * H_;
  int ty = tid >> 4, tx = tid & 15;
  float accA[4][4], accG[4][4];
#pragma unroll
  for (int i = 0; i < 4; ++i)
#pragma unroll
    for (int jj = 0; jj < 4; ++jj) { accA[i][jj] = 0.f; accG[i][jj] = 0.f; }

  for (int kc = 0; kc < H_; kc += 32) {
#pragma unroll
    for (int it = 0; it < 4; ++it) {
      int idx = tid + (it << 8);           // 0..1023
      int r  = idx >> 3;                   // 0..127
      int k4 = (idx & 7) << 2;             // 0,4,..,28
      int grow = Mt * 64 + ((r < 64) ? r : (r + 192));  // g-rows at +256
      float4 w4 = *(const float4*)(gwL + (size_t)grow * H_ + kc + k4);
      Wl[k4 + 0][r] = w4.x; Wl[k4 + 1][r] = w4.y;
      Wl[k4 + 2][r] = w4.z; Wl[k4 + 3][r] = w4.w;
    }
#pragma unroll
    for (int it = 0; it < 2; ++it) {
      int idx = tid + (it << 8);           // 0..511
      int k  = idx >> 4;
      int c4 = (idx & 15) << 2;
      *(float4*)&Gl[k][c4] =
          *(const float4*)(G + ((size_t)(b * H_ + kc + k)) * LSEQ + l0 + c4);
    }
    __syncthreads();
#pragma unroll
    for (int k = 0; k < 32; ++k) {
      float4 wa = *(float4*)&Wl[k][ty * 4];
      float4 wg = *(float4*)&Wl[k][64 + ty * 4];
      float4 gc = *(float4*)&Gl[k][tx * 4];
      float wav[4] = {wa.x, wa.y, wa.z, wa.w};
      float wgv[4] = {wg.x, wg.y, wg.z, wg.w};
      float gcv[4] = {gc.x, gc.y, gc.z, gc.w};
#pragma unroll
      for (int i = 0; i < 4; ++i)
#pragma unroll
        for (int jj = 0; jj < 4; ++jj) {
          accA[i][jj] = fmaf(wav[i], gcv[jj], accA[i][jj]);
          accG[i][jj] = fmaf(wgv[i], gcv[jj], accG[i][jj]);
        }
    }
    __syncthreads();
  }
  const float* gbL = gb + layer * 2 * H_;
#pragma unroll
  for (int i = 0; i < 4; ++i) {
    int oc = Mt * 64 + ty * 4 + i;
    float ba = gbL[oc], bg = gbL[oc + H_];
    size_t off = ((size_t)(b * H_ + oc)) * LSEQ + l0 + tx * 4;
    float4 hres = *(float4*)(h + off);
    float hv[4] = {hres.x, hres.y, hres.z, hres.w};
    float ov[4];
#pragma unroll
    for (int jj = 0; jj < 4; ++jj) {
      float av = accA[i][jj] + ba;
      float gv = accG[i][jj] + bg;
      float sg = 1.f / (1.f + expf(-gv));
      ov[jj] = fmaf(av, sg, hv[jj]);
    }
    *(float4*)(h + off) = make_float4(ov[0], ov[1], ov[2], ov[3]);
  }
}

// ---------------------------------------------------------------------------
// LayerNorm over channel dim (256) per (b,l) column, in place.
// grid B*(L/64), block 256 (4 parts x 64 cols).
// ---------------------------------------------------------------------------
__global__ __launch_bounds__(256) void k_ln(
    float* __restrict__ h, const float* __restrict__ lng,
    const float* __restrict__ lnb, int layer)
{
  __shared__ float S[4][64], SS[4][64];
  int tid = threadIdx.x;
  int blk = blockIdx.x;
  int b  = blk >> 6;
  int l0 = (blk & 63) << 6;
  int tx = tid & 63, part = tid >> 6;
  size_t base = ((size_t)b * H_) * LSEQ + l0 + tx;
  float s = 0.f, ss = 0.f;
  for (int c = 0; c < 64; ++c) {
    float v = h[base + (size_t)(part * 64 + c) * LSEQ];
    s += v; ss = fmaf(v, v, ss);
  }
  S[part][tx] = s; SS[part][tx] = ss;
  __syncthreads();
  float st  = S[0][tx] + S[1][tx] + S[2][tx] + S[3][tx];
  float sst = SS[0][tx] + SS[1][tx] + SS[2][tx] + SS[3][tx];
  float mu  = st * (1.f / H_);
  float var = sst * (1.f / H_) - mu * mu;
  float rstd = rsqrtf(var + LN_EPSF);
  for (int c = 0; c < 64; ++c) {
    int hh = part * 64 + c;
    size_t off = base + (size_t)hh * LSEQ;
    float v = h[off];
    h[off] = (v - mu) * rstd * lng[layer * H_ + hh] + lnb[layer * H_ + hh];
  }
}

// ---------------------------------------------------------------------------
// Mean-pool over L, decode (256->2), softmax. grid B, block 256.
// ---------------------------------------------------------------------------
__global__ __launch_bounds__(256) void k_final(
    const float* __restrict__ h, const float* __restrict__ dw,
    const float* __restrict__ db, float* __restrict__ out)
{
  __shared__ float P[H_];
  __shared__ float Z[2];
  int b = blockIdx.x, tid = threadIdx.x;
  const float4* row = (const float4*)(h + ((size_t)(b * H_ + tid)) * LSEQ);
  float a0 = 0, a1 = 0, a2 = 0, a3 = 0;
  for (int t = 0; t < LSEQ / 4; ++t) {
    float4 v = row[t];
    a0 += v.x; a1 += v.y; a2 += v.z; a3 += v.w;
  }
  P[tid] = (a0 + a1 + a2 + a3) * (1.f / LSEQ);
  __syncthreads();
  if (tid < 2) {
    float z = db[tid];
    for (int k = 0; k < H_; ++k) z = fmaf(P[k], dw[k * DOUT + tid], z);
    Z[tid] = z;
  }
  __syncthreads();
  if (tid == 0) {
    float m = fmaxf(Z[0], Z[1]);
    float e0 = expf(Z[0] - m), e1 = expf(Z[1] - m);
    float inv = 1.f / (e0 + e1);
    out[b * 2 + 0] = e0 * inv;
    out[b * 2 + 1] = e1 * inv;
  }
}

// ---------------------------------------------------------------------------
extern "C" void kernel_launch(void* const* d_in, const int* in_sizes, int n_in,
                              void* d_out, int out_size, void* d_ws, size_t ws_size,
                              hipStream_t stream) {
  (void)in_sizes; (void)n_in; (void)out_size; (void)ws_size;
  const float* x      = (const float*)d_in[0];
  const float* enc_w  = (const float*)d_in[1];
  const float* enc_b  = (const float*)d_in[2];
  const float* log_dt = (const float*)d_in[3];
  const float* Cri    = (const float*)d_in[4];
  const float* lAr    = (const float*)d_in[5];
  const float* Aim    = (const float*)d_in[6];
  const float* Dsk    = (const float*)d_in[7];
  const float* glu_w  = (const float*)d_in[8];
  const float* glu_b  = (const float*)d_in[9];
  const float* ln_g   = (const float*)d_in[10];
  const float* ln_b   = (const float*)d_in[11];
  const float* dec_w  = (const float*)d_in[12];
  const float* dec_b  = (const float*)d_in[13];
  float* out = (float*)d_out;

  float* h = (float*)d_ws;                       // (B,H,L) fp32, 128MB
  float* G = h + (size_t)B_ * H_ * LSEQ;         // (B,H,L) fp32, 128MB

  k_encoder<<<B_ * (LSEQ / 32), 256, 0, stream>>>(x, enc_w, enc_b, h);
  for (int i = 0; i < NL_; ++i) {
    k_scan<<<(B_ * H_) / 4, 256, 0, stream>>>(h, G, log_dt, Cri, lAr, Aim, Dsk, i);
    k_glu<<<dim3((B_ * LSEQ) / 64, 4), 256, 0, stream>>>(G, h, glu_w, glu_b, i);
    k_ln<<<B_ * (LSEQ / 64), 256, 0, stream>>>(h, ln_g, ln_b, i);
  }
  k_final<<<B_, 256, 0, stream>>>(h, dec_w, dec_b, out);
}

// Round 2
// 2004.508 us; speedup vs baseline: 1.8137x; 1.8137x over previous
//
#include <hip/hip_runtime.h>
#include <math.h>

#define B_    32
#define DIN   64
#define LSEQ  4096
#define H_    256
#define N2_   32
#define NL_   4
#define DOUT  2
#define LN_EPSF 1e-5f

typedef __bf16 bf16x8 __attribute__((ext_vector_type(8)));
typedef float  f32x4  __attribute__((ext_vector_type(4)));

__device__ inline unsigned short f2bf(float f) {
  unsigned u = __builtin_bit_cast(unsigned, f);
  u += 0x7FFFu + ((u >> 16) & 1u);
  return (unsigned short)(u >> 16);
}

// ---------------------------------------------------------------------------
// Convert glu_w fp32 -> bf16, pre-swizzled into per-K-chunk LDS image order:
// out[((layer*4+kc4)*512 + r)*64 + uu*8 + j] = bf16(W[layer][r][kc4*64 + ((uu^(r&7))*8 + j)])
// so k_glu can stage with linear coalesced 16B loads + linear LDS writes.
// ---------------------------------------------------------------------------
__global__ __launch_bounds__(256) void k_wconv(
    const float* __restrict__ gw, unsigned short* __restrict__ wb)
{
  int t = blockIdx.x * 256 + threadIdx.x;      // 65536 threads
  int uu = t & 7;
  int r  = (t >> 3) & 511;
  int l4 = t >> 12;                            // layer*4 + kc4
  int layer = l4 >> 2, kc4 = l4 & 3;
  int ksrc = kc4 * 64 + ((uu ^ (r & 7)) << 3);
  const float* src = gw + ((size_t)(layer * 512 + r)) * H_ + ksrc;
  unsigned short* dst = wb + (size_t)t * 8;
#pragma unroll
  for (int j = 0; j < 8; ++j) dst[j] = f2bf(src[j]);
}

// ---------------------------------------------------------------------------
// Encoder: h[b,d,l] = sum_c x[b,c,l]*ew[c,d] + eb[d]  (unchanged)
// ---------------------------------------------------------------------------
__global__ __launch_bounds__(256) void k_encoder(
    const float* __restrict__ x, const float* __restrict__ ew,
    const float* __restrict__ eb, float* __restrict__ h)
{
  __shared__ __align__(16) float Wl[32][256];
  __shared__ __align__(16) float Xl[32][32];
  int tid = threadIdx.x;
  int blk = blockIdx.x;
  int b  = blk >> 7;
  int l0 = (blk & 127) << 5;
  int ty = tid >> 3;
  int tx = tid & 7;
  float acc[8][4];
#pragma unroll
  for (int i = 0; i < 8; ++i)
#pragma unroll
    for (int j = 0; j < 4; ++j) acc[i][j] = 0.f;

  for (int kc = 0; kc < DIN; kc += 32) {
    const float4* ew4 = (const float4*)(ew + kc * H_);
#pragma unroll
    for (int it = 0; it < 8; ++it) {
      int idx = tid + (it << 8);
      ((float4*)&Wl[0][0])[idx] = ew4[idx];
    }
    {
      int c = tid >> 3, p = (tid & 7) << 2;
      *(float4*)&Xl[c][p] =
          *(const float4*)(x + ((size_t)(b * DIN + kc + c)) * LSEQ + l0 + p);
    }
    __syncthreads();
#pragma unroll
    for (int k = 0; k < 32; ++k) {
      float4 w0 = *(float4*)&Wl[k][ty * 8];
      float4 w1 = *(float4*)&Wl[k][ty * 8 + 4];
      float4 xv = *(float4*)&Xl[k][tx * 4];
      float wvv[8] = {w0.x, w0.y, w0.z, w0.w, w1.x, w1.y, w1.z, w1.w};
      float xs[4]  = {xv.x, xv.y, xv.z, xv.w};
#pragma unroll
      for (int i = 0; i < 8; ++i)
#pragma unroll
        for (int j = 0; j < 4; ++j) acc[i][j] = fmaf(wvv[i], xs[j], acc[i][j]);
    }
    __syncthreads();
  }
#pragma unroll
  for (int i = 0; i < 8; ++i) {
    int d = ty * 8 + i;
    float bia = eb[d];
    float4 o = make_float4(acc[i][0] + bia, acc[i][1] + bia,
                           acc[i][2] + bia, acc[i][3] + bia);
    *(float4*)(h + ((size_t)(b * H_ + d)) * LSEQ + l0 + tx * 4) = o;
  }
}

// ---------------------------------------------------------------------------
// S4D scan (unchanged math). Output G now bf16 (ushort bits).
// ---------------------------------------------------------------------------
__global__ __launch_bounds__(256) void k_scan(
    const float* __restrict__ hin, unsigned short* __restrict__ G,
    const float* __restrict__ log_dt, const float* __restrict__ Cri,
    const float* __restrict__ lAr, const float* __restrict__ Aim,
    const float* __restrict__ Dsk, int layer)
{
  int tid = threadIdx.x;
  int wv   = tid >> 6;
  int lane = tid & 63;
  int row  = blockIdx.x * 4 + wv;     // b*H + h
  int hh   = row & (H_ - 1);
  int g = lane >> 2;
  int j = lane & 3;
  const float* U = hin + (size_t)row * LSEQ;
  unsigned short* Gr = G + (size_t)row * LSEQ;

  float dt  = expf(log_dt[layer * H_ + hh]);
  float dsk = Dsk[layer * H_ + hh];
  int pbase = (layer * H_ + hh) * N2_ + j * 8;

  float ar[8], ai[8], ctr[8], cti[8], dAr[8], dAi[8];
#pragma unroll
  for (int k = 0; k < 8; ++k) {
    int n = pbase + k;
    float Are  = -expf(lAr[n]);
    float Aimv = Aim[n];
    float dr = Are * dt, di = Aimv * dt;
    dAr[k] = dr; dAi[k] = di;
    float er = expf(dr), sn, cs;
    sincosf(di, &sn, &cs);
    ar[k] = er * cs; ai[k] = er * sn;
    float nr = ar[k] - 1.f, ni = ai[k];
    float inv = 1.f / (Are * Are + Aimv * Aimv);
    float qr = (nr * Are + ni * Aimv) * inv;
    float qi = (ni * Are - nr * Aimv) * inv;
    float Cr = Cri[2 * n], Ci = Cri[2 * n + 1];
    ctr[k] = 2.f * (Cr * qr - Ci * qi);
    cti[k] = 2.f * (Cr * qi + Ci * qr);
  }

  int cb = g << 8;
  float sr[8], si[8];
#pragma unroll
  for (int k = 0; k < 8; ++k) { sr[k] = 0.f; si[k] = 0.f; }

  // pass 1: local end-state
  for (int t4 = 0; t4 < 64; ++t4) {
    float4 u4 = *(const float4*)(U + cb + t4 * 4);
    float us[4] = {u4.x, u4.y, u4.z, u4.w};
#pragma unroll
    for (int tt = 0; tt < 4; ++tt) {
      float u = us[tt];
#pragma unroll
      for (int k = 0; k < 8; ++k) {
        float nsr = fmaf(ar[k], sr[k], fmaf(-ai[k], si[k], u));
        si[k] = fmaf(ar[k], si[k], ai[k] * sr[k]);
        sr[k] = nsr;
      }
    }
  }

  // chunk scan
  for (int dd = 0; dd < 4; ++dd) {
    int d = 1 << dd;
    float fac = (float)(256 * d);
#pragma unroll
    for (int k = 0; k < 8; ++k) {
      float er = expf(dAr[k] * fac), sn, cs;
      sincosf(dAi[k] * fac, &sn, &cs);
      float mr = er * cs, mi = er * sn;
      float pr = __shfl_up(sr[k], (unsigned)(d * 4));
      float pi = __shfl_up(si[k], (unsigned)(d * 4));
      if (g >= d) {
        sr[k] = fmaf(mr, pr, fmaf(-mi, pi, sr[k]));
        si[k] = fmaf(mr, pi, fmaf(mi, pr, si[k]));
      }
    }
  }
#pragma unroll
  for (int k = 0; k < 8; ++k) {
    float pr = __shfl_up(sr[k], 4u);
    float pi = __shfl_up(si[k], 4u);
    sr[k] = (g == 0) ? 0.f : pr;
    si[k] = (g == 0) ? 0.f : pi;
  }

  // pass 2
  for (int t16 = 0; t16 < 16; ++t16) {
    float yb[4] = {0.f, 0.f, 0.f, 0.f};
#pragma unroll
    for (int q4 = 0; q4 < 4; ++q4) {
      float4 u4 = *(const float4*)(U + cb + t16 * 16 + q4 * 4);
      float us[4] = {u4.x, u4.y, u4.z, u4.w};
#pragma unroll
      for (int tt = 0; tt < 4; ++tt) {
        float u = us[tt];
        float yp = 0.f;
#pragma unroll
        for (int k = 0; k < 8; ++k) {
          float nsr = fmaf(ar[k], sr[k], fmaf(-ai[k], si[k], u));
          si[k] = fmaf(ar[k], si[k], ai[k] * sr[k]);
          sr[k] = nsr;
          yp = fmaf(ctr[k], sr[k], yp);
          yp = fmaf(-cti[k], si[k], yp);
        }
        yp += __shfl_xor(yp, 1);
        yp += __shfl_xor(yp, 2);
        float yv = fmaf(dsk, u, yp);
        float ge = 0.5f * yv * (1.f + erff(yv * 0.70710678118f));
        int step = q4 * 4 + tt;
        if (j == (step >> 2)) yb[step & 3] = ge;
      }
    }
    ushort4 o4;
    o4.x = f2bf(yb[0]); o4.y = f2bf(yb[1]);
    o4.z = f2bf(yb[2]); o4.w = f2bf(yb[3]);
    *(ushort4*)(Gr + cb + t16 * 16 + j * 4) = o4;
  }
}

// ---------------------------------------------------------------------------
// GLU via bf16 MFMA + fused residual + LayerNorm.
// Block: 512 thr (8 waves), tile = all 512 GEMM rows x 64 cols, BK=64.
// Wave w owns channels [w*32, w*32+32): a-rows = ch, g-rows = ch+256 ->
// GLU pairs are lane-local in the D fragments.
// LDS: Wl 64KB (swizzled units, staged linearly from pre-swizzled Wb),
//      Gl 8KB  (transposed [col][k], swizzled), Red 4KB (LN reduction).
// ---------------------------------------------------------------------------
__global__ __launch_bounds__(512, 4) void k_glu(
    const unsigned short* __restrict__ Wb, const unsigned short* __restrict__ G,
    float* __restrict__ h, const float* __restrict__ gb,
    const float* __restrict__ lng, const float* __restrict__ lnb, int layer)
{
  extern __shared__ char smem[];
  char* WlB = smem;                       // 65536 B
  char* GlB = smem + 65536;               // 8192 B
  float2* Red = (float2*)(smem + 65536 + 8192);  // 8*64 float2 = 4096 B

  int tid = threadIdx.x;
  int w = tid >> 6, lane = tid & 63;
  int b  = blockIdx.x >> 6;
  int l0 = (blockIdx.x & 63) << 6;
  int rgrp = lane >> 4, lc = lane & 15;

  f32x4 acc[4][4];
#pragma unroll
  for (int m = 0; m < 4; ++m)
#pragma unroll
    for (int n = 0; n < 4; ++n) acc[m][n] = (f32x4){0.f, 0.f, 0.f, 0.f};

  const unsigned short* wsrc = Wb + (size_t)(layer * 4) * 512 * 64;

  for (int kc4 = 0; kc4 < 4; ++kc4) {
    if (kc4) __syncthreads();
    // --- W stage: linear coalesced 16B loads -> linear LDS writes ---
    const unsigned short* wc = wsrc + (size_t)kc4 * 512 * 64;
#pragma unroll
    for (int i = 0; i < 8; ++i) {
      int off = w * 8192 + i * 1024 + lane * 16;   // bytes
      uint4 v = *(const uint4*)((const char*)wc + off);
      *(uint4*)(WlB + off) = v;
    }
    // --- G stage: transpose [k][l] -> [col][k] with unit swizzle ---
    {
      int col = lane;
      int kc = kc4 * 64;
      unsigned pk0, pk1, pk2, pk3;
      size_t base = (size_t)(b * H_ + kc + w * 8) * LSEQ + l0 + col;
      unsigned v0 = G[base];
      unsigned v1 = G[base + (size_t)1 * LSEQ];
      unsigned v2 = G[base + (size_t)2 * LSEQ];
      unsigned v3 = G[base + (size_t)3 * LSEQ];
      unsigned v4 = G[base + (size_t)4 * LSEQ];
      unsigned v5 = G[base + (size_t)5 * LSEQ];
      unsigned v6 = G[base + (size_t)6 * LSEQ];
      unsigned v7 = G[base + (size_t)7 * LSEQ];
      pk0 = v0 | (v1 << 16); pk1 = v2 | (v3 << 16);
      pk2 = v4 | (v5 << 16); pk3 = v6 | (v7 << 16);
      *(uint4*)(GlB + col * 128 + ((w ^ (col & 7)) << 4)) =
          make_uint4(pk0, pk1, pk2, pk3);
    }
    __syncthreads();
    // --- compute: 2 k-sub-steps x 16 MFMA ---
#pragma unroll
    for (int ks = 0; ks < 2; ++ks) {
      int u = ks * 4 + rgrp;
      bf16x8 af[4], bff[4];
#pragma unroll
      for (int m = 0; m < 4; ++m) {
        int grow = ((m < 2) ? (w * 32 + m * 16) : (256 + w * 32 + (m - 2) * 16)) + lc;
        af[m] = *(const bf16x8*)(WlB + grow * 128 + ((u ^ (grow & 7)) << 4));
      }
#pragma unroll
      for (int n = 0; n < 4; ++n) {
        int gcol = n * 16 + lc;
        bff[n] = *(const bf16x8*)(GlB + gcol * 128 + ((u ^ (gcol & 7)) << 4));
      }
#pragma unroll
      for (int m = 0; m < 4; ++m)
#pragma unroll
        for (int n = 0; n < 4; ++n)
          acc[m][n] = __builtin_amdgcn_mfma_f32_16x16x32_bf16(
              af[m], bff[n], acc[m][n], 0, 0, 0);
    }
  }

  // --- epilogue: bias + GLU + residual, LN stats ---
  const float* gbL = gb + layer * 2 * H_;
  float out[2][4][4];
  float s[4], ss[4];
#pragma unroll
  for (int n = 0; n < 4; ++n) { s[n] = 0.f; ss[n] = 0.f; }
#pragma unroll
  for (int mA = 0; mA < 2; ++mA) {
#pragma unroll
    for (int reg = 0; reg < 4; ++reg) {
      int ch = w * 32 + mA * 16 + rgrp * 4 + reg;
      float ba = gbL[ch], bg = gbL[ch + H_];
#pragma unroll
      for (int n = 0; n < 4; ++n) {
        int col = n * 16 + lc;
        size_t off = (size_t)(b * H_ + ch) * LSEQ + l0 + col;
        float a = acc[mA][n][reg] + ba;
        float gv = acc[mA + 2][n][reg] + bg;
        float sg = 1.f / (1.f + expf(-gv));
        float o = fmaf(a, sg, h[off]);
        out[mA][n][reg] = o;
        s[n] += o; ss[n] = fmaf(o, o, ss[n]);
      }
    }
  }
#pragma unroll
  for (int n = 0; n < 4; ++n) {
    s[n]  += __shfl_xor(s[n], 16);  s[n]  += __shfl_xor(s[n], 32);
    ss[n] += __shfl_xor(ss[n], 16); ss[n] += __shfl_xor(ss[n], 32);
  }
  if (lane < 16) {
#pragma unroll
    for (int n = 0; n < 4; ++n)
      Red[w * 64 + n * 16 + lane] = make_float2(s[n], ss[n]);
  }
  __syncthreads();
  float mu[4], rs[4];
#pragma unroll
  for (int n = 0; n < 4; ++n) {
    int col = n * 16 + lc;
    float ts = 0.f, tss = 0.f;
#pragma unroll
    for (int ww = 0; ww < 8; ++ww) {
      float2 v = Red[ww * 64 + col];
      ts += v.x; tss += v.y;
    }
    mu[n] = ts * (1.f / H_);
    rs[n] = rsqrtf(tss * (1.f / H_) - mu[n] * mu[n] + LN_EPSF);
  }
#pragma unroll
  for (int mA = 0; mA < 2; ++mA) {
#pragma unroll
    for (int reg = 0; reg < 4; ++reg) {
      int ch = w * 32 + mA * 16 + rgrp * 4 + reg;
      float lg = lng[layer * H_ + ch], lb = lnb[layer * H_ + ch];
#pragma unroll
      for (int n = 0; n < 4; ++n) {
        int col = n * 16 + lc;
        size_t off = (size_t)(b * H_ + ch) * LSEQ + l0 + col;
        h[off] = (out[mA][n][reg] - mu[n]) * rs[n] * lg + lb;
      }
    }
  }
}

// ---------------------------------------------------------------------------
// Mean-pool over L, decode (256->2), softmax. grid B, block 256.
// ---------------------------------------------------------------------------
__global__ __launch_bounds__(256) void k_final(
    const float* __restrict__ h, const float* __restrict__ dw,
    const float* __restrict__ db, float* __restrict__ out)
{
  __shared__ float P[H_];
  __shared__ float Z[2];
  int b = blockIdx.x, tid = threadIdx.x;
  const float4* row = (const float4*)(h + ((size_t)(b * H_ + tid)) * LSEQ);
  float a0 = 0, a1 = 0, a2 = 0, a3 = 0;
  for (int t = 0; t < LSEQ / 4; ++t) {
    float4 v = row[t];
    a0 += v.x; a1 += v.y; a2 += v.z; a3 += v.w;
  }
  P[tid] = (a0 + a1 + a2 + a3) * (1.f / LSEQ);
  __syncthreads();
  if (tid < 2) {
    float z = db[tid];
    for (int k = 0; k < H_; ++k) z = fmaf(P[k], dw[k * DOUT + tid], z);
    Z[tid] = z;
  }
  __syncthreads();
  if (tid == 0) {
    float m = fmaxf(Z[0], Z[1]);
    float e0 = expf(Z[0] - m), e1 = expf(Z[1] - m);
    float inv = 1.f / (e0 + e1);
    out[b * 2 + 0] = e0 * inv;
    out[b * 2 + 1] = e1 * inv;
  }
}

// ---------------------------------------------------------------------------
extern "C" void kernel_launch(void* const* d_in, const int* in_sizes, int n_in,
                              void* d_out, int out_size, void* d_ws, size_t ws_size,
                              hipStream_t stream) {
  (void)in_sizes; (void)n_in; (void)out_size; (void)ws_size;
  const float* x      = (const float*)d_in[0];
  const float* enc_w  = (const float*)d_in[1];
  const float* enc_b  = (const float*)d_in[2];
  const float* log_dt = (const float*)d_in[3];
  const float* Cri    = (const float*)d_in[4];
  const float* lAr    = (const float*)d_in[5];
  const float* Aim    = (const float*)d_in[6];
  const float* Dsk    = (const float*)d_in[7];
  const float* glu_w  = (const float*)d_in[8];
  const float* glu_b  = (const float*)d_in[9];
  const float* ln_g   = (const float*)d_in[10];
  const float* ln_b   = (const float*)d_in[11];
  const float* dec_w  = (const float*)d_in[12];
  const float* dec_b  = (const float*)d_in[13];
  float* out = (float*)d_out;

  float* h = (float*)d_ws;                                  // 128 MB fp32
  unsigned short* G  = (unsigned short*)(h + (size_t)B_ * H_ * LSEQ);  // 64 MB bf16
  unsigned short* Wb = G + (size_t)B_ * H_ * LSEQ;          // 1 MB bf16 (pre-swizzled)

  k_wconv<<<256, 256, 0, stream>>>(glu_w, Wb);
  k_encoder<<<B_ * (LSEQ / 32), 256, 0, stream>>>(x, enc_w, enc_b, h);
  for (int i = 0; i < NL_; ++i) {
    k_scan<<<(B_ * H_) / 4, 256, 0, stream>>>(h, G, log_dt, Cri, lAr, Aim, Dsk, i);
    k_glu<<<B_ * (LSEQ / 64), 512, 77824, stream>>>(Wb, G, h, glu_b, ln_g, ln_b, i);
  }
  k_final<<<B_, 256, 0, stream>>>(h, dec_w, dec_b, out);
}

// Round 5
// 1311.354 us; speedup vs baseline: 2.7724x; 1.5286x over previous
//
#include <hip/hip_runtime.h>
#include <math.h>

#define B_    32
#define DIN   64
#define LSEQ  4096
#define H_    256
#define N2_   32
#define NL_   4
#define DOUT  2
#define LN_EPSF 1e-5f

typedef __bf16 bf16x8 __attribute__((ext_vector_type(8)));
typedef float  f32x4  __attribute__((ext_vector_type(4)));

__device__ inline unsigned short f2bf(float f) {
  unsigned u = __builtin_bit_cast(unsigned, f);
  u += 0x7FFFu + ((u >> 16) & 1u);
  return (unsigned short)(u >> 16);
}
__device__ inline float bf2f(unsigned short u) {
  return __builtin_bit_cast(float, ((unsigned)u) << 16);
}

// ZOH discretization params for mode n of (layer, hh)
__device__ inline void mode_params(const float* log_dt, const float* Cri,
                                   const float* lAr, const float* Aim,
                                   int layer, int hh, int n, float dt,
                                   float& dr, float& di, float& ctr, float& cti) {
  int idx = (layer * H_ + hh) * N2_ + n;
  float Are = -expf(lAr[idx]);
  float Aimv = Aim[idx];
  dr = Are * dt; di = Aimv * dt;
  float er = expf(dr), sn, cs;
  sincosf(di, &sn, &cs);
  float arr = er * cs, aii = er * sn;
  float nr = arr - 1.f, ni = aii;
  float inv = 1.f / (Are * Are + Aimv * Aimv);
  float qr = (nr * Are + ni * Aimv) * inv;
  float qi = (ni * Are - nr * Aimv) * inv;
  float Cr = Cri[2 * idx], Ci = Cri[2 * idx + 1];
  ctr = 2.f * (Cr * qr - Ci * qi);
  cti = 2.f * (Cr * qi + Ci * qr);
}

// ---------------------------------------------------------------------------
// k_prep: per (layer,h) build pre-swizzled bf16 images (64x64 each):
//  Tt[i][t]   = k[i-t] (i>=t else 0), k[d] = Re(sum_n ct_n a_n^d)
//  Win[r][t]  = Re/Im(a_n^(63-t)), r=2n(+1)
//  Whi/Wlo[i][r] = hi/lo bf16 of M[i][r]: M[i][2n]=Re(ct a^(i+1)), [2n+1]=-Im(..)
// Element (row,kk) stored at row*64 + ((kk>>3)^(row&7))*8 + (kk&7)  (u16).
// grid NL_*H_ blocks x 64 threads.
// ---------------------------------------------------------------------------
__global__ __launch_bounds__(64) void k_prep(
    const float* __restrict__ log_dt, const float* __restrict__ Cri,
    const float* __restrict__ lAr, const float* __restrict__ Aim,
    unsigned short* __restrict__ TtG, unsigned short* __restrict__ WinG,
    unsigned short* __restrict__ WhiG, unsigned short* __restrict__ WloG)
{
  int bid = blockIdx.x;
  int layer = bid >> 8, hh = bid & 255;
  int lane = threadIdx.x;
  __shared__ float Kf[64];
  float dt = expf(log_dt[layer * H_ + hh]);

  // k[lane]
  float kd = 0.f;
  for (int n = 0; n < N2_; ++n) {
    float dr, di, ctr, cti;
    mode_params(log_dt, Cri, lAr, Aim, layer, hh, n, dt, dr, di, ctr, cti);
    float er = expf(dr * (float)lane), sn, cs;
    sincosf(di * (float)lane, &sn, &cs);
    kd += ctr * (er * cs) - cti * (er * sn);
  }
  Kf[lane] = kd;
  __syncthreads();

  size_t base = (size_t)bid * 4096;
  // Tt row i = lane
  for (int t = 0; t < 64; ++t) {
    float v = (t <= lane) ? Kf[lane - t] : 0.f;
    TtG[base + lane * 64 + (((t >> 3) ^ (lane & 7)) << 3) + (t & 7)] = f2bf(v);
  }
  // Win row r = lane
  {
    int n = lane >> 1, im = lane & 1;
    float dr, di, ctr, cti;
    mode_params(log_dt, Cri, lAr, Aim, layer, hh, n, dt, dr, di, ctr, cti);
    for (int t = 0; t < 64; ++t) {
      float e = (float)(63 - t);
      float er = expf(dr * e), sn, cs;
      sincosf(di * e, &sn, &cs);
      float v = im ? (er * sn) : (er * cs);
      WinG[base + lane * 64 + (((t >> 3) ^ (lane & 7)) << 3) + (t & 7)] = f2bf(v);
    }
  }
  // W rows i = lane
  for (int r = 0; r < 64; ++r) {
    int n = r >> 1;
    float dr, di, ctr, cti;
    mode_params(log_dt, Cri, lAr, Aim, layer, hh, n, dt, dr, di, ctr, cti);
    float e = (float)(lane + 1);
    float er = expf(dr * e), sn, cs;
    sincosf(di * e, &sn, &cs);
    float wre = ctr * (er * cs) - cti * (er * sn);
    float wim = ctr * (er * sn) + cti * (er * cs);
    float v = (r & 1) ? -wim : wre;
    unsigned short hi = f2bf(v);
    float lo = v - bf2f(hi);
    size_t off = base + lane * 64 + (((r >> 3) ^ (lane & 7)) << 3) + (r & 7);
    WhiG[off] = hi;
    WloG[off] = f2bf(lo);
  }
}

// ---------------------------------------------------------------------------
// k_wconv: glu_w fp32 -> bf16 pre-swizzled (unchanged from round 2)
// ---------------------------------------------------------------------------
__global__ __launch_bounds__(256) void k_wconv(
    const float* __restrict__ gw, unsigned short* __restrict__ wb)
{
  int t = blockIdx.x * 256 + threadIdx.x;
  int uu = t & 7;
  int r  = (t >> 3) & 511;
  int l4 = t >> 12;
  int layer = l4 >> 2, kc4 = l4 & 3;
  int ksrc = kc4 * 64 + ((uu ^ (r & 7)) << 3);
  const float* src = gw + ((size_t)(layer * 512 + r)) * H_ + ksrc;
  unsigned short* dst = wb + (size_t)t * 8;
#pragma unroll
  for (int j = 0; j < 8; ++j) dst[j] = f2bf(src[j]);
}

// ---------------------------------------------------------------------------
// Encoder (unchanged)
// ---------------------------------------------------------------------------
__global__ __launch_bounds__(256) void k_encoder(
    const float* __restrict__ x, const float* __restrict__ ew,
    const float* __restrict__ eb, float* __restrict__ h)
{
  __shared__ __align__(16) float Wl[32][256];
  __shared__ __align__(16) float Xl[32][32];
  int tid = threadIdx.x;
  int blk = blockIdx.x;
  int b  = blk >> 7;
  int l0 = (blk & 127) << 5;
  int ty = tid >> 3;
  int tx = tid & 7;
  float acc[8][4];
#pragma unroll
  for (int i = 0; i < 8; ++i)
#pragma unroll
    for (int j = 0; j < 4; ++j) acc[i][j] = 0.f;

  for (int kc = 0; kc < DIN; kc += 32) {
    const float4* ew4 = (const float4*)(ew + kc * H_);
#pragma unroll
    for (int it = 0; it < 8; ++it) {
      int idx = tid + (it << 8);
      ((float4*)&Wl[0][0])[idx] = ew4[idx];
    }
    {
      int c = tid >> 3, p = (tid & 7) << 2;
      *(float4*)&Xl[c][p] =
          *(const float4*)(x + ((size_t)(b * DIN + kc + c)) * LSEQ + l0 + p);
    }
    __syncthreads();
#pragma unroll
    for (int k = 0; k < 32; ++k) {
      float4 w0 = *(float4*)&Wl[k][ty * 8];
      float4 w1 = *(float4*)&Wl[k][ty * 8 + 4];
      float4 xv = *(float4*)&Xl[k][tx * 4];
      float wvv[8] = {w0.x, w0.y, w0.z, w0.w, w1.x, w1.y, w1.z, w1.w};
      float xs[4]  = {xv.x, xv.y, xv.z, xv.w};
#pragma unroll
      for (int i = 0; i < 8; ++i)
#pragma unroll
        for (int j = 0; j < 4; ++j) acc[i][j] = fmaf(wvv[i], xs[j], acc[i][j]);
    }
    __syncthreads();
  }
#pragma unroll
  for (int i = 0; i < 8; ++i) {
    int d = ty * 8 + i;
    float bia = eb[d];
    float4 o = make_float4(acc[i][0] + bia, acc[i][1] + bia,
                           acc[i][2] + bia, acc[i][3] + bia);
    *(float4*)(h + ((size_t)(b * H_ + d)) * LSEQ + l0 + tx * 4) = o;
  }
}

// ---------------------------------------------------------------------------
// k_chunk: MFMA chunked S4D scan + GELU. One block per (h,b): full 4096 row.
//  Phase 1: Yloc = U@Tt', Bst = U@Win'  (bf16 MFMA, fp32 acc)
//  Phase 2: 32 lanes scan chunk states (fp32, exact a^64), write S hi/lo bf16;
//           threads 64+ stage Whi/Wlo into Tt/Win LDS space.
//  Phase 3: Y += Shi@Whi + Slo@Whi + Shi@Wlo; +D*u; GELU; coalesced G write.
// ---------------------------------------------------------------------------
__global__ __launch_bounds__(256) void k_chunk(
    const float* __restrict__ hin, unsigned short* __restrict__ G,
    const unsigned short* __restrict__ TtG, const unsigned short* __restrict__ WinG,
    const unsigned short* __restrict__ WhiG, const unsigned short* __restrict__ WloG,
    const float* __restrict__ log_dt, const float* __restrict__ lAr,
    const float* __restrict__ Aim, const float* __restrict__ Dsk, int layer)
{
  __shared__ __align__(16) char smem[57344];
  char* Ul   = smem;            // 8KB bf16 [c][t] swz
  char* TtL  = smem + 8192;     // 8KB bf16 [i][t] swz -> later Whi [i][r]
  char* WinL = smem + 16384;    // 8KB bf16 [r][t] swz -> later Wlo [i][r]
  float* BstF = (float*)(smem + 24576);  // 16KB f32 [c][r] -> later Y u16 [c][i]
  char* ShiL = smem + 40960;    // 8KB bf16 [c][r] swz
  char* SloL = smem + 49152;    // 8KB

  int tid = threadIdx.x;
  int w = tid >> 6, lane = tid & 63;
  int rg = lane >> 4, lc = lane & 15;
  int bid = blockIdx.x;
  int hh = bid >> 5, b = bid & 31;
  size_t wbase = ((size_t)(layer * H_ + hh)) * 4096;
  const float* Urow = hin + ((size_t)(b * H_ + hh)) * LSEQ;

  // ---- stage U (fp32->bf16, swizzled) + Tt + Win (linear) ----
#pragma unroll
  for (int it = 0; it < 2; ++it) {
    int idx = tid + (it << 8);          // 0..511
    int c = idx >> 3, uu = idx & 7;
    const float* src = Urow + c * 64 + uu * 8;
    float4 u0 = *(const float4*)(src);
    float4 u1 = *(const float4*)(src + 4);
    unsigned p0 = f2bf(u0.x) | ((unsigned)f2bf(u0.y) << 16);
    unsigned p1 = f2bf(u0.z) | ((unsigned)f2bf(u0.w) << 16);
    unsigned p2 = f2bf(u1.x) | ((unsigned)f2bf(u1.y) << 16);
    unsigned p3 = f2bf(u1.z) | ((unsigned)f2bf(u1.w) << 16);
    *(uint4*)(Ul + c * 128 + ((uu ^ (c & 7)) << 4)) = make_uint4(p0, p1, p2, p3);
    ((uint4*)TtL)[idx]  = ((const uint4*)(TtG + wbase))[idx];
    ((uint4*)WinL)[idx] = ((const uint4*)(WinG + wbase))[idx];
  }
  __syncthreads();

  // ---- phase 1 GEMMs ----
  f32x4 accY[4], accB[4];
#pragma unroll
  for (int nb = 0; nb < 4; ++nb) {
    accY[nb] = (f32x4){0.f, 0.f, 0.f, 0.f};
    accB[nb] = (f32x4){0.f, 0.f, 0.f, 0.f};
  }
#pragma unroll
  for (int ks = 0; ks < 2; ++ks) {
    int ca = w * 16 + lc;
    int u = ks * 4 + rg;
    bf16x8 A = *(const bf16x8*)(Ul + ca * 128 + ((u ^ (ca & 7)) << 4));
#pragma unroll
    for (int nb = 0; nb < 4; ++nb) {
      int col = nb * 16 + lc;
      bf16x8 Bt = *(const bf16x8*)(TtL + col * 128 + ((u ^ (col & 7)) << 4));
      bf16x8 Bw = *(const bf16x8*)(WinL + col * 128 + ((u ^ (col & 7)) << 4));
      accY[nb] = __builtin_amdgcn_mfma_f32_16x16x32_bf16(A, Bt, accY[nb], 0, 0, 0);
      accB[nb] = __builtin_amdgcn_mfma_f32_16x16x32_bf16(A, Bw, accB[nb], 0, 0, 0);
    }
  }
  // Bst frags -> LDS f32 [c][r]
#pragma unroll
  for (int nb = 0; nb < 4; ++nb)
#pragma unroll
    for (int reg = 0; reg < 4; ++reg)
      BstF[(w * 16 + rg * 4 + reg) * 64 + nb * 16 + lc] = accB[nb][reg];
  __syncthreads();

  // ---- phase 2: scan (tid<32) || stage Whi/Wlo (tid>=64) ----
  if (tid < 32) {
    int n = tid;
    int pidx = (layer * H_ + hh) * N2_ + n;
    float dtv = expf(log_dt[layer * H_ + hh]);
    float dr = -expf(lAr[pidx]) * dtv;
    float di = Aim[pidx] * dtv;
    float er = expf(dr * 64.f), sn, cs;
    sincosf(di * 64.f, &sn, &cs);
    float aQr = er * cs, aQi = er * sn;
    float Sr = 0.f, Si = 0.f;
    int swzu = n >> 2;                       // (2n)>>3
    int bofs = ((2 * n) & 7) * 2;
    for (int c = 0; c < 64; ++c) {
      unsigned short hr = f2bf(Sr), hi_ = f2bf(Si);
      unsigned hiw = (unsigned)hr | ((unsigned)hi_ << 16);
      unsigned low = (unsigned)f2bf(Sr - bf2f(hr)) |
                     ((unsigned)f2bf(Si - bf2f(hi_)) << 16);
      int boff = c * 128 + ((swzu ^ (c & 7)) << 4) + bofs;
      *(unsigned*)(ShiL + boff) = hiw;
      *(unsigned*)(SloL + boff) = low;
      float2 Bc = *(float2*)(BstF + c * 64 + 2 * n);
      float nsr = fmaf(aQr, Sr, fmaf(-aQi, Si, Bc.x));
      Si = fmaf(aQr, Si, fmaf(aQi, Sr, Bc.y));
      Sr = nsr;
    }
  } else if (tid >= 64) {
#pragma unroll
    for (int it = 0; it < 6; ++it) {
      int j = (tid - 64) + it * 192;
      if (j < 512)
        ((uint4*)TtL)[j] = ((const uint4*)(WhiG + wbase))[j];
      else if (j < 1024)
        ((uint4*)WinL)[j - 512] = ((const uint4*)(WloG + wbase))[j - 512];
    }
  }
  __syncthreads();

  // ---- phase 3: correction GEMMs ----
#pragma unroll
  for (int ks = 0; ks < 2; ++ks) {
    int ca = w * 16 + lc;
    int u = ks * 4 + rg;
    bf16x8 Ah = *(const bf16x8*)(ShiL + ca * 128 + ((u ^ (ca & 7)) << 4));
    bf16x8 Al = *(const bf16x8*)(SloL + ca * 128 + ((u ^ (ca & 7)) << 4));
#pragma unroll
    for (int nb = 0; nb < 4; ++nb) {
      int col = nb * 16 + lc;
      bf16x8 Wh = *(const bf16x8*)(TtL + col * 128 + ((u ^ (col & 7)) << 4));
      bf16x8 Wl2 = *(const bf16x8*)(WinL + col * 128 + ((u ^ (col & 7)) << 4));
      accY[nb] = __builtin_amdgcn_mfma_f32_16x16x32_bf16(Ah, Wh, accY[nb], 0, 0, 0);
      accY[nb] = __builtin_amdgcn_mfma_f32_16x16x32_bf16(Al, Wh, accY[nb], 0, 0, 0);
      accY[nb] = __builtin_amdgcn_mfma_f32_16x16x32_bf16(Ah, Wl2, accY[nb], 0, 0, 0);
    }
  }

  // ---- epilogue: +D*u, GELU, pack to LDS (reuse Bst as u16 [c][i]) ----
  float dsk = Dsk[layer * H_ + hh];
  unsigned short* Yl = (unsigned short*)BstF;
#pragma unroll
  for (int nb = 0; nb < 4; ++nb) {
#pragma unroll
    for (int reg = 0; reg < 4; ++reg) {
      int c = w * 16 + rg * 4 + reg;
      int i = nb * 16 + lc;
      unsigned short ub = *(unsigned short*)(
          Ul + c * 128 + (((i >> 3) ^ (c & 7)) << 4) + (i & 7) * 2);
      float yv = fmaf(dsk, bf2f(ub), accY[nb][reg]);
      float ge = 0.5f * yv * (1.f + erff(yv * 0.70710678118f));
      Yl[c * 64 + i] = f2bf(ge);
    }
  }
  __syncthreads();
  unsigned short* Gr = G + ((size_t)(b * H_ + hh)) * LSEQ;
#pragma unroll
  for (int it = 0; it < 2; ++it) {
    int idx = tid + (it << 8);
    *(uint4*)(Gr + idx * 8) = ((uint4*)Yl)[idx];
  }
}

// ---------------------------------------------------------------------------
// GLU via bf16 MFMA + fused residual + LayerNorm (unchanged from round 2)
// ---------------------------------------------------------------------------
__global__ __launch_bounds__(512, 4) void k_glu(
    const unsigned short* __restrict__ Wb, const unsigned short* __restrict__ G,
    float* __restrict__ h, const float* __restrict__ gb,
    const float* __restrict__ lng, const float* __restrict__ lnb, int layer)
{
  extern __shared__ char smem[];
  char* WlB = smem;
  char* GlB = smem + 65536;
  float2* Red = (float2*)(smem + 65536 + 8192);

  int tid = threadIdx.x;
  int w = tid >> 6, lane = tid & 63;
  int b  = blockIdx.x >> 6;
  int l0 = (blockIdx.x & 63) << 6;
  int rgrp = lane >> 4, lc = lane & 15;

  f32x4 acc[4][4];
#pragma unroll
  for (int m = 0; m < 4; ++m)
#pragma unroll
    for (int n = 0; n < 4; ++n) acc[m][n] = (f32x4){0.f, 0.f, 0.f, 0.f};

  const unsigned short* wsrc = Wb + (size_t)(layer * 4) * 512 * 64;

  for (int kc4 = 0; kc4 < 4; ++kc4) {
    if (kc4) __syncthreads();
    const unsigned short* wc = wsrc + (size_t)kc4 * 512 * 64;
#pragma unroll
    for (int i = 0; i < 8; ++i) {
      int off = w * 8192 + i * 1024 + lane * 16;
      uint4 v = *(const uint4*)((const char*)wc + off);
      *(uint4*)(WlB + off) = v;
    }
    {
      int col = lane;
      int kc = kc4 * 64;
      size_t base = (size_t)(b * H_ + kc + w * 8) * LSEQ + l0 + col;
      unsigned v0 = G[base];
      unsigned v1 = G[base + (size_t)1 * LSEQ];
      unsigned v2 = G[base + (size_t)2 * LSEQ];
      unsigned v3 = G[base + (size_t)3 * LSEQ];
      unsigned v4 = G[base + (size_t)4 * LSEQ];
      unsigned v5 = G[base + (size_t)5 * LSEQ];
      unsigned v6 = G[base + (size_t)6 * LSEQ];
      unsigned v7 = G[base + (size_t)7 * LSEQ];
      unsigned pk0 = v0 | (v1 << 16), pk1 = v2 | (v3 << 16);
      unsigned pk2 = v4 | (v5 << 16), pk3 = v6 | (v7 << 16);
      *(uint4*)(GlB + col * 128 + ((w ^ (col & 7)) << 4)) =
          make_uint4(pk0, pk1, pk2, pk3);
    }
    __syncthreads();
#pragma unroll
    for (int ks = 0; ks < 2; ++ks) {
      int u = ks * 4 + rgrp;
      bf16x8 af[4], bff[4];
#pragma unroll
      for (int m = 0; m < 4; ++m) {
        int grow = ((m < 2) ? (w * 32 + m * 16) : (256 + w * 32 + (m - 2) * 16)) + lc;
        af[m] = *(const bf16x8*)(WlB + grow * 128 + ((u ^ (grow & 7)) << 4));
      }
#pragma unroll
      for (int n = 0; n < 4; ++n) {
        int gcol = n * 16 + lc;
        bff[n] = *(const bf16x8*)(GlB + gcol * 128 + ((u ^ (gcol & 7)) << 4));
      }
#pragma unroll
      for (int m = 0; m < 4; ++m)
#pragma unroll
        for (int n = 0; n < 4; ++n)
          acc[m][n] = __builtin_amdgcn_mfma_f32_16x16x32_bf16(
              af[m], bff[n], acc[m][n], 0, 0, 0);
    }
  }

  const float* gbL = gb + layer * 2 * H_;
  float out[2][4][4];
  float s[4], ss[4];
#pragma unroll
  for (int n = 0; n < 4; ++n) { s[n] = 0.f; ss[n] = 0.f; }
#pragma unroll
  for (int mA = 0; mA < 2; ++mA) {
#pragma unroll
    for (int reg = 0; reg < 4; ++reg) {
      int ch = w * 32 + mA * 16 + rgrp * 4 + reg;
      float ba = gbL[ch], bg = gbL[ch + H_];
#pragma unroll
      for (int n = 0; n < 4; ++n) {
        int col = n * 16 + lc;
        size_t off = (size_t)(b * H_ + ch) * LSEQ + l0 + col;
        float a = acc[mA][n][reg] + ba;
        float gv = acc[mA + 2][n][reg] + bg;
        float sg = 1.f / (1.f + expf(-gv));
        float o = fmaf(a, sg, h[off]);
        out[mA][n][reg] = o;
        s[n] += o; ss[n] = fmaf(o, o, ss[n]);
      }
    }
  }
#pragma unroll
  for (int n = 0; n < 4; ++n) {
    s[n]  += __shfl_xor(s[n], 16);  s[n]  += __shfl_xor(s[n], 32);
    ss[n] += __shfl_xor(ss[n], 16); ss[n] += __shfl_xor(ss[n], 32);
  }
  if (lane < 16) {
#pragma unroll
    for (int n = 0; n < 4; ++n)
      Red[w * 64 + n * 16 + lane] = make_float2(s[n], ss[n]);
  }
  __syncthreads();
  float mu[4], rs[4];
#pragma unroll
  for (int n = 0; n < 4; ++n) {
    int col = n * 16 + lc;
    float ts = 0.f, tss = 0.f;
#pragma unroll
    for (int ww = 0; ww < 8; ++ww) {
      float2 v = Red[ww * 64 + col];
      ts += v.x; tss += v.y;
    }
    mu[n] = ts * (1.f / H_);
    rs[n] = rsqrtf(tss * (1.f / H_) - mu[n] * mu[n] + LN_EPSF);
  }
#pragma unroll
  for (int mA = 0; mA < 2; ++mA) {
#pragma unroll
    for (int reg = 0; reg < 4; ++reg) {
      int ch = w * 32 + mA * 16 + rgrp * 4 + reg;
      float lg = lng[layer * H_ + ch], lb = lnb[layer * H_ + ch];
#pragma unroll
      for (int n = 0; n < 4; ++n) {
        int col = n * 16 + lc;
        size_t off = (size_t)(b * H_ + ch) * LSEQ + l0 + col;
        h[off] = (out[mA][n][reg] - mu[n]) * rs[n] * lg + lb;
      }
    }
  }
}

// ---------------------------------------------------------------------------
// Mean-pool, decode, softmax (unchanged)
// ---------------------------------------------------------------------------
__global__ __launch_bounds__(256) void k_final(
    const float* __restrict__ h, const float* __restrict__ dw,
    const float* __restrict__ db, float* __restrict__ out)
{
  __shared__ float P[H_];
  __shared__ float Z[2];
  int b = blockIdx.x, tid = threadIdx.x;
  const float4* row = (const float4*)(h + ((size_t)(b * H_ + tid)) * LSEQ);
  float a0 = 0, a1 = 0, a2 = 0, a3 = 0;
  for (int t = 0; t < LSEQ / 4; ++t) {
    float4 v = row[t];
    a0 += v.x; a1 += v.y; a2 += v.z; a3 += v.w;
  }
  P[tid] = (a0 + a1 + a2 + a3) * (1.f / LSEQ);
  __syncthreads();
  if (tid < 2) {
    float z = db[tid];
    for (int k = 0; k < H_; ++k) z = fmaf(P[k], dw[k * DOUT + tid], z);
    Z[tid] = z;
  }
  __syncthreads();
  if (tid == 0) {
    float m = fmaxf(Z[0], Z[1]);
    float e0 = expf(Z[0] - m), e1 = expf(Z[1] - m);
    float inv = 1.f / (e0 + e1);
    out[b * 2 + 0] = e0 * inv;
    out[b * 2 + 1] = e1 * inv;
  }
}

// ---------------------------------------------------------------------------
extern "C" void kernel_launch(void* const* d_in, const int* in_sizes, int n_in,
                              void* d_out, int out_size, void* d_ws, size_t ws_size,
                              hipStream_t stream) {
  (void)in_sizes; (void)n_in; (void)out_size; (void)ws_size;
  const float* x      = (const float*)d_in[0];
  const float* enc_w  = (const float*)d_in[1];
  const float* enc_b  = (const float*)d_in[2];
  const float* log_dt = (const float*)d_in[3];
  const float* Cri    = (const float*)d_in[4];
  const float* lAr    = (const float*)d_in[5];
  const float* Aim    = (const float*)d_in[6];
  const float* Dsk    = (const float*)d_in[7];
  const float* glu_w  = (const float*)d_in[8];
  const float* glu_b  = (const float*)d_in[9];
  const float* ln_g   = (const float*)d_in[10];
  const float* ln_b   = (const float*)d_in[11];
  const float* dec_w  = (const float*)d_in[12];
  const float* dec_b  = (const float*)d_in[13];
  float* out = (float*)d_out;

  float* h = (float*)d_ws;                                   // 128 MB
  unsigned short* G   = (unsigned short*)(h + (size_t)B_ * H_ * LSEQ);  // 64 MB
  unsigned short* Wb  = G + (size_t)B_ * H_ * LSEQ;          // 1 MB
  unsigned short* TtG = Wb + 524288;                         // 8 MB
  unsigned short* WinG = TtG + 4194304;                      // 8 MB
  unsigned short* WhiG = WinG + 4194304;                     // 8 MB
  unsigned short* WloG = WhiG + 4194304;                     // 8 MB

  k_wconv<<<256, 256, 0, stream>>>(glu_w, Wb);
  k_prep<<<NL_ * H_, 64, 0, stream>>>(log_dt, Cri, lAr, Aim, TtG, WinG, WhiG, WloG);
  k_encoder<<<B_ * (LSEQ / 32), 256, 0, stream>>>(x, enc_w, enc_b, h);
  for (int i = 0; i < NL_; ++i) {
    k_chunk<<<H_ * B_, 256, 0, stream>>>(h, G, TtG, WinG, WhiG, WloG,
                                         log_dt, lAr, Aim, Dsk, i);
    k_glu<<<B_ * (LSEQ / 64), 512, 77824, stream>>>(Wb, G, h, glu_b, ln_g, ln_b, i);
  }
  k_final<<<B_, 256, 0, stream>>>(h, dec_w, dec_b, out);
}

// Round 6
// 1133.829 us; speedup vs baseline: 3.2065x; 1.1566x over previous
//
#include <hip/hip_runtime.h>
#include <math.h>

#define B_    32
#define DIN   64
#define LSEQ  4096
#define H_    256
#define N2_   32
#define NL_   4
#define DOUT  2
#define LN_EPSF 1e-5f

typedef __bf16 bf16x8 __attribute__((ext_vector_type(8)));
typedef float  f32x4  __attribute__((ext_vector_type(4)));

__device__ inline unsigned short f2bf(float f) {
  unsigned u = __builtin_bit_cast(unsigned, f);
  u += 0x7FFFu + ((u >> 16) & 1u);
  return (unsigned short)(u >> 16);
}
__device__ inline float bf2f(unsigned short u) {
  return __builtin_bit_cast(float, ((unsigned)u) << 16);
}

// ZOH discretization params for mode n of (layer, hh)
__device__ inline void mode_params(const float* log_dt, const float* Cri,
                                   const float* lAr, const float* Aim,
                                   int layer, int hh, int n, float dt,
                                   float& dr, float& di, float& ctr, float& cti) {
  int idx = (layer * H_ + hh) * N2_ + n;
  float Are = -expf(lAr[idx]);
  float Aimv = Aim[idx];
  dr = Are * dt; di = Aimv * dt;
  float er = expf(dr), sn, cs;
  sincosf(di, &sn, &cs);
  float arr = er * cs, aii = er * sn;
  float nr = arr - 1.f, ni = aii;
  float inv = 1.f / (Are * Are + Aimv * Aimv);
  float qr = (nr * Are + ni * Aimv) * inv;
  float qi = (ni * Are - nr * Aimv) * inv;
  float Cr = Cri[2 * idx], Ci = Cri[2 * idx + 1];
  ctr = 2.f * (Cr * qr - Ci * qi);
  cti = 2.f * (Cr * qi + Ci * qr);
}

// ---------------------------------------------------------------------------
// k_prep: per (layer,h) build pre-swizzled bf16 images (64x64 each):
//  Tt[i][t]   = k[i-t] (i>=t else 0), k[d] = Re(sum_n ct_n a_n^d)
//  Win[r][t]  = Re/Im(a_n^(63-t)), r=2n(+1)
//  Whi/Wlo[i][r] = hi/lo bf16 of M[i][r]: M[i][2n]=Re(ct a^(i+1)), [2n+1]=-Im(..)
// Element (row,kk) stored at row*64 + ((kk>>3)^(row&7))*8 + (kk&7)  (u16).
// ---------------------------------------------------------------------------
__global__ __launch_bounds__(64) void k_prep(
    const float* __restrict__ log_dt, const float* __restrict__ Cri,
    const float* __restrict__ lAr, const float* __restrict__ Aim,
    unsigned short* __restrict__ TtG, unsigned short* __restrict__ WinG,
    unsigned short* __restrict__ WhiG, unsigned short* __restrict__ WloG)
{
  int bid = blockIdx.x;
  int layer = bid >> 8, hh = bid & 255;
  int lane = threadIdx.x;
  __shared__ float Kf[64];
  float dt = expf(log_dt[layer * H_ + hh]);

  float kd = 0.f;
  for (int n = 0; n < N2_; ++n) {
    float dr, di, ctr, cti;
    mode_params(log_dt, Cri, lAr, Aim, layer, hh, n, dt, dr, di, ctr, cti);
    float er = expf(dr * (float)lane), sn, cs;
    sincosf(di * (float)lane, &sn, &cs);
    kd += ctr * (er * cs) - cti * (er * sn);
  }
  Kf[lane] = kd;
  __syncthreads();

  size_t base = (size_t)bid * 4096;
  for (int t = 0; t < 64; ++t) {
    float v = (t <= lane) ? Kf[lane - t] : 0.f;
    TtG[base + lane * 64 + (((t >> 3) ^ (lane & 7)) << 3) + (t & 7)] = f2bf(v);
  }
  {
    int n = lane >> 1, im = lane & 1;
    float dr, di, ctr, cti;
    mode_params(log_dt, Cri, lAr, Aim, layer, hh, n, dt, dr, di, ctr, cti);
    for (int t = 0; t < 64; ++t) {
      float e = (float)(63 - t);
      float er = expf(dr * e), sn, cs;
      sincosf(di * e, &sn, &cs);
      float v = im ? (er * sn) : (er * cs);
      WinG[base + lane * 64 + (((t >> 3) ^ (lane & 7)) << 3) + (t & 7)] = f2bf(v);
    }
  }
  for (int r = 0; r < 64; ++r) {
    int n = r >> 1;
    float dr, di, ctr, cti;
    mode_params(log_dt, Cri, lAr, Aim, layer, hh, n, dt, dr, di, ctr, cti);
    float e = (float)(lane + 1);
    float er = expf(dr * e), sn, cs;
    sincosf(di * e, &sn, &cs);
    float wre = ctr * (er * cs) - cti * (er * sn);
    float wim = ctr * (er * sn) + cti * (er * cs);
    float v = (r & 1) ? -wim : wre;
    unsigned short hi = f2bf(v);
    float lo = v - bf2f(hi);
    size_t off = base + lane * 64 + (((r >> 3) ^ (lane & 7)) << 3) + (r & 7);
    WhiG[off] = hi;
    WloG[off] = f2bf(lo);
  }
}

// ---------------------------------------------------------------------------
// k_wconv: glu_w fp32 -> bf16 pre-swizzled (unchanged)
// ---------------------------------------------------------------------------
__global__ __launch_bounds__(256) void k_wconv(
    const float* __restrict__ gw, unsigned short* __restrict__ wb)
{
  int t = blockIdx.x * 256 + threadIdx.x;
  int uu = t & 7;
  int r  = (t >> 3) & 511;
  int l4 = t >> 12;
  int layer = l4 >> 2, kc4 = l4 & 3;
  int ksrc = kc4 * 64 + ((uu ^ (r & 7)) << 3);
  const float* src = gw + ((size_t)(layer * 512 + r)) * H_ + ksrc;
  unsigned short* dst = wb + (size_t)t * 8;
#pragma unroll
  for (int j = 0; j < 8; ++j) dst[j] = f2bf(src[j]);
}

// ---------------------------------------------------------------------------
// Encoder (unchanged)
// ---------------------------------------------------------------------------
__global__ __launch_bounds__(256) void k_encoder(
    const float* __restrict__ x, const float* __restrict__ ew,
    const float* __restrict__ eb, float* __restrict__ h)
{
  __shared__ __align__(16) float Wl[32][256];
  __shared__ __align__(16) float Xl[32][32];
  int tid = threadIdx.x;
  int blk = blockIdx.x;
  int b  = blk >> 7;
  int l0 = (blk & 127) << 5;
  int ty = tid >> 3;
  int tx = tid & 7;
  float acc[8][4];
#pragma unroll
  for (int i = 0; i < 8; ++i)
#pragma unroll
    for (int j = 0; j < 4; ++j) acc[i][j] = 0.f;

  for (int kc = 0; kc < DIN; kc += 32) {
    const float4* ew4 = (const float4*)(ew + kc * H_);
#pragma unroll
    for (int it = 0; it < 8; ++it) {
      int idx = tid + (it << 8);
      ((float4*)&Wl[0][0])[idx] = ew4[idx];
    }
    {
      int c = tid >> 3, p = (tid & 7) << 2;
      *(float4*)&Xl[c][p] =
          *(const float4*)(x + ((size_t)(b * DIN + kc + c)) * LSEQ + l0 + p);
    }
    __syncthreads();
#pragma unroll
    for (int k = 0; k < 32; ++k) {
      float4 w0 = *(float4*)&Wl[k][ty * 8];
      float4 w1 = *(float4*)&Wl[k][ty * 8 + 4];
      float4 xv = *(float4*)&Xl[k][tx * 4];
      float wvv[8] = {w0.x, w0.y, w0.z, w0.w, w1.x, w1.y, w1.z, w1.w};
      float xs[4]  = {xv.x, xv.y, xv.z, xv.w};
#pragma unroll
      for (int i = 0; i < 8; ++i)
#pragma unroll
        for (int j = 0; j < 4; ++j) acc[i][j] = fmaf(wvv[i], xs[j], acc[i][j]);
    }
    __syncthreads();
  }
#pragma unroll
  for (int i = 0; i < 8; ++i) {
    int d = ty * 8 + i;
    float bia = eb[d];
    float4 o = make_float4(acc[i][0] + bia, acc[i][1] + bia,
                           acc[i][2] + bia, acc[i][3] + bia);
    *(float4*)(h + ((size_t)(b * H_ + d)) * LSEQ + l0 + tx * 4) = o;
  }
}

// ---------------------------------------------------------------------------
// k_chunk v2: MFMA chunked S4D scan + GELU, 40KB LDS (4 blocks/CU),
// wave-parallel Hillis-Steele chunk scan in registers.
//  LDS: Ul 8KB | TtL 8KB (Tt -> Whi) | WinL 8KB (Win -> Wlo)
//       SS 16KB (BstT f32 [r][c] xor-swz -> Shi 8KB + Slo 8KB -> Yl 8KB)
// ---------------------------------------------------------------------------
__global__ __launch_bounds__(256, 4) void k_chunk(
    const float* __restrict__ hin, unsigned short* __restrict__ G,
    const unsigned short* __restrict__ TtG, const unsigned short* __restrict__ WinG,
    const unsigned short* __restrict__ WhiG, const unsigned short* __restrict__ WloG,
    const float* __restrict__ log_dt, const float* __restrict__ lAr,
    const float* __restrict__ Aim, const float* __restrict__ Dsk, int layer)
{
  __shared__ __align__(16) char smem[40960];
  char* Ul    = smem;                      // 8KB bf16 [c][t] swz
  char* TtL   = smem + 8192;               // 8KB: Tt -> Whi
  char* WinL  = smem + 16384;              // 8KB: Win -> Wlo
  float* BstT = (float*)(smem + 24576);    // 16KB f32 [r][c^((r&7)<<2)]
  char* ShiL  = smem + 24576;              // 8KB (after scan)
  char* SloL  = smem + 32768;              // 8KB

  int tid = threadIdx.x;
  int w = tid >> 6, lane = tid & 63;
  int rg = lane >> 4, lc = lane & 15;
  int bid = blockIdx.x;
  int hh = bid >> 5, b = bid & 31;
  size_t wbase = ((size_t)(layer * H_ + hh)) * 4096;
  const float* Urow = hin + ((size_t)(b * H_ + hh)) * LSEQ;

  // ---- stage U (fp32->bf16, swizzled) + Tt + Win (linear) ----
#pragma unroll
  for (int it = 0; it < 2; ++it) {
    int idx = tid + (it << 8);          // 0..511
    int c = idx >> 3, uu = idx & 7;
    const float* src = Urow + c * 64 + uu * 8;
    float4 u0 = *(const float4*)(src);
    float4 u1 = *(const float4*)(src + 4);
    unsigned p0 = f2bf(u0.x) | ((unsigned)f2bf(u0.y) << 16);
    unsigned p1 = f2bf(u0.z) | ((unsigned)f2bf(u0.w) << 16);
    unsigned p2 = f2bf(u1.x) | ((unsigned)f2bf(u1.y) << 16);
    unsigned p3 = f2bf(u1.z) | ((unsigned)f2bf(u1.w) << 16);
    *(uint4*)(Ul + c * 128 + ((uu ^ (c & 7)) << 4)) = make_uint4(p0, p1, p2, p3);
    ((uint4*)TtL)[idx]  = ((const uint4*)(TtG + wbase))[idx];
    ((uint4*)WinL)[idx] = ((const uint4*)(WinG + wbase))[idx];
  }
  __syncthreads();

  // ---- phase 1 GEMMs: Yloc = U@Tt', Bst = U@Win' ----
  f32x4 accY[4], accB[4];
#pragma unroll
  for (int nb = 0; nb < 4; ++nb) {
    accY[nb] = (f32x4){0.f, 0.f, 0.f, 0.f};
    accB[nb] = (f32x4){0.f, 0.f, 0.f, 0.f};
  }
#pragma unroll
  for (int ks = 0; ks < 2; ++ks) {
    int ca = w * 16 + lc;
    int u = ks * 4 + rg;
    bf16x8 A = *(const bf16x8*)(Ul + ca * 128 + ((u ^ (ca & 7)) << 4));
#pragma unroll
    for (int nb = 0; nb < 4; ++nb) {
      int col = nb * 16 + lc;
      bf16x8 Bt = *(const bf16x8*)(TtL + col * 128 + ((u ^ (col & 7)) << 4));
      bf16x8 Bw = *(const bf16x8*)(WinL + col * 128 + ((u ^ (col & 7)) << 4));
      accY[nb] = __builtin_amdgcn_mfma_f32_16x16x32_bf16(A, Bt, accY[nb], 0, 0, 0);
      accB[nb] = __builtin_amdgcn_mfma_f32_16x16x32_bf16(A, Bw, accB[nb], 0, 0, 0);
    }
  }
  // accB -> BstT[r][c] (xor-swizzled column so scan reads are conflict-free)
#pragma unroll
  for (int nb = 0; nb < 4; ++nb)
#pragma unroll
    for (int reg = 0; reg < 4; ++reg) {
      int r = nb * 16 + lc;
      int cc = w * 16 + rg * 4 + reg;
      BstT[r * 64 + (cc ^ ((r & 7) << 2))] = accB[nb][reg];
    }
  __syncthreads();

  // ---- phase 2: wave-parallel chunk scan (wave w: modes 8w..8w+7, lane=c) ----
  float Sr[8], Si[8], Mr[8], Mi[8];
  int c = lane;
  {
    int pbase = (layer * H_ + hh) * N2_ + w * 8;
    float dtv = expf(log_dt[layer * H_ + hh]);
#pragma unroll
    for (int q = 0; q < 8; ++q) {
      float dr = -expf(lAr[pbase + q]) * dtv;
      float di = Aim[pbase + q] * dtv;
      float er = expf(dr * 64.f), sn, cs;
      sincosf(di * 64.f, &sn, &cs);
      Mr[q] = er * cs; Mi[q] = er * sn;         // a^64
      int r0 = (w * 8 + q) * 2, r1 = r0 + 1;
      Sr[q] = BstT[r0 * 64 + (c ^ ((r0 & 7) << 2))];
      Si[q] = BstT[r1 * 64 + (c ^ ((r1 & 7) << 2))];
    }
  }
  // issue Whi/Wlo global loads early (latency hidden under scan)
  uint4 wst[4];
#pragma unroll
  for (int i = 0; i < 2; ++i) {
    wst[i]     = ((const uint4*)(WhiG + wbase))[tid + (i << 8)];
    wst[i + 2] = ((const uint4*)(WloG + wbase))[tid + (i << 8)];
  }
  __syncthreads();   // all BstT reads complete before Shi/Slo overwrite

  // Hillis-Steele inclusive scan over 64 chunks; multiplier squared per step
#pragma unroll
  for (int dd = 0; dd < 6; ++dd) {
    int d = 1 << dd;
#pragma unroll
    for (int q = 0; q < 8; ++q) {
      float pr = __shfl_up(Sr[q], (unsigned)d);
      float pi = __shfl_up(Si[q], (unsigned)d);
      if (lane >= d) {
        Sr[q] = fmaf(Mr[q], pr, fmaf(-Mi[q], pi, Sr[q]));
        Si[q] = fmaf(Mr[q], pi, fmaf(Mi[q], pr, Si[q]));
      }
      if (dd < 5) {
        float t = fmaf(Mr[q], Mr[q], -Mi[q] * Mi[q]);
        Mi[q] = 2.f * Mr[q] * Mi[q];
        Mr[q] = t;
      }
    }
  }
  // exclusive shift: state entering chunk c
#pragma unroll
  for (int q = 0; q < 8; ++q) {
    float pr = __shfl_up(Sr[q], 1u);
    float pi = __shfl_up(Si[q], 1u);
    Sr[q] = (lane == 0) ? 0.f : pr;
    Si[q] = (lane == 0) ? 0.f : pi;
  }
  // write S hi/lo (phase3 fragment layout) + stage Whi/Wlo into LDS
#pragma unroll
  for (int q = 0; q < 8; ++q) {
    int n = w * 8 + q;
    unsigned short hr = f2bf(Sr[q]), hi_ = f2bf(Si[q]);
    unsigned hiw = (unsigned)hr | ((unsigned)hi_ << 16);
    unsigned low = (unsigned)f2bf(Sr[q] - bf2f(hr)) |
                   ((unsigned)f2bf(Si[q] - bf2f(hi_)) << 16);
    int boff = c * 128 + (((n >> 2) ^ (c & 7)) << 4) + (((2 * n) & 7) << 1);
    *(unsigned*)(ShiL + boff) = hiw;
    *(unsigned*)(SloL + boff) = low;
  }
#pragma unroll
  for (int i = 0; i < 2; ++i) {
    ((uint4*)TtL)[tid + (i << 8)]  = wst[i];
    ((uint4*)WinL)[tid + (i << 8)] = wst[i + 2];
  }
  __syncthreads();

  // ---- phase 3: correction GEMMs ----
#pragma unroll
  for (int ks = 0; ks < 2; ++ks) {
    int ca = w * 16 + lc;
    int u = ks * 4 + rg;
    bf16x8 Ah = *(const bf16x8*)(ShiL + ca * 128 + ((u ^ (ca & 7)) << 4));
    bf16x8 Al = *(const bf16x8*)(SloL + ca * 128 + ((u ^ (ca & 7)) << 4));
#pragma unroll
    for (int nb = 0; nb < 4; ++nb) {
      int col = nb * 16 + lc;
      bf16x8 Wh = *(const bf16x8*)(TtL + col * 128 + ((u ^ (col & 7)) << 4));
      bf16x8 Wl2 = *(const bf16x8*)(WinL + col * 128 + ((u ^ (col & 7)) << 4));
      accY[nb] = __builtin_amdgcn_mfma_f32_16x16x32_bf16(Ah, Wh, accY[nb], 0, 0, 0);
      accY[nb] = __builtin_amdgcn_mfma_f32_16x16x32_bf16(Al, Wh, accY[nb], 0, 0, 0);
      accY[nb] = __builtin_amdgcn_mfma_f32_16x16x32_bf16(Ah, Wl2, accY[nb], 0, 0, 0);
    }
  }
  __syncthreads();   // phase3 LDS reads done before Yl overwrites Shi

  // ---- epilogue: +D*u, GELU, pack to LDS, coalesced global write ----
  float dsk = Dsk[layer * H_ + hh];
  unsigned short* Yl = (unsigned short*)(smem + 24576);
#pragma unroll
  for (int nb = 0; nb < 4; ++nb) {
#pragma unroll
    for (int reg = 0; reg < 4; ++reg) {
      int cc = w * 16 + rg * 4 + reg;
      int i = nb * 16 + lc;
      unsigned short ub = *(unsigned short*)(
          Ul + cc * 128 + (((i >> 3) ^ (cc & 7)) << 4) + (i & 7) * 2);
      float yv = fmaf(dsk, bf2f(ub), accY[nb][reg]);
      float ge = 0.5f * yv * (1.f + erff(yv * 0.70710678118f));
      Yl[cc * 64 + i] = f2bf(ge);
    }
  }
  __syncthreads();
  unsigned short* Gr = G + ((size_t)(b * H_ + hh)) * LSEQ;
#pragma unroll
  for (int it = 0; it < 2; ++it) {
    int idx = tid + (it << 8);
    *(uint4*)(Gr + idx * 8) = ((uint4*)Yl)[idx];
  }
}

// ---------------------------------------------------------------------------
// GLU via bf16 MFMA + fused residual + LayerNorm (unchanged)
// ---------------------------------------------------------------------------
__global__ __launch_bounds__(512, 4) void k_glu(
    const unsigned short* __restrict__ Wb, const unsigned short* __restrict__ G,
    float* __restrict__ h, const float* __restrict__ gb,
    const float* __restrict__ lng, const float* __restrict__ lnb, int layer)
{
  extern __shared__ char smem[];
  char* WlB = smem;
  char* GlB = smem + 65536;
  float2* Red = (float2*)(smem + 65536 + 8192);

  int tid = threadIdx.x;
  int w = tid >> 6, lane = tid & 63;
  int b  = blockIdx.x >> 6;
  int l0 = (blockIdx.x & 63) << 6;
  int rgrp = lane >> 4, lc = lane & 15;

  f32x4 acc[4][4];
#pragma unroll
  for (int m = 0; m < 4; ++m)
#pragma unroll
    for (int n = 0; n < 4; ++n) acc[m][n] = (f32x4){0.f, 0.f, 0.f, 0.f};

  const unsigned short* wsrc = Wb + (size_t)(layer * 4) * 512 * 64;

  for (int kc4 = 0; kc4 < 4; ++kc4) {
    if (kc4) __syncthreads();
    const unsigned short* wc = wsrc + (size_t)kc4 * 512 * 64;
#pragma unroll
    for (int i = 0; i < 8; ++i) {
      int off = w * 8192 + i * 1024 + lane * 16;
      uint4 v = *(const uint4*)((const char*)wc + off);
      *(uint4*)(WlB + off) = v;
    }
    {
      int col = lane;
      int kc = kc4 * 64;
      size_t base = (size_t)(b * H_ + kc + w * 8) * LSEQ + l0 + col;
      unsigned v0 = G[base];
      unsigned v1 = G[base + (size_t)1 * LSEQ];
      unsigned v2 = G[base + (size_t)2 * LSEQ];
      unsigned v3 = G[base + (size_t)3 * LSEQ];
      unsigned v4 = G[base + (size_t)4 * LSEQ];
      unsigned v5 = G[base + (size_t)5 * LSEQ];
      unsigned v6 = G[base + (size_t)6 * LSEQ];
      unsigned v7 = G[base + (size_t)7 * LSEQ];
      unsigned pk0 = v0 | (v1 << 16), pk1 = v2 | (v3 << 16);
      unsigned pk2 = v4 | (v5 << 16), pk3 = v6 | (v7 << 16);
      *(uint4*)(GlB + col * 128 + ((w ^ (col & 7)) << 4)) =
          make_uint4(pk0, pk1, pk2, pk3);
    }
    __syncthreads();
#pragma unroll
    for (int ks = 0; ks < 2; ++ks) {
      int u = ks * 4 + rgrp;
      bf16x8 af[4], bff[4];
#pragma unroll
      for (int m = 0; m < 4; ++m) {
        int grow = ((m < 2) ? (w * 32 + m * 16) : (256 + w * 32 + (m - 2) * 16)) + lc;
        af[m] = *(const bf16x8*)(WlB + grow * 128 + ((u ^ (grow & 7)) << 4));
      }
#pragma unroll
      for (int n = 0; n < 4; ++n) {
        int gcol = n * 16 + lc;
        bff[n] = *(const bf16x8*)(GlB + gcol * 128 + ((u ^ (gcol & 7)) << 4));
      }
#pragma unroll
      for (int m = 0; m < 4; ++m)
#pragma unroll
        for (int n = 0; n < 4; ++n)
          acc[m][n] = __builtin_amdgcn_mfma_f32_16x16x32_bf16(
              af[m], bff[n], acc[m][n], 0, 0, 0);
    }
  }

  const float* gbL = gb + layer * 2 * H_;
  float out[2][4][4];
  float s[4], ss[4];
#pragma unroll
  for (int n = 0; n < 4; ++n) { s[n] = 0.f; ss[n] = 0.f; }
#pragma unroll
  for (int mA = 0; mA < 2; ++mA) {
#pragma unroll
    for (int reg = 0; reg < 4; ++reg) {
      int ch = w * 32 + mA * 16 + rgrp * 4 + reg;
      float ba = gbL[ch], bg = gbL[ch + H_];
#pragma unroll
      for (int n = 0; n < 4; ++n) {
        int col = n * 16 + lc;
        size_t off = (size_t)(b * H_ + ch) * LSEQ + l0 + col;
        float a = acc[mA][n][reg] + ba;
        float gv = acc[mA + 2][n][reg] + bg;
        float sg = 1.f / (1.f + expf(-gv));
        float o = fmaf(a, sg, h[off]);
        out[mA][n][reg] = o;
        s[n] += o; ss[n] = fmaf(o, o, ss[n]);
      }
    }
  }
#pragma unroll
  for (int n = 0; n < 4; ++n) {
    s[n]  += __shfl_xor(s[n], 16);  s[n]  += __shfl_xor(s[n], 32);
    ss[n] += __shfl_xor(ss[n], 16); ss[n] += __shfl_xor(ss[n], 32);
  }
  if (lane < 16) {
#pragma unroll
    for (int n = 0; n < 4; ++n)
      Red[w * 64 + n * 16 + lane] = make_float2(s[n], ss[n]);
  }
  __syncthreads();
  float mu[4], rs[4];
#pragma unroll
  for (int n = 0; n < 4; ++n) {
    int col = n * 16 + lc;
    float ts = 0.f, tss = 0.f;
#pragma unroll
    for (int ww = 0; ww < 8; ++ww) {
      float2 v = Red[ww * 64 + col];
      ts += v.x; tss += v.y;
    }
    mu[n] = ts * (1.f / H_);
    rs[n] = rsqrtf(tss * (1.f / H_) - mu[n] * mu[n] + LN_EPSF);
  }
#pragma unroll
  for (int mA = 0; mA < 2; ++mA) {
#pragma unroll
    for (int reg = 0; reg < 4; ++reg) {
      int ch = w * 32 + mA * 16 + rgrp * 4 + reg;
      float lg = lng[layer * H_ + ch], lb = lnb[layer * H_ + ch];
#pragma unroll
      for (int n = 0; n < 4; ++n) {
        int col = n * 16 + lc;
        size_t off = (size_t)(b * H_ + ch) * LSEQ + l0 + col;
        h[off] = (out[mA][n][reg] - mu[n]) * rs[n] * lg + lb;
      }
    }
  }
}

// ---------------------------------------------------------------------------
// Mean-pool, decode, softmax (unchanged)
// ---------------------------------------------------------------------------
__global__ __launch_bounds__(256) void k_final(
    const float* __restrict__ h, const float* __restrict__ dw,
    const float* __restrict__ db, float* __restrict__ out)
{
  __shared__ float P[H_];
  __shared__ float Z[2];
  int b = blockIdx.x, tid = threadIdx.x;
  const float4* row = (const float4*)(h + ((size_t)(b * H_ + tid)) * LSEQ);
  float a0 = 0, a1 = 0, a2 = 0, a3 = 0;
  for (int t = 0; t < LSEQ / 4; ++t) {
    float4 v = row[t];
    a0 += v.x; a1 += v.y; a2 += v.z; a3 += v.w;
  }
  P[tid] = (a0 + a1 + a2 + a3) * (1.f / LSEQ);
  __syncthreads();
  if (tid < 2) {
    float z = db[tid];
    for (int k = 0; k < H_; ++k) z = fmaf(P[k], dw[k * DOUT + tid], z);
    Z[tid] = z;
  }
  __syncthreads();
  if (tid == 0) {
    float m = fmaxf(Z[0], Z[1]);
    float e0 = expf(Z[0] - m), e1 = expf(Z[1] - m);
    float inv = 1.f / (e0 + e1);
    out[b * 2 + 0] = e0 * inv;
    out[b * 2 + 1] = e1 * inv;
  }
}

// ---------------------------------------------------------------------------
extern "C" void kernel_launch(void* const* d_in, const int* in_sizes, int n_in,
                              void* d_out, int out_size, void* d_ws, size_t ws_size,
                              hipStream_t stream) {
  (void)in_sizes; (void)n_in; (void)out_size; (void)ws_size;
  const float* x      = (const float*)d_in[0];
  const float* enc_w  = (const float*)d_in[1];
  const float* enc_b  = (const float*)d_in[2];
  const float* log_dt = (const float*)d_in[3];
  const float* Cri    = (const float*)d_in[4];
  const float* lAr    = (const float*)d_in[5];
  const float* Aim    = (const float*)d_in[6];
  const float* Dsk    = (const float*)d_in[7];
  const float* glu_w  = (const float*)d_in[8];
  const float* glu_b  = (const float*)d_in[9];
  const float* ln_g   = (const float*)d_in[10];
  const float* ln_b   = (const float*)d_in[11];
  const float* dec_w  = (const float*)d_in[12];
  const float* dec_b  = (const float*)d_in[13];
  float* out = (float*)d_out;

  float* h = (float*)d_ws;                                   // 128 MB
  unsigned short* G   = (unsigned short*)(h + (size_t)B_ * H_ * LSEQ);  // 64 MB
  unsigned short* Wb  = G + (size_t)B_ * H_ * LSEQ;          // 1 MB
  unsigned short* TtG = Wb + 524288;                         // 8 MB
  unsigned short* WinG = TtG + 4194304;                      // 8 MB
  unsigned short* WhiG = WinG + 4194304;                     // 8 MB
  unsigned short* WloG = WhiG + 4194304;                     // 8 MB

  k_wconv<<<256, 256, 0, stream>>>(glu_w, Wb);
  k_prep<<<NL_ * H_, 64, 0, stream>>>(log_dt, Cri, lAr, Aim, TtG, WinG, WhiG, WloG);
  k_encoder<<<B_ * (LSEQ / 32), 256, 0, stream>>>(x, enc_w, enc_b, h);
  for (int i = 0; i < NL_; ++i) {
    k_chunk<<<H_ * B_, 256, 0, stream>>>(h, G, TtG, WinG, WhiG, WloG,
                                         log_dt, lAr, Aim, Dsk, i);
    k_glu<<<B_ * (LSEQ / 64), 512, 77824, stream>>>(Wb, G, h, glu_b, ln_g, ln_b, i);
  }
  k_final<<<B_, 256, 0, stream>>>(h, dec_w, dec_b, out);
}

// Round 7
// 1091.409 us; speedup vs baseline: 3.3311x; 1.0389x over previous
//
#include <hip/hip_runtime.h>
#include <math.h>

#define B_    32
#define DIN   64
#define LSEQ  4096
#define H_    256
#define N2_   32
#define NL_   4
#define DOUT  2
#define LN_EPSF 1e-5f

typedef __bf16 bf16x8 __attribute__((ext_vector_type(8)));
typedef float  f32x4  __attribute__((ext_vector_type(4)));

__device__ inline unsigned short f2bf(float f) {
  unsigned u = __builtin_bit_cast(unsigned, f);
  u += 0x7FFFu + ((u >> 16) & 1u);
  return (unsigned short)(u >> 16);
}
__device__ inline float bf2f(unsigned short u) {
  return __builtin_bit_cast(float, ((unsigned)u) << 16);
}

// ZOH discretization params for mode n of (layer, hh)
__device__ inline void mode_params(const float* log_dt, const float* Cri,
                                   const float* lAr, const float* Aim,
                                   int layer, int hh, int n, float dt,
                                   float& dr, float& di, float& ctr, float& cti) {
  int idx = (layer * H_ + hh) * N2_ + n;
  float Are = -expf(lAr[idx]);
  float Aimv = Aim[idx];
  dr = Are * dt; di = Aimv * dt;
  float er = expf(dr), sn, cs;
  sincosf(di, &sn, &cs);
  float arr = er * cs, aii = er * sn;
  float nr = arr - 1.f, ni = aii;
  float inv = 1.f / (Are * Are + Aimv * Aimv);
  float qr = (nr * Are + ni * Aimv) * inv;
  float qi = (ni * Are - nr * Aimv) * inv;
  float Cr = Cri[2 * idx], Ci = Cri[2 * idx + 1];
  ctr = 2.f * (Cr * qr - Ci * qi);
  cti = 2.f * (Cr * qi + Ci * qr);
}

// ---------------------------------------------------------------------------
// k_prep: per (layer,h) build pre-swizzled bf16 images (64x64 each):
//  Tt[i][t]   = k[i-t] (i>=t else 0), k[d] = Re(sum_n ct_n a_n^d)
//  Win[r][t]  = Re/Im(a_n^(63-t)), r=2n(+1)
//  Whi/Wlo[i][r] = hi/lo bf16 of M[i][r]: M[i][2n]=Re(ct a^(i+1)), [2n+1]=-Im(..)
//  AQG[bid*32+n] = a_n^64  (chunk-jump multiplier table for k_chunk's scan)
// Element (row,kk) stored at row*64 + ((kk>>3)^(row&7))*8 + (kk&7)  (u16).
// ---------------------------------------------------------------------------
__global__ __launch_bounds__(64) void k_prep(
    const float* __restrict__ log_dt, const float* __restrict__ Cri,
    const float* __restrict__ lAr, const float* __restrict__ Aim,
    unsigned short* __restrict__ TtG, unsigned short* __restrict__ WinG,
    unsigned short* __restrict__ WhiG, unsigned short* __restrict__ WloG,
    float2* __restrict__ AQG)
{
  int bid = blockIdx.x;
  int layer = bid >> 8, hh = bid & 255;
  int lane = threadIdx.x;
  __shared__ float Kf[64];
  float dt = expf(log_dt[layer * H_ + hh]);

  float kd = 0.f;
  for (int n = 0; n < N2_; ++n) {
    float dr, di, ctr, cti;
    mode_params(log_dt, Cri, lAr, Aim, layer, hh, n, dt, dr, di, ctr, cti);
    float er = expf(dr * (float)lane), sn, cs;
    sincosf(di * (float)lane, &sn, &cs);
    kd += ctr * (er * cs) - cti * (er * sn);
  }
  Kf[lane] = kd;
  // a^64 table
  if (lane < N2_) {
    int idx = (layer * H_ + hh) * N2_ + lane;
    float dr64 = -expf(lAr[idx]) * dt * 64.f;
    float di64 = Aim[idx] * dt * 64.f;
    float er = expf(dr64), sn, cs;
    sincosf(di64, &sn, &cs);
    AQG[bid * N2_ + lane] = make_float2(er * cs, er * sn);
  }
  __syncthreads();

  size_t base = (size_t)bid * 4096;
  for (int t = 0; t < 64; ++t) {
    float v = (t <= lane) ? Kf[lane - t] : 0.f;
    TtG[base + lane * 64 + (((t >> 3) ^ (lane & 7)) << 3) + (t & 7)] = f2bf(v);
  }
  {
    int n = lane >> 1, im = lane & 1;
    float dr, di, ctr, cti;
    mode_params(log_dt, Cri, lAr, Aim, layer, hh, n, dt, dr, di, ctr, cti);
    for (int t = 0; t < 64; ++t) {
      float e = (float)(63 - t);
      float er = expf(dr * e), sn, cs;
      sincosf(di * e, &sn, &cs);
      float v = im ? (er * sn) : (er * cs);
      WinG[base + lane * 64 + (((t >> 3) ^ (lane & 7)) << 3) + (t & 7)] = f2bf(v);
    }
  }
  for (int r = 0; r < 64; ++r) {
    int n = r >> 1;
    float dr, di, ctr, cti;
    mode_params(log_dt, Cri, lAr, Aim, layer, hh, n, dt, dr, di, ctr, cti);
    float e = (float)(lane + 1);
    float er = expf(dr * e), sn, cs;
    sincosf(di * e, &sn, &cs);
    float wre = ctr * (er * cs) - cti * (er * sn);
    float wim = ctr * (er * sn) + cti * (er * cs);
    float v = (r & 1) ? -wim : wre;
    unsigned short hi = f2bf(v);
    float lo = v - bf2f(hi);
    size_t off = base + lane * 64 + (((r >> 3) ^ (lane & 7)) << 3) + (r & 7);
    WhiG[off] = hi;
    WloG[off] = f2bf(lo);
  }
}

// ---------------------------------------------------------------------------
// k_wconv: glu_w fp32 -> bf16 pre-swizzled (unchanged)
// ---------------------------------------------------------------------------
__global__ __launch_bounds__(256) void k_wconv(
    const float* __restrict__ gw, unsigned short* __restrict__ wb)
{
  int t = blockIdx.x * 256 + threadIdx.x;
  int uu = t & 7;
  int r  = (t >> 3) & 511;
  int l4 = t >> 12;
  int layer = l4 >> 2, kc4 = l4 & 3;
  int ksrc = kc4 * 64 + ((uu ^ (r & 7)) << 3);
  const float* src = gw + ((size_t)(layer * 512 + r)) * H_ + ksrc;
  unsigned short* dst = wb + (size_t)t * 8;
#pragma unroll
  for (int j = 0; j < 8; ++j) dst[j] = f2bf(src[j]);
}

// ---------------------------------------------------------------------------
// Encoder (unchanged)
// ---------------------------------------------------------------------------
__global__ __launch_bounds__(256) void k_encoder(
    const float* __restrict__ x, const float* __restrict__ ew,
    const float* __restrict__ eb, float* __restrict__ h)
{
  __shared__ __align__(16) float Wl[32][256];
  __shared__ __align__(16) float Xl[32][32];
  int tid = threadIdx.x;
  int blk = blockIdx.x;
  int b  = blk >> 7;
  int l0 = (blk & 127) << 5;
  int ty = tid >> 3;
  int tx = tid & 7;
  float acc[8][4];
#pragma unroll
  for (int i = 0; i < 8; ++i)
#pragma unroll
    for (int j = 0; j < 4; ++j) acc[i][j] = 0.f;

  for (int kc = 0; kc < DIN; kc += 32) {
    const float4* ew4 = (const float4*)(ew + kc * H_);
#pragma unroll
    for (int it = 0; it < 8; ++it) {
      int idx = tid + (it << 8);
      ((float4*)&Wl[0][0])[idx] = ew4[idx];
    }
    {
      int c = tid >> 3, p = (tid & 7) << 2;
      *(float4*)&Xl[c][p] =
          *(const float4*)(x + ((size_t)(b * DIN + kc + c)) * LSEQ + l0 + p);
    }
    __syncthreads();
#pragma unroll
    for (int k = 0; k < 32; ++k) {
      float4 w0 = *(float4*)&Wl[k][ty * 8];
      float4 w1 = *(float4*)&Wl[k][ty * 8 + 4];
      float4 xv = *(float4*)&Xl[k][tx * 4];
      float wvv[8] = {w0.x, w0.y, w0.z, w0.w, w1.x, w1.y, w1.z, w1.w};
      float xs[4]  = {xv.x, xv.y, xv.z, xv.w};
#pragma unroll
      for (int i = 0; i < 8; ++i)
#pragma unroll
        for (int j = 0; j < 4; ++j) acc[i][j] = fmaf(wvv[i], xs[j], acc[i][j]);
    }
    __syncthreads();
  }
#pragma unroll
  for (int i = 0; i < 8; ++i) {
    int d = ty * 8 + i;
    float bia = eb[d];
    float4 o = make_float4(acc[i][0] + bia, acc[i][1] + bia,
                           acc[i][2] + bia, acc[i][3] + bia);
    *(float4*)(h + ((size_t)(b * H_ + d)) * LSEQ + l0 + tx * 4) = o;
  }
}

// ---------------------------------------------------------------------------
// k_chunk v3: MFMA chunked S4D scan + GELU, 40KB LDS (4 blocks/CU),
// wave-parallel Hillis-Steele chunk scan; a^64 from precomputed table.
//  LDS: Ul 8KB | TtL 8KB (Tt -> Whi) | WinL 8KB (Win -> Wlo)
//       SS 16KB (BstT f32 [r][c] xor-swz -> Shi 8KB + Slo 8KB -> Yl 8KB)
// ---------------------------------------------------------------------------
__global__ __launch_bounds__(256, 4) void k_chunk(
    const float* __restrict__ hin, unsigned short* __restrict__ G,
    const unsigned short* __restrict__ TtG, const unsigned short* __restrict__ WinG,
    const unsigned short* __restrict__ WhiG, const unsigned short* __restrict__ WloG,
    const float2* __restrict__ AQG, const float* __restrict__ Dsk, int layer)
{
  __shared__ __align__(16) char smem[40960];
  char* Ul    = smem;                      // 8KB bf16 [c][t] swz
  char* TtL   = smem + 8192;               // 8KB: Tt -> Whi
  char* WinL  = smem + 16384;              // 8KB: Win -> Wlo
  float* BstT = (float*)(smem + 24576);    // 16KB f32 [r][c^((r&7)<<2)]
  char* ShiL  = smem + 24576;              // 8KB (after scan)
  char* SloL  = smem + 32768;              // 8KB

  int tid = threadIdx.x;
  int w = tid >> 6, lane = tid & 63;
  int rg = lane >> 4, lc = lane & 15;
  int bid = blockIdx.x;
  int hh = bid >> 5, b = bid & 31;
  size_t wbase = ((size_t)(layer * H_ + hh)) * 4096;
  const float* Urow = hin + ((size_t)(b * H_ + hh)) * LSEQ;

  // ---- stage U (fp32->bf16, swizzled) + Tt + Win (linear) ----
#pragma unroll
  for (int it = 0; it < 2; ++it) {
    int idx = tid + (it << 8);          // 0..511
    int c = idx >> 3, uu = idx & 7;
    const float* src = Urow + c * 64 + uu * 8;
    float4 u0 = *(const float4*)(src);
    float4 u1 = *(const float4*)(src + 4);
    unsigned p0 = f2bf(u0.x) | ((unsigned)f2bf(u0.y) << 16);
    unsigned p1 = f2bf(u0.z) | ((unsigned)f2bf(u0.w) << 16);
    unsigned p2 = f2bf(u1.x) | ((unsigned)f2bf(u1.y) << 16);
    unsigned p3 = f2bf(u1.z) | ((unsigned)f2bf(u1.w) << 16);
    *(uint4*)(Ul + c * 128 + ((uu ^ (c & 7)) << 4)) = make_uint4(p0, p1, p2, p3);
    ((uint4*)TtL)[idx]  = ((const uint4*)(TtG + wbase))[idx];
    ((uint4*)WinL)[idx] = ((const uint4*)(WinG + wbase))[idx];
  }
  __syncthreads();

  // ---- phase 1 GEMMs: Yloc = U@Tt', Bst = U@Win' ----
  f32x4 accY[4], accB[4];
#pragma unroll
  for (int nb = 0; nb < 4; ++nb) {
    accY[nb] = (f32x4){0.f, 0.f, 0.f, 0.f};
    accB[nb] = (f32x4){0.f, 0.f, 0.f, 0.f};
  }
#pragma unroll
  for (int ks = 0; ks < 2; ++ks) {
    int ca = w * 16 + lc;
    int u = ks * 4 + rg;
    bf16x8 A = *(const bf16x8*)(Ul + ca * 128 + ((u ^ (ca & 7)) << 4));
#pragma unroll
    for (int nb = 0; nb < 4; ++nb) {
      int col = nb * 16 + lc;
      bf16x8 Bt = *(const bf16x8*)(TtL + col * 128 + ((u ^ (col & 7)) << 4));
      bf16x8 Bw = *(const bf16x8*)(WinL + col * 128 + ((u ^ (col & 7)) << 4));
      accY[nb] = __builtin_amdgcn_mfma_f32_16x16x32_bf16(A, Bt, accY[nb], 0, 0, 0);
      accB[nb] = __builtin_amdgcn_mfma_f32_16x16x32_bf16(A, Bw, accB[nb], 0, 0, 0);
    }
  }
  // accB -> BstT[r][c] (xor-swizzled column so scan reads are conflict-free)
#pragma unroll
  for (int nb = 0; nb < 4; ++nb)
#pragma unroll
    for (int reg = 0; reg < 4; ++reg) {
      int r = nb * 16 + lc;
      int cc = w * 16 + rg * 4 + reg;
      BstT[r * 64 + (cc ^ ((r & 7) << 2))] = accB[nb][reg];
    }
  __syncthreads();

  // ---- phase 2: wave-parallel chunk scan (wave w: modes 8w..8w+7, lane=c) ----
  float Sr[8], Si[8], Mr[8], Mi[8];
  int c = lane;
  {
    const float2* aqb = AQG + (size_t)(layer * H_ + hh) * N2_ + w * 8;
#pragma unroll
    for (int q = 0; q < 8; ++q) {
      float2 aq = aqb[q];                       // a^64 (wave-uniform)
      Mr[q] = aq.x; Mi[q] = aq.y;
      int r0 = (w * 8 + q) * 2, r1 = r0 + 1;
      Sr[q] = BstT[r0 * 64 + (c ^ ((r0 & 7) << 2))];
      Si[q] = BstT[r1 * 64 + (c ^ ((r1 & 7) << 2))];
    }
  }
  // issue Whi/Wlo global loads early (latency hidden under scan)
  uint4 wst[4];
#pragma unroll
  for (int i = 0; i < 2; ++i) {
    wst[i]     = ((const uint4*)(WhiG + wbase))[tid + (i << 8)];
    wst[i + 2] = ((const uint4*)(WloG + wbase))[tid + (i << 8)];
  }
  __syncthreads();   // all BstT reads complete before Shi/Slo overwrite

  // Hillis-Steele inclusive scan over 64 chunks; multiplier squared per step
#pragma unroll
  for (int dd = 0; dd < 6; ++dd) {
    int d = 1 << dd;
#pragma unroll
    for (int q = 0; q < 8; ++q) {
      float pr = __shfl_up(Sr[q], (unsigned)d);
      float pi = __shfl_up(Si[q], (unsigned)d);
      if (lane >= d) {
        Sr[q] = fmaf(Mr[q], pr, fmaf(-Mi[q], pi, Sr[q]));
        Si[q] = fmaf(Mr[q], pi, fmaf(Mi[q], pr, Si[q]));
      }
      if (dd < 5) {
        float t = fmaf(Mr[q], Mr[q], -Mi[q] * Mi[q]);
        Mi[q] = 2.f * Mr[q] * Mi[q];
        Mr[q] = t;
      }
    }
  }
  // exclusive shift: state entering chunk c
#pragma unroll
  for (int q = 0; q < 8; ++q) {
    float pr = __shfl_up(Sr[q], 1u);
    float pi = __shfl_up(Si[q], 1u);
    Sr[q] = (lane == 0) ? 0.f : pr;
    Si[q] = (lane == 0) ? 0.f : pi;
  }
  // write S hi/lo (phase3 fragment layout) + stage Whi/Wlo into LDS
#pragma unroll
  for (int q = 0; q < 8; ++q) {
    int n = w * 8 + q;
    unsigned short hr = f2bf(Sr[q]), hi_ = f2bf(Si[q]);
    unsigned hiw = (unsigned)hr | ((unsigned)hi_ << 16);
    unsigned low = (unsigned)f2bf(Sr[q] - bf2f(hr)) |
                   ((unsigned)f2bf(Si[q] - bf2f(hi_)) << 16);
    int boff = c * 128 + (((n >> 2) ^ (c & 7)) << 4) + (((2 * n) & 7) << 1);
    *(unsigned*)(ShiL + boff) = hiw;
    *(unsigned*)(SloL + boff) = low;
  }
#pragma unroll
  for (int i = 0; i < 2; ++i) {
    ((uint4*)TtL)[tid + (i << 8)]  = wst[i];
    ((uint4*)WinL)[tid + (i << 8)] = wst[i + 2];
  }
  __syncthreads();

  // ---- phase 3: correction GEMMs ----
#pragma unroll
  for (int ks = 0; ks < 2; ++ks) {
    int ca = w * 16 + lc;
    int u = ks * 4 + rg;
    bf16x8 Ah = *(const bf16x8*)(ShiL + ca * 128 + ((u ^ (ca & 7)) << 4));
    bf16x8 Al = *(const bf16x8*)(SloL + ca * 128 + ((u ^ (ca & 7)) << 4));
#pragma unroll
    for (int nb = 0; nb < 4; ++nb) {
      int col = nb * 16 + lc;
      bf16x8 Wh = *(const bf16x8*)(TtL + col * 128 + ((u ^ (col & 7)) << 4));
      bf16x8 Wl2 = *(const bf16x8*)(WinL + col * 128 + ((u ^ (col & 7)) << 4));
      accY[nb] = __builtin_amdgcn_mfma_f32_16x16x32_bf16(Ah, Wh, accY[nb], 0, 0, 0);
      accY[nb] = __builtin_amdgcn_mfma_f32_16x16x32_bf16(Al, Wh, accY[nb], 0, 0, 0);
      accY[nb] = __builtin_amdgcn_mfma_f32_16x16x32_bf16(Ah, Wl2, accY[nb], 0, 0, 0);
    }
  }
  __syncthreads();   // phase3 LDS reads done before Yl overwrites Shi

  // ---- epilogue: +D*u, GELU, pack to LDS, coalesced global write ----
  float dsk = Dsk[layer * H_ + hh];
  unsigned short* Yl = (unsigned short*)(smem + 24576);
#pragma unroll
  for (int nb = 0; nb < 4; ++nb) {
#pragma unroll
    for (int reg = 0; reg < 4; ++reg) {
      int cc = w * 16 + rg * 4 + reg;
      int i = nb * 16 + lc;
      unsigned short ub = *(unsigned short*)(
          Ul + cc * 128 + (((i >> 3) ^ (cc & 7)) << 4) + (i & 7) * 2);
      float yv = fmaf(dsk, bf2f(ub), accY[nb][reg]);
      float ge = 0.5f * yv * (1.f + erff(yv * 0.70710678118f));
      Yl[cc * 64 + i] = f2bf(ge);
    }
  }
  __syncthreads();
  unsigned short* Gr = G + ((size_t)(b * H_ + hh)) * LSEQ;
#pragma unroll
  for (int it = 0; it < 2; ++it) {
    int idx = tid + (it << 8);
    *(uint4*)(Gr + idx * 8) = ((uint4*)Yl)[idx];
  }
}

// ---------------------------------------------------------------------------
// GLU via bf16 MFMA + fused residual + LayerNorm (unchanged)
// ---------------------------------------------------------------------------
__global__ __launch_bounds__(512, 4) void k_glu(
    const unsigned short* __restrict__ Wb, const unsigned short* __restrict__ G,
    float* __restrict__ h, const float* __restrict__ gb,
    const float* __restrict__ lng, const float* __restrict__ lnb, int layer)
{
  extern __shared__ char smem[];
  char* WlB = smem;
  char* GlB = smem + 65536;
  float2* Red = (float2*)(smem + 65536 + 8192);

  int tid = threadIdx.x;
  int w = tid >> 6, lane = tid & 63;
  int b  = blockIdx.x >> 6;
  int l0 = (blockIdx.x & 63) << 6;
  int rgrp = lane >> 4, lc = lane & 15;

  f32x4 acc[4][4];
#pragma unroll
  for (int m = 0; m < 4; ++m)
#pragma unroll
    for (int n = 0; n < 4; ++n) acc[m][n] = (f32x4){0.f, 0.f, 0.f, 0.f};

  const unsigned short* wsrc = Wb + (size_t)(layer * 4) * 512 * 64;

  for (int kc4 = 0; kc4 < 4; ++kc4) {
    if (kc4) __syncthreads();
    const unsigned short* wc = wsrc + (size_t)kc4 * 512 * 64;
#pragma unroll
    for (int i = 0; i < 8; ++i) {
      int off = w * 8192 + i * 1024 + lane * 16;
      uint4 v = *(const uint4*)((const char*)wc + off);
      *(uint4*)(WlB + off) = v;
    }
    {
      int col = lane;
      int kc = kc4 * 64;
      size_t base = (size_t)(b * H_ + kc + w * 8) * LSEQ + l0 + col;
      unsigned v0 = G[base];
      unsigned v1 = G[base + (size_t)1 * LSEQ];
      unsigned v2 = G[base + (size_t)2 * LSEQ];
      unsigned v3 = G[base + (size_t)3 * LSEQ];
      unsigned v4 = G[base + (size_t)4 * LSEQ];
      unsigned v5 = G[base + (size_t)5 * LSEQ];
      unsigned v6 = G[base + (size_t)6 * LSEQ];
      unsigned v7 = G[base + (size_t)7 * LSEQ];
      unsigned pk0 = v0 | (v1 << 16), pk1 = v2 | (v3 << 16);
      unsigned pk2 = v4 | (v5 << 16), pk3 = v6 | (v7 << 16);
      *(uint4*)(GlB + col * 128 + ((w ^ (col & 7)) << 4)) =
          make_uint4(pk0, pk1, pk2, pk3);
    }
    __syncthreads();
#pragma unroll
    for (int ks = 0; ks < 2; ++ks) {
      int u = ks * 4 + rgrp;
      bf16x8 af[4], bff[4];
#pragma unroll
      for (int m = 0; m < 4; ++m) {
        int grow = ((m < 2) ? (w * 32 + m * 16) : (256 + w * 32 + (m - 2) * 16)) + lc;
        af[m] = *(const bf16x8*)(WlB + grow * 128 + ((u ^ (grow & 7)) << 4));
      }
#pragma unroll
      for (int n = 0; n < 4; ++n) {
        int gcol = n * 16 + lc;
        bff[n] = *(const bf16x8*)(GlB + gcol * 128 + ((u ^ (gcol & 7)) << 4));
      }
#pragma unroll
      for (int m = 0; m < 4; ++m)
#pragma unroll
        for (int n = 0; n < 4; ++n)
          acc[m][n] = __builtin_amdgcn_mfma_f32_16x16x32_bf16(
              af[m], bff[n], acc[m][n], 0, 0, 0);
    }
  }

  const float* gbL = gb + layer * 2 * H_;
  float out[2][4][4];
  float s[4], ss[4];
#pragma unroll
  for (int n = 0; n < 4; ++n) { s[n] = 0.f; ss[n] = 0.f; }
#pragma unroll
  for (int mA = 0; mA < 2; ++mA) {
#pragma unroll
    for (int reg = 0; reg < 4; ++reg) {
      int ch = w * 32 + mA * 16 + rgrp * 4 + reg;
      float ba = gbL[ch], bg = gbL[ch + H_];
#pragma unroll
      for (int n = 0; n < 4; ++n) {
        int col = n * 16 + lc;
        size_t off = (size_t)(b * H_ + ch) * LSEQ + l0 + col;
        float a = acc[mA][n][reg] + ba;
        float gv = acc[mA + 2][n][reg] + bg;
        float sg = 1.f / (1.f + expf(-gv));
        float o = fmaf(a, sg, h[off]);
        out[mA][n][reg] = o;
        s[n] += o; ss[n] = fmaf(o, o, ss[n]);
      }
    }
  }
#pragma unroll
  for (int n = 0; n < 4; ++n) {
    s[n]  += __shfl_xor(s[n], 16);  s[n]  += __shfl_xor(s[n], 32);
    ss[n] += __shfl_xor(ss[n], 16); ss[n] += __shfl_xor(ss[n], 32);
  }
  if (lane < 16) {
#pragma unroll
    for (int n = 0; n < 4; ++n)
      Red[w * 64 + n * 16 + lane] = make_float2(s[n], ss[n]);
  }
  __syncthreads();
  float mu[4], rs[4];
#pragma unroll
  for (int n = 0; n < 4; ++n) {
    int col = n * 16 + lc;
    float ts = 0.f, tss = 0.f;
#pragma unroll
    for (int ww = 0; ww < 8; ++ww) {
      float2 v = Red[ww * 64 + col];
      ts += v.x; tss += v.y;
    }
    mu[n] = ts * (1.f / H_);
    rs[n] = rsqrtf(tss * (1.f / H_) - mu[n] * mu[n] + LN_EPSF);
  }
#pragma unroll
  for (int mA = 0; mA < 2; ++mA) {
#pragma unroll
    for (int reg = 0; reg < 4; ++reg) {
      int ch = w * 32 + mA * 16 + rgrp * 4 + reg;
      float lg = lng[layer * H_ + ch], lb = lnb[layer * H_ + ch];
#pragma unroll
      for (int n = 0; n < 4; ++n) {
        int col = n * 16 + lc;
        size_t off = (size_t)(b * H_ + ch) * LSEQ + l0 + col;
        h[off] = (out[mA][n][reg] - mu[n]) * rs[n] * lg + lb;
      }
    }
  }
}

// ---------------------------------------------------------------------------
// Mean-pool, decode, softmax (unchanged)
// ---------------------------------------------------------------------------
__global__ __launch_bounds__(256) void k_final(
    const float* __restrict__ h, const float* __restrict__ dw,
    const float* __restrict__ db, float* __restrict__ out)
{
  __shared__ float P[H_];
  __shared__ float Z[2];
  int b = blockIdx.x, tid = threadIdx.x;
  const float4* row = (const float4*)(h + ((size_t)(b * H_ + tid)) * LSEQ);
  float a0 = 0, a1 = 0, a2 = 0, a3 = 0;
  for (int t = 0; t < LSEQ / 4; ++t) {
    float4 v = row[t];
    a0 += v.x; a1 += v.y; a2 += v.z; a3 += v.w;
  }
  P[tid] = (a0 + a1 + a2 + a3) * (1.f / LSEQ);
  __syncthreads();
  if (tid < 2) {
    float z = db[tid];
    for (int k = 0; k < H_; ++k) z = fmaf(P[k], dw[k * DOUT + tid], z);
    Z[tid] = z;
  }
  __syncthreads();
  if (tid == 0) {
    float m = fmaxf(Z[0], Z[1]);
    float e0 = expf(Z[0] - m), e1 = expf(Z[1] - m);
    float inv = 1.f / (e0 + e1);
    out[b * 2 + 0] = e0 * inv;
    out[b * 2 + 1] = e1 * inv;
  }
}

// ---------------------------------------------------------------------------
extern "C" void kernel_launch(void* const* d_in, const int* in_sizes, int n_in,
                              void* d_out, int out_size, void* d_ws, size_t ws_size,
                              hipStream_t stream) {
  (void)in_sizes; (void)n_in; (void)out_size; (void)ws_size;
  const float* x      = (const float*)d_in[0];
  const float* enc_w  = (const float*)d_in[1];
  const float* enc_b  = (const float*)d_in[2];
  const float* log_dt = (const float*)d_in[3];
  const float* Cri    = (const float*)d_in[4];
  const float* lAr    = (const float*)d_in[5];
  const float* Aim    = (const float*)d_in[6];
  const float* Dsk    = (const float*)d_in[7];
  const float* glu_w  = (const float*)d_in[8];
  const float* glu_b  = (const float*)d_in[9];
  const float* ln_g   = (const float*)d_in[10];
  const float* ln_b   = (const float*)d_in[11];
  const float* dec_w  = (const float*)d_in[12];
  const float* dec_b  = (const float*)d_in[13];
  float* out = (float*)d_out;

  float* h = (float*)d_ws;                                   // 128 MB
  unsigned short* G   = (unsigned short*)(h + (size_t)B_ * H_ * LSEQ);  // 64 MB
  unsigned short* Wb  = G + (size_t)B_ * H_ * LSEQ;          // 1 MB
  unsigned short* TtG = Wb + 524288;                         // 8 MB
  unsigned short* WinG = TtG + 4194304;                      // 8 MB
  unsigned short* WhiG = WinG + 4194304;                     // 8 MB
  unsigned short* WloG = WhiG + 4194304;                     // 8 MB
  float2* AQG = (float2*)(WloG + 4194304);                   // 256 KB

  k_wconv<<<256, 256, 0, stream>>>(glu_w, Wb);
  k_prep<<<NL_ * H_, 64, 0, stream>>>(log_dt, Cri, lAr, Aim, TtG, WinG, WhiG, WloG, AQG);
  k_encoder<<<B_ * (LSEQ / 32), 256, 0, stream>>>(x, enc_w, enc_b, h);
  for (int i = 0; i < NL_; ++i) {
    k_chunk<<<H_ * B_, 256, 0, stream>>>(h, G, TtG, WinG, WhiG, WloG,
                                         AQG, Dsk, i);
    k_glu<<<B_ * (LSEQ / 64), 512, 77824, stream>>>(Wb, G, h, glu_b, ln_g, ln_b, i);
  }
  k_final<<<B_, 256, 0, stream>>>(h, dec_w, dec_b, out);
}

// Round 9
// 991.146 us; speedup vs baseline: 3.6680x; 1.1012x over previous
//
#include <hip/hip_runtime.h>
#include <math.h>

#define B_    32
#define DIN   64
#define LSEQ  4096
#define H_    256
#define N2_   32
#define NL_   4
#define DOUT  2
#define LN_EPSF 1e-5f

typedef __bf16 bf16x8 __attribute__((ext_vector_type(8)));
typedef float  f32x4  __attribute__((ext_vector_type(4)));

__device__ inline unsigned short f2bf(float f) {
  unsigned u = __builtin_bit_cast(unsigned, f);
  u += 0x7FFFu + ((u >> 16) & 1u);
  return (unsigned short)(u >> 16);
}
__device__ inline float bf2f(unsigned short u) {
  return __builtin_bit_cast(float, ((unsigned)u) << 16);
}

// ZOH discretization params for mode n of (layer, hh)
__device__ inline void mode_params(const float* log_dt, const float* Cri,
                                   const float* lAr, const float* Aim,
                                   int layer, int hh, int n, float dt,
                                   float& dr, float& di, float& ctr, float& cti) {
  int idx = (layer * H_ + hh) * N2_ + n;
  float Are = -expf(lAr[idx]);
  float Aimv = Aim[idx];
  dr = Are * dt; di = Aimv * dt;
  float er = expf(dr), sn, cs;
  sincosf(di, &sn, &cs);
  float arr = er * cs, aii = er * sn;
  float nr = arr - 1.f, ni = aii;
  float inv = 1.f / (Are * Are + Aimv * Aimv);
  float qr = (nr * Are + ni * Aimv) * inv;
  float qi = (ni * Are - nr * Aimv) * inv;
  float Cr = Cri[2 * idx], Ci = Cri[2 * idx + 1];
  ctr = 2.f * (Cr * qr - Ci * qi);
  cti = 2.f * (Cr * qi + Ci * qr);
}

// ---------------------------------------------------------------------------
// k_prep: per (layer,h) build pre-swizzled bf16 images (64x64 each) + a^64 tbl
// ---------------------------------------------------------------------------
__global__ __launch_bounds__(64) void k_prep(
    const float* __restrict__ log_dt, const float* __restrict__ Cri,
    const float* __restrict__ lAr, const float* __restrict__ Aim,
    unsigned short* __restrict__ TtG, unsigned short* __restrict__ WinG,
    unsigned short* __restrict__ WhiG, unsigned short* __restrict__ WloG,
    float2* __restrict__ AQG)
{
  int bid = blockIdx.x;
  int layer = bid >> 8, hh = bid & 255;
  int lane = threadIdx.x;
  __shared__ float Kf[64];
  float dt = expf(log_dt[layer * H_ + hh]);

  float kd = 0.f;
  for (int n = 0; n < N2_; ++n) {
    float dr, di, ctr, cti;
    mode_params(log_dt, Cri, lAr, Aim, layer, hh, n, dt, dr, di, ctr, cti);
    float er = expf(dr * (float)lane), sn, cs;
    sincosf(di * (float)lane, &sn, &cs);
    kd += ctr * (er * cs) - cti * (er * sn);
  }
  Kf[lane] = kd;
  if (lane < N2_) {
    int idx = (layer * H_ + hh) * N2_ + lane;
    float dr64 = -expf(lAr[idx]) * dt * 64.f;
    float di64 = Aim[idx] * dt * 64.f;
    float er = expf(dr64), sn, cs;
    sincosf(di64, &sn, &cs);
    AQG[bid * N2_ + lane] = make_float2(er * cs, er * sn);
  }
  __syncthreads();

  size_t base = (size_t)bid * 4096;
  for (int t = 0; t < 64; ++t) {
    float v = (t <= lane) ? Kf[lane - t] : 0.f;
    TtG[base + lane * 64 + (((t >> 3) ^ (lane & 7)) << 3) + (t & 7)] = f2bf(v);
  }
  {
    int n = lane >> 1, im = lane & 1;
    float dr, di, ctr, cti;
    mode_params(log_dt, Cri, lAr, Aim, layer, hh, n, dt, dr, di, ctr, cti);
    for (int t = 0; t < 64; ++t) {
      float e = (float)(63 - t);
      float er = expf(dr * e), sn, cs;
      sincosf(di * e, &sn, &cs);
      float v = im ? (er * sn) : (er * cs);
      WinG[base + lane * 64 + (((t >> 3) ^ (lane & 7)) << 3) + (t & 7)] = f2bf(v);
    }
  }
  for (int r = 0; r < 64; ++r) {
    int n = r >> 1;
    float dr, di, ctr, cti;
    mode_params(log_dt, Cri, lAr, Aim, layer, hh, n, dt, dr, di, ctr, cti);
    float e = (float)(lane + 1);
    float er = expf(dr * e), sn, cs;
    sincosf(di * e, &sn, &cs);
    float wre = ctr * (er * cs) - cti * (er * sn);
    float wim = ctr * (er * sn) + cti * (er * cs);
    float v = (r & 1) ? -wim : wre;
    unsigned short hi = f2bf(v);
    float lo = v - bf2f(hi);
    size_t off = base + lane * 64 + (((r >> 3) ^ (lane & 7)) << 3) + (r & 7);
    WhiG[off] = hi;
    WloG[off] = f2bf(lo);
  }
}

// ---------------------------------------------------------------------------
// k_wconv: glu_w fp32 -> bf16 pre-swizzled (unchanged)
// ---------------------------------------------------------------------------
__global__ __launch_bounds__(256) void k_wconv(
    const float* __restrict__ gw, unsigned short* __restrict__ wb)
{
  int t = blockIdx.x * 256 + threadIdx.x;
  int uu = t & 7;
  int r  = (t >> 3) & 511;
  int l4 = t >> 12;
  int layer = l4 >> 2, kc4 = l4 & 3;
  int ksrc = kc4 * 64 + ((uu ^ (r & 7)) << 3);
  const float* src = gw + ((size_t)(layer * 512 + r)) * H_ + ksrc;
  unsigned short* dst = wb + (size_t)t * 8;
#pragma unroll
  for (int j = 0; j < 8; ++j) dst[j] = f2bf(src[j]);
}

// ---------------------------------------------------------------------------
// Encoder (unchanged)
// ---------------------------------------------------------------------------
__global__ __launch_bounds__(256) void k_encoder(
    const float* __restrict__ x, const float* __restrict__ ew,
    const float* __restrict__ eb, float* __restrict__ h)
{
  __shared__ __align__(16) float Wl[32][256];
  __shared__ __align__(16) float Xl[32][32];
  int tid = threadIdx.x;
  int blk = blockIdx.x;
  int b  = blk >> 7;
  int l0 = (blk & 127) << 5;
  int ty = tid >> 3;
  int tx = tid & 7;
  float acc[8][4];
#pragma unroll
  for (int i = 0; i < 8; ++i)
#pragma unroll
    for (int j = 0; j < 4; ++j) acc[i][j] = 0.f;

  for (int kc = 0; kc < DIN; kc += 32) {
    const float4* ew4 = (const float4*)(ew + kc * H_);
#pragma unroll
    for (int it = 0; it < 8; ++it) {
      int idx = tid + (it << 8);
      ((float4*)&Wl[0][0])[idx] = ew4[idx];
    }
    {
      int c = tid >> 3, p = (tid & 7) << 2;
      *(float4*)&Xl[c][p] =
          *(const float4*)(x + ((size_t)(b * DIN + kc + c)) * LSEQ + l0 + p);
    }
    __syncthreads();
#pragma unroll
    for (int k = 0; k < 32; ++k) {
      float4 w0 = *(float4*)&Wl[k][ty * 8];
      float4 w1 = *(float4*)&Wl[k][ty * 8 + 4];
      float4 xv = *(float4*)&Xl[k][tx * 4];
      float wvv[8] = {w0.x, w0.y, w0.z, w0.w, w1.x, w1.y, w1.z, w1.w};
      float xs[4]  = {xv.x, xv.y, xv.z, xv.w};
#pragma unroll
      for (int i = 0; i < 8; ++i)
#pragma unroll
        for (int j = 0; j < 4; ++j) acc[i][j] = fmaf(wvv[i], xs[j], acc[i][j]);
    }
    __syncthreads();
  }
#pragma unroll
  for (int i = 0; i < 8; ++i) {
    int d = ty * 8 + i;
    float bia = eb[d];
    float4 o = make_float4(acc[i][0] + bia, acc[i][1] + bia,
                           acc[i][2] + bia, acc[i][3] + bia);
    *(float4*)(h + ((size_t)(b * H_ + d)) * LSEQ + l0 + tx * 4) = o;
  }
}

// ---------------------------------------------------------------------------
// k_chunk v3 (unchanged from round 7)
// ---------------------------------------------------------------------------
__global__ __launch_bounds__(256, 4) void k_chunk(
    const float* __restrict__ hin, unsigned short* __restrict__ G,
    const unsigned short* __restrict__ TtG, const unsigned short* __restrict__ WinG,
    const unsigned short* __restrict__ WhiG, const unsigned short* __restrict__ WloG,
    const float2* __restrict__ AQG, const float* __restrict__ Dsk, int layer)
{
  __shared__ __align__(16) char smem[40960];
  char* Ul    = smem;                      // 8KB bf16 [c][t] swz
  char* TtL   = smem + 8192;               // 8KB: Tt -> Whi
  char* WinL  = smem + 16384;              // 8KB: Win -> Wlo
  float* BstT = (float*)(smem + 24576);    // 16KB f32 [r][c^((r&7)<<2)]
  char* ShiL  = smem + 24576;              // 8KB (after scan)
  char* SloL  = smem + 32768;              // 8KB

  int tid = threadIdx.x;
  int w = tid >> 6, lane = tid & 63;
  int rg = lane >> 4, lc = lane & 15;
  int bid = blockIdx.x;
  int hh = bid >> 5, b = bid & 31;
  size_t wbase = ((size_t)(layer * H_ + hh)) * 4096;
  const float* Urow = hin + ((size_t)(b * H_ + hh)) * LSEQ;

#pragma unroll
  for (int it = 0; it < 2; ++it) {
    int idx = tid + (it << 8);          // 0..511
    int c = idx >> 3, uu = idx & 7;
    const float* src = Urow + c * 64 + uu * 8;
    float4 u0 = *(const float4*)(src);
    float4 u1 = *(const float4*)(src + 4);
    unsigned p0 = f2bf(u0.x) | ((unsigned)f2bf(u0.y) << 16);
    unsigned p1 = f2bf(u0.z) | ((unsigned)f2bf(u0.w) << 16);
    unsigned p2 = f2bf(u1.x) | ((unsigned)f2bf(u1.y) << 16);
    unsigned p3 = f2bf(u1.z) | ((unsigned)f2bf(u1.w) << 16);
    *(uint4*)(Ul + c * 128 + ((uu ^ (c & 7)) << 4)) = make_uint4(p0, p1, p2, p3);
    ((uint4*)TtL)[idx]  = ((const uint4*)(TtG + wbase))[idx];
    ((uint4*)WinL)[idx] = ((const uint4*)(WinG + wbase))[idx];
  }
  __syncthreads();

  f32x4 accY[4], accB[4];
#pragma unroll
  for (int nb = 0; nb < 4; ++nb) {
    accY[nb] = (f32x4){0.f, 0.f, 0.f, 0.f};
    accB[nb] = (f32x4){0.f, 0.f, 0.f, 0.f};
  }
#pragma unroll
  for (int ks = 0; ks < 2; ++ks) {
    int ca = w * 16 + lc;
    int u = ks * 4 + rg;
    bf16x8 A = *(const bf16x8*)(Ul + ca * 128 + ((u ^ (ca & 7)) << 4));
#pragma unroll
    for (int nb = 0; nb < 4; ++nb) {
      int col = nb * 16 + lc;
      bf16x8 Bt = *(const bf16x8*)(TtL + col * 128 + ((u ^ (col & 7)) << 4));
      bf16x8 Bw = *(const bf16x8*)(WinL + col * 128 + ((u ^ (col & 7)) << 4));
      accY[nb] = __builtin_amdgcn_mfma_f32_16x16x32_bf16(A, Bt, accY[nb], 0, 0, 0);
      accB[nb] = __builtin_amdgcn_mfma_f32_16x16x32_bf16(A, Bw, accB[nb], 0, 0, 0);
    }
  }
#pragma unroll
  for (int nb = 0; nb < 4; ++nb)
#pragma unroll
    for (int reg = 0; reg < 4; ++reg) {
      int r = nb * 16 + lc;
      int cc = w * 16 + rg * 4 + reg;
      BstT[r * 64 + (cc ^ ((r & 7) << 2))] = accB[nb][reg];
    }
  __syncthreads();

  float Sr[8], Si[8], Mr[8], Mi[8];
  int c = lane;
  {
    const float2* aqb = AQG + (size_t)(layer * H_ + hh) * N2_ + w * 8;
#pragma unroll
    for (int q = 0; q < 8; ++q) {
      float2 aq = aqb[q];
      Mr[q] = aq.x; Mi[q] = aq.y;
      int r0 = (w * 8 + q) * 2, r1 = r0 + 1;
      Sr[q] = BstT[r0 * 64 + (c ^ ((r0 & 7) << 2))];
      Si[q] = BstT[r1 * 64 + (c ^ ((r1 & 7) << 2))];
    }
  }
  uint4 wst[4];
#pragma unroll
  for (int i = 0; i < 2; ++i) {
    wst[i]     = ((const uint4*)(WhiG + wbase))[tid + (i << 8)];
    wst[i + 2] = ((const uint4*)(WloG + wbase))[tid + (i << 8)];
  }
  __syncthreads();

#pragma unroll
  for (int dd = 0; dd < 6; ++dd) {
    int d = 1 << dd;
#pragma unroll
    for (int q = 0; q < 8; ++q) {
      float pr = __shfl_up(Sr[q], (unsigned)d);
      float pi = __shfl_up(Si[q], (unsigned)d);
      if (lane >= d) {
        Sr[q] = fmaf(Mr[q], pr, fmaf(-Mi[q], pi, Sr[q]));
        Si[q] = fmaf(Mr[q], pi, fmaf(Mi[q], pr, Si[q]));
      }
      if (dd < 5) {
        float t = fmaf(Mr[q], Mr[q], -Mi[q] * Mi[q]);
        Mi[q] = 2.f * Mr[q] * Mi[q];
        Mr[q] = t;
      }
    }
  }
#pragma unroll
  for (int q = 0; q < 8; ++q) {
    float pr = __shfl_up(Sr[q], 1u);
    float pi = __shfl_up(Si[q], 1u);
    Sr[q] = (lane == 0) ? 0.f : pr;
    Si[q] = (lane == 0) ? 0.f : pi;
  }
#pragma unroll
  for (int q = 0; q < 8; ++q) {
    int n = w * 8 + q;
    unsigned short hr = f2bf(Sr[q]), hi_ = f2bf(Si[q]);
    unsigned hiw = (unsigned)hr | ((unsigned)hi_ << 16);
    unsigned low = (unsigned)f2bf(Sr[q] - bf2f(hr)) |
                   ((unsigned)f2bf(Si[q] - bf2f(hi_)) << 16);
    int boff = c * 128 + (((n >> 2) ^ (c & 7)) << 4) + (((2 * n) & 7) << 1);
    *(unsigned*)(ShiL + boff) = hiw;
    *(unsigned*)(SloL + boff) = low;
  }
#pragma unroll
  for (int i = 0; i < 2; ++i) {
    ((uint4*)TtL)[tid + (i << 8)]  = wst[i];
    ((uint4*)WinL)[tid + (i << 8)] = wst[i + 2];
  }
  __syncthreads();

#pragma unroll
  for (int ks = 0; ks < 2; ++ks) {
    int ca = w * 16 + lc;
    int u = ks * 4 + rg;
    bf16x8 Ah = *(const bf16x8*)(ShiL + ca * 128 + ((u ^ (ca & 7)) << 4));
    bf16x8 Al = *(const bf16x8*)(SloL + ca * 128 + ((u ^ (ca & 7)) << 4));
#pragma unroll
    for (int nb = 0; nb < 4; ++nb) {
      int col = nb * 16 + lc;
      bf16x8 Wh = *(const bf16x8*)(TtL + col * 128 + ((u ^ (col & 7)) << 4));
      bf16x8 Wl2 = *(const bf16x8*)(WinL + col * 128 + ((u ^ (col & 7)) << 4));
      accY[nb] = __builtin_amdgcn_mfma_f32_16x16x32_bf16(Ah, Wh, accY[nb], 0, 0, 0);
      accY[nb] = __builtin_amdgcn_mfma_f32_16x16x32_bf16(Al, Wh, accY[nb], 0, 0, 0);
      accY[nb] = __builtin_amdgcn_mfma_f32_16x16x32_bf16(Ah, Wl2, accY[nb], 0, 0, 0);
    }
  }
  __syncthreads();

  float dsk = Dsk[layer * H_ + hh];
  unsigned short* Yl = (unsigned short*)(smem + 24576);
#pragma unroll
  for (int nb = 0; nb < 4; ++nb) {
#pragma unroll
    for (int reg = 0; reg < 4; ++reg) {
      int cc = w * 16 + rg * 4 + reg;
      int i = nb * 16 + lc;
      unsigned short ub = *(unsigned short*)(
          Ul + cc * 128 + (((i >> 3) ^ (cc & 7)) << 4) + (i & 7) * 2);
      float yv = fmaf(dsk, bf2f(ub), accY[nb][reg]);
      float ge = 0.5f * yv * (1.f + erff(yv * 0.70710678118f));
      Yl[cc * 64 + i] = f2bf(ge);
    }
  }
  __syncthreads();
  unsigned short* Gr = G + ((size_t)(b * H_ + hh)) * LSEQ;
#pragma unroll
  for (int it = 0; it < 2; ++it) {
    int idx = tid + (it << 8);
    *(uint4*)(Gr + idx * 8) = ((uint4*)Yl)[idx];
  }
}

// ---------------------------------------------------------------------------
// GLU via bf16 MFMA + fused residual + LayerNorm (unchanged)
// ---------------------------------------------------------------------------
__global__ __launch_bounds__(512, 4) void k_glu(
    const unsigned short* __restrict__ Wb, const unsigned short* __restrict__ G,
    float* __restrict__ h, const float* __restrict__ gb,
    const float* __restrict__ lng, const float* __restrict__ lnb, int layer)
{
  extern __shared__ char smem[];
  char* WlB = smem;
  char* GlB = smem + 65536;
  float2* Red = (float2*)(smem + 65536 + 8192);

  int tid = threadIdx.x;
  int w = tid >> 6, lane = tid & 63;
  int b  = blockIdx.x >> 6;
  int l0 = (blockIdx.x & 63) << 6;
  int rgrp = lane >> 4, lc = lane & 15;

  f32x4 acc[4][4];
#pragma unroll
  for (int m = 0; m < 4; ++m)
#pragma unroll
    for (int n = 0; n < 4; ++n) acc[m][n] = (f32x4){0.f, 0.f, 0.f, 0.f};

  const unsigned short* wsrc = Wb + (size_t)(layer * 4) * 512 * 64;

  for (int kc4 = 0; kc4 < 4; ++kc4) {
    if (kc4) __syncthreads();
    const unsigned short* wc = wsrc + (size_t)kc4 * 512 * 64;
#pragma unroll
    for (int i = 0; i < 8; ++i) {
      int off = w * 8192 + i * 1024 + lane * 16;
      uint4 v = *(const uint4*)((const char*)wc + off);
      *(uint4*)(WlB + off) = v;
    }
    {
      int col = lane;
      int kc = kc4 * 64;
      size_t base = (size_t)(b * H_ + kc + w * 8) * LSEQ + l0 + col;
      unsigned v0 = G[base];
      unsigned v1 = G[base + (size_t)1 * LSEQ];
      unsigned v2 = G[base + (size_t)2 * LSEQ];
      unsigned v3 = G[base + (size_t)3 * LSEQ];
      unsigned v4 = G[base + (size_t)4 * LSEQ];
      unsigned v5 = G[base + (size_t)5 * LSEQ];
      unsigned v6 = G[base + (size_t)6 * LSEQ];
      unsigned v7 = G[base + (size_t)7 * LSEQ];
      unsigned pk0 = v0 | (v1 << 16), pk1 = v2 | (v3 << 16);
      unsigned pk2 = v4 | (v5 << 16), pk3 = v6 | (v7 << 16);
      *(uint4*)(GlB + col * 128 + ((w ^ (col & 7)) << 4)) =
          make_uint4(pk0, pk1, pk2, pk3);
    }
    __syncthreads();
#pragma unroll
    for (int ks = 0; ks < 2; ++ks) {
      int u = ks * 4 + rgrp;
      bf16x8 af[4], bff[4];
#pragma unroll
      for (int m = 0; m < 4; ++m) {
        int grow = ((m < 2) ? (w * 32 + m * 16) : (256 + w * 32 + (m - 2) * 16)) + lc;
        af[m] = *(const bf16x8*)(WlB + grow * 128 + ((u ^ (grow & 7)) << 4));
      }
#pragma unroll
      for (int n = 0; n < 4; ++n) {
        int gcol = n * 16 + lc;
        bff[n] = *(const bf16x8*)(GlB + gcol * 128 + ((u ^ (gcol & 7)) << 4));
      }
#pragma unroll
      for (int m = 0; m < 4; ++m)
#pragma unroll
        for (int n = 0; n < 4; ++n)
          acc[m][n] = __builtin_amdgcn_mfma_f32_16x16x32_bf16(
              af[m], bff[n], acc[m][n], 0, 0, 0);
    }
  }

  const float* gbL = gb + layer * 2 * H_;
  float out[2][4][4];
  float s[4], ss[4];
#pragma unroll
  for (int n = 0; n < 4; ++n) { s[n] = 0.f; ss[n] = 0.f; }
#pragma unroll
  for (int mA = 0; mA < 2; ++mA) {
#pragma unroll
    for (int reg = 0; reg < 4; ++reg) {
      int ch = w * 32 + mA * 16 + rgrp * 4 + reg;
      float ba = gbL[ch], bg = gbL[ch + H_];
#pragma unroll
      for (int n = 0; n < 4; ++n) {
        int col = n * 16 + lc;
        size_t off = (size_t)(b * H_ + ch) * LSEQ + l0 + col;
        float a = acc[mA][n][reg] + ba;
        float gv = acc[mA + 2][n][reg] + bg;
        float sg = 1.f / (1.f + expf(-gv));
        float o = fmaf(a, sg, h[off]);
        out[mA][n][reg] = o;
        s[n] += o; ss[n] = fmaf(o, o, ss[n]);
      }
    }
  }
#pragma unroll
  for (int n = 0; n < 4; ++n) {
    s[n]  += __shfl_xor(s[n], 16);  s[n]  += __shfl_xor(s[n], 32);
    ss[n] += __shfl_xor(ss[n], 16); ss[n] += __shfl_xor(ss[n], 32);
  }
  if (lane < 16) {
#pragma unroll
    for (int n = 0; n < 4; ++n)
      Red[w * 64 + n * 16 + lane] = make_float2(s[n], ss[n]);
  }
  __syncthreads();
  float mu[4], rs[4];
#pragma unroll
  for (int n = 0; n < 4; ++n) {
    int col = n * 16 + lc;
    float ts = 0.f, tss = 0.f;
#pragma unroll
    for (int ww = 0; ww < 8; ++ww) {
      float2 v = Red[ww * 64 + col];
      ts += v.x; tss += v.y;
    }
    mu[n] = ts * (1.f / H_);
    rs[n] = rsqrtf(tss * (1.f / H_) - mu[n] * mu[n] + LN_EPSF);
  }
#pragma unroll
  for (int mA = 0; mA < 2; ++mA) {
#pragma unroll
    for (int reg = 0; reg < 4; ++reg) {
      int ch = w * 32 + mA * 16 + rgrp * 4 + reg;
      float lg = lng[layer * H_ + ch], lb = lnb[layer * H_ + ch];
#pragma unroll
      for (int n = 0; n < 4; ++n) {
        int col = n * 16 + lc;
        size_t off = (size_t)(b * H_ + ch) * LSEQ + l0 + col;
        h[off] = (out[mA][n][reg] - mu[n]) * rs[n] * lg + lb;
      }
    }
  }
}

// ---------------------------------------------------------------------------
// k_pool: mean over L per (b,h) row. One wave per row, 2048 blocks.
// ---------------------------------------------------------------------------
__global__ __launch_bounds__(256) void k_pool(
    const float* __restrict__ h, float* __restrict__ P)
{
  int row = blockIdx.x * 4 + (threadIdx.x >> 6);    // b*H + ch
  int lane = threadIdx.x & 63;
  const float4* src = (const float4*)(h + (size_t)row * LSEQ);
  float s = 0.f;
#pragma unroll
  for (int i = 0; i < 16; ++i) {
    float4 v = src[lane + i * 64];
    s += (v.x + v.y) + (v.z + v.w);
  }
#pragma unroll
  for (int d = 1; d < 64; d <<= 1) s += __shfl_xor(s, d);
  if (lane == 0) P[row] = s * (1.f / LSEQ);
}

// ---------------------------------------------------------------------------
// k_dec: decode (256->2) + softmax from pooled P. grid B, block 64.
// ---------------------------------------------------------------------------
__global__ __launch_bounds__(64) void k_dec(
    const float* __restrict__ P, const float* __restrict__ dw,
    const float* __restrict__ db, float* __restrict__ out)
{
  int b = blockIdx.x, lane = threadIdx.x;
  float z0 = 0.f, z1 = 0.f;
#pragma unroll
  for (int i = 0; i < 4; ++i) {
    int k = lane + i * 64;
    float p = P[b * H_ + k];
    z0 = fmaf(p, dw[k * DOUT + 0], z0);
    z1 = fmaf(p, dw[k * DOUT + 1], z1);
  }
#pragma unroll
  for (int d = 1; d < 64; d <<= 1) {
    z0 += __shfl_xor(z0, d);
    z1 += __shfl_xor(z1, d);
  }
  if (lane == 0) {
    z0 += db[0]; z1 += db[1];
    float m = fmaxf(z0, z1);
    float e0 = expf(z0 - m), e1 = expf(z1 - m);
    float inv = 1.f / (e0 + e1);
    out[b * 2 + 0] = e0 * inv;
    out[b * 2 + 1] = e1 * inv;
  }
}

// ---------------------------------------------------------------------------
extern "C" void kernel_launch(void* const* d_in, const int* in_sizes, int n_in,
                              void* d_out, int out_size, void* d_ws, size_t ws_size,
                              hipStream_t stream) {
  (void)in_sizes; (void)n_in; (void)out_size; (void)ws_size;
  const float* x      = (const float*)d_in[0];
  const float* enc_w  = (const float*)d_in[1];
  const float* enc_b  = (const float*)d_in[2];
  const float* log_dt = (const float*)d_in[3];
  const float* Cri    = (const float*)d_in[4];
  const float* lAr    = (const float*)d_in[5];
  const float* Aim    = (const float*)d_in[6];
  const float* Dsk    = (const float*)d_in[7];
  const float* glu_w  = (const float*)d_in[8];
  const float* glu_b  = (const float*)d_in[9];
  const float* ln_g   = (const float*)d_in[10];
  const float* ln_b   = (const float*)d_in[11];
  const float* dec_w  = (const float*)d_in[12];
  const float* dec_b  = (const float*)d_in[13];
  float* out = (float*)d_out;

  float* h = (float*)d_ws;                                   // 128 MB
  unsigned short* G   = (unsigned short*)(h + (size_t)B_ * H_ * LSEQ);  // 64 MB
  unsigned short* Wb  = G + (size_t)B_ * H_ * LSEQ;          // 1 MB
  unsigned short* TtG = Wb + 524288;                         // 8 MB
  unsigned short* WinG = TtG + 4194304;                      // 8 MB
  unsigned short* WhiG = WinG + 4194304;                     // 8 MB
  unsigned short* WloG = WhiG + 4194304;                     // 8 MB
  float2* AQG = (float2*)(WloG + 4194304);                   // 256 KB
  float* P    = (float*)(AQG + NL_ * H_ * N2_);              // 32 KB

  k_wconv<<<256, 256, 0, stream>>>(glu_w, Wb);
  k_prep<<<NL_ * H_, 64, 0, stream>>>(log_dt, Cri, lAr, Aim, TtG, WinG, WhiG, WloG, AQG);
  k_encoder<<<B_ * (LSEQ / 32), 256, 0, stream>>>(x, enc_w, enc_b, h);
  for (int i = 0; i < NL_; ++i) {
    k_chunk<<<H_ * B_, 256, 0, stream>>>(h, G, TtG, WinG, WhiG, WloG,
                                         AQG, Dsk, i);
    k_glu<<<B_ * (LSEQ / 64), 512, 77824, stream>>>(Wb, G, h, glu_b, ln_g, ln_b, i);
  }
  k_pool<<<(B_ * H_) / 4, 256, 0, stream>>>(h, P);
  k_dec<<<B_, 64, 0, stream>>>(P, dec_w, dec_b, out);
}

// Round 10
// 945.037 us; speedup vs baseline: 3.8470x; 1.0488x over previous
//
#include <hip/hip_runtime.h>
#include <math.h>

#define B_    32
#define DIN   64
#define LSEQ  4096
#define H_    256
#define N2_   32
#define NL_   4
#define DOUT  2
#define LN_EPSF 1e-5f

typedef __bf16 bf16x8 __attribute__((ext_vector_type(8)));
typedef float  f32x4  __attribute__((ext_vector_type(4)));

__device__ inline unsigned short f2bf(float f) {
  unsigned u = __builtin_bit_cast(unsigned, f);
  u += 0x7FFFu + ((u >> 16) & 1u);
  return (unsigned short)(u >> 16);
}
__device__ inline float bf2f(unsigned short u) {
  return __builtin_bit_cast(float, ((unsigned)u) << 16);
}

// ZOH discretization params for mode n of (layer, hh)
__device__ inline void mode_params(const float* log_dt, const float* Cri,
                                   const float* lAr, const float* Aim,
                                   int layer, int hh, int n, float dt,
                                   float& dr, float& di, float& ctr, float& cti) {
  int idx = (layer * H_ + hh) * N2_ + n;
  float Are = -expf(lAr[idx]);
  float Aimv = Aim[idx];
  dr = Are * dt; di = Aimv * dt;
  float er = expf(dr), sn, cs;
  sincosf(di, &sn, &cs);
  float arr = er * cs, aii = er * sn;
  float nr = arr - 1.f, ni = aii;
  float inv = 1.f / (Are * Are + Aimv * Aimv);
  float qr = (nr * Are + ni * Aimv) * inv;
  float qi = (ni * Are - nr * Aimv) * inv;
  float Cr = Cri[2 * idx], Ci = Cri[2 * idx + 1];
  ctr = 2.f * (Cr * qr - Ci * qi);
  cti = 2.f * (Cr * qi + Ci * qr);
}

// ---------------------------------------------------------------------------
// k_prep: per (layer,h) build pre-swizzled bf16 images (64x64 each) + a^64 tbl
// ---------------------------------------------------------------------------
__global__ __launch_bounds__(64) void k_prep(
    const float* __restrict__ log_dt, const float* __restrict__ Cri,
    const float* __restrict__ lAr, const float* __restrict__ Aim,
    unsigned short* __restrict__ TtG, unsigned short* __restrict__ WinG,
    unsigned short* __restrict__ WhiG, unsigned short* __restrict__ WloG,
    float2* __restrict__ AQG)
{
  int bid = blockIdx.x;
  int layer = bid >> 8, hh = bid & 255;
  int lane = threadIdx.x;
  __shared__ float Kf[64];
  float dt = expf(log_dt[layer * H_ + hh]);

  float kd = 0.f;
  for (int n = 0; n < N2_; ++n) {
    float dr, di, ctr, cti;
    mode_params(log_dt, Cri, lAr, Aim, layer, hh, n, dt, dr, di, ctr, cti);
    float er = expf(dr * (float)lane), sn, cs;
    sincosf(di * (float)lane, &sn, &cs);
    kd += ctr * (er * cs) - cti * (er * sn);
  }
  Kf[lane] = kd;
  if (lane < N2_) {
    int idx = (layer * H_ + hh) * N2_ + lane;
    float dr64 = -expf(lAr[idx]) * dt * 64.f;
    float di64 = Aim[idx] * dt * 64.f;
    float er = expf(dr64), sn, cs;
    sincosf(di64, &sn, &cs);
    AQG[bid * N2_ + lane] = make_float2(er * cs, er * sn);
  }
  __syncthreads();

  size_t base = (size_t)bid * 4096;
  for (int t = 0; t < 64; ++t) {
    float v = (t <= lane) ? Kf[lane - t] : 0.f;
    TtG[base + lane * 64 + (((t >> 3) ^ (lane & 7)) << 3) + (t & 7)] = f2bf(v);
  }
  {
    int n = lane >> 1, im = lane & 1;
    float dr, di, ctr, cti;
    mode_params(log_dt, Cri, lAr, Aim, layer, hh, n, dt, dr, di, ctr, cti);
    for (int t = 0; t < 64; ++t) {
      float e = (float)(63 - t);
      float er = expf(dr * e), sn, cs;
      sincosf(di * e, &sn, &cs);
      float v = im ? (er * sn) : (er * cs);
      WinG[base + lane * 64 + (((t >> 3) ^ (lane & 7)) << 3) + (t & 7)] = f2bf(v);
    }
  }
  for (int r = 0; r < 64; ++r) {
    int n = r >> 1;
    float dr, di, ctr, cti;
    mode_params(log_dt, Cri, lAr, Aim, layer, hh, n, dt, dr, di, ctr, cti);
    float e = (float)(lane + 1);
    float er = expf(dr * e), sn, cs;
    sincosf(di * e, &sn, &cs);
    float wre = ctr * (er * cs) - cti * (er * sn);
    float wim = ctr * (er * sn) + cti * (er * cs);
    float v = (r & 1) ? -wim : wre;
    unsigned short hi = f2bf(v);
    float lo = v - bf2f(hi);
    size_t off = base + lane * 64 + (((r >> 3) ^ (lane & 7)) << 3) + (r & 7);
    WhiG[off] = hi;
    WloG[off] = f2bf(lo);
  }
}

// ---------------------------------------------------------------------------
// k_wconv: glu_w fp32 -> bf16 pre-swizzled (unchanged)
// ---------------------------------------------------------------------------
__global__ __launch_bounds__(256) void k_wconv(
    const float* __restrict__ gw, unsigned short* __restrict__ wb)
{
  int t = blockIdx.x * 256 + threadIdx.x;
  int uu = t & 7;
  int r  = (t >> 3) & 511;
  int l4 = t >> 12;
  int layer = l4 >> 2, kc4 = l4 & 3;
  int ksrc = kc4 * 64 + ((uu ^ (r & 7)) << 3);
  const float* src = gw + ((size_t)(layer * 512 + r)) * H_ + ksrc;
  unsigned short* dst = wb + (size_t)t * 8;
#pragma unroll
  for (int j = 0; j < 8; ++j) dst[j] = f2bf(src[j]);
}

// ---------------------------------------------------------------------------
// Encoder: now writes bf16 h
// ---------------------------------------------------------------------------
__global__ __launch_bounds__(256) void k_encoder(
    const float* __restrict__ x, const float* __restrict__ ew,
    const float* __restrict__ eb, unsigned short* __restrict__ h)
{
  __shared__ __align__(16) float Wl[32][256];
  __shared__ __align__(16) float Xl[32][32];
  int tid = threadIdx.x;
  int blk = blockIdx.x;
  int b  = blk >> 7;
  int l0 = (blk & 127) << 5;
  int ty = tid >> 3;
  int tx = tid & 7;
  float acc[8][4];
#pragma unroll
  for (int i = 0; i < 8; ++i)
#pragma unroll
    for (int j = 0; j < 4; ++j) acc[i][j] = 0.f;

  for (int kc = 0; kc < DIN; kc += 32) {
    const float4* ew4 = (const float4*)(ew + kc * H_);
#pragma unroll
    for (int it = 0; it < 8; ++it) {
      int idx = tid + (it << 8);
      ((float4*)&Wl[0][0])[idx] = ew4[idx];
    }
    {
      int c = tid >> 3, p = (tid & 7) << 2;
      *(float4*)&Xl[c][p] =
          *(const float4*)(x + ((size_t)(b * DIN + kc + c)) * LSEQ + l0 + p);
    }
    __syncthreads();
#pragma unroll
    for (int k = 0; k < 32; ++k) {
      float4 w0 = *(float4*)&Wl[k][ty * 8];
      float4 w1 = *(float4*)&Wl[k][ty * 8 + 4];
      float4 xv = *(float4*)&Xl[k][tx * 4];
      float wvv[8] = {w0.x, w0.y, w0.z, w0.w, w1.x, w1.y, w1.z, w1.w};
      float xs[4]  = {xv.x, xv.y, xv.z, xv.w};
#pragma unroll
      for (int i = 0; i < 8; ++i)
#pragma unroll
        for (int j = 0; j < 4; ++j) acc[i][j] = fmaf(wvv[i], xs[j], acc[i][j]);
    }
    __syncthreads();
  }
#pragma unroll
  for (int i = 0; i < 8; ++i) {
    int d = ty * 8 + i;
    float bia = eb[d];
    ushort4 o;
    o.x = f2bf(acc[i][0] + bia); o.y = f2bf(acc[i][1] + bia);
    o.z = f2bf(acc[i][2] + bia); o.w = f2bf(acc[i][3] + bia);
    *(ushort4*)(h + ((size_t)(b * H_ + d)) * LSEQ + l0 + tx * 4) = o;
  }
}

// ---------------------------------------------------------------------------
// k_chunk v4: bf16 h input (staging = pure copy+swizzle, no conversion)
// ---------------------------------------------------------------------------
__global__ __launch_bounds__(256, 4) void k_chunk(
    const unsigned short* __restrict__ hin, unsigned short* __restrict__ G,
    const unsigned short* __restrict__ TtG, const unsigned short* __restrict__ WinG,
    const unsigned short* __restrict__ WhiG, const unsigned short* __restrict__ WloG,
    const float2* __restrict__ AQG, const float* __restrict__ Dsk, int layer)
{
  __shared__ __align__(16) char smem[40960];
  char* Ul    = smem;                      // 8KB bf16 [c][t] swz
  char* TtL   = smem + 8192;               // 8KB: Tt -> Whi
  char* WinL  = smem + 16384;              // 8KB: Win -> Wlo
  float* BstT = (float*)(smem + 24576);    // 16KB f32 [r][c^((r&7)<<2)]
  char* ShiL  = smem + 24576;              // 8KB (after scan)
  char* SloL  = smem + 32768;              // 8KB

  int tid = threadIdx.x;
  int w = tid >> 6, lane = tid & 63;
  int rg = lane >> 4, lc = lane & 15;
  int bid = blockIdx.x;
  int hh = bid >> 5, b = bid & 31;
  size_t wbase = ((size_t)(layer * H_ + hh)) * 4096;
  const unsigned short* Urow = hin + ((size_t)(b * H_ + hh)) * LSEQ;

#pragma unroll
  for (int it = 0; it < 2; ++it) {
    int idx = tid + (it << 8);          // 0..511
    int c = idx >> 3, uu = idx & 7;
    uint4 v = ((const uint4*)Urow)[idx];
    *(uint4*)(Ul + c * 128 + ((uu ^ (c & 7)) << 4)) = v;
    ((uint4*)TtL)[idx]  = ((const uint4*)(TtG + wbase))[idx];
    ((uint4*)WinL)[idx] = ((const uint4*)(WinG + wbase))[idx];
  }
  __syncthreads();

  f32x4 accY[4], accB[4];
#pragma unroll
  for (int nb = 0; nb < 4; ++nb) {
    accY[nb] = (f32x4){0.f, 0.f, 0.f, 0.f};
    accB[nb] = (f32x4){0.f, 0.f, 0.f, 0.f};
  }
#pragma unroll
  for (int ks = 0; ks < 2; ++ks) {
    int ca = w * 16 + lc;
    int u = ks * 4 + rg;
    bf16x8 A = *(const bf16x8*)(Ul + ca * 128 + ((u ^ (ca & 7)) << 4));
#pragma unroll
    for (int nb = 0; nb < 4; ++nb) {
      int col = nb * 16 + lc;
      bf16x8 Bt = *(const bf16x8*)(TtL + col * 128 + ((u ^ (col & 7)) << 4));
      bf16x8 Bw = *(const bf16x8*)(WinL + col * 128 + ((u ^ (col & 7)) << 4));
      accY[nb] = __builtin_amdgcn_mfma_f32_16x16x32_bf16(A, Bt, accY[nb], 0, 0, 0);
      accB[nb] = __builtin_amdgcn_mfma_f32_16x16x32_bf16(A, Bw, accB[nb], 0, 0, 0);
    }
  }
#pragma unroll
  for (int nb = 0; nb < 4; ++nb)
#pragma unroll
    for (int reg = 0; reg < 4; ++reg) {
      int r = nb * 16 + lc;
      int cc = w * 16 + rg * 4 + reg;
      BstT[r * 64 + (cc ^ ((r & 7) << 2))] = accB[nb][reg];
    }
  __syncthreads();

  float Sr[8], Si[8], Mr[8], Mi[8];
  int c = lane;
  {
    const float2* aqb = AQG + (size_t)(layer * H_ + hh) * N2_ + w * 8;
#pragma unroll
    for (int q = 0; q < 8; ++q) {
      float2 aq = aqb[q];
      Mr[q] = aq.x; Mi[q] = aq.y;
      int r0 = (w * 8 + q) * 2, r1 = r0 + 1;
      Sr[q] = BstT[r0 * 64 + (c ^ ((r0 & 7) << 2))];
      Si[q] = BstT[r1 * 64 + (c ^ ((r1 & 7) << 2))];
    }
  }
  uint4 wst[4];
#pragma unroll
  for (int i = 0; i < 2; ++i) {
    wst[i]     = ((const uint4*)(WhiG + wbase))[tid + (i << 8)];
    wst[i + 2] = ((const uint4*)(WloG + wbase))[tid + (i << 8)];
  }
  __syncthreads();

#pragma unroll
  for (int dd = 0; dd < 6; ++dd) {
    int d = 1 << dd;
#pragma unroll
    for (int q = 0; q < 8; ++q) {
      float pr = __shfl_up(Sr[q], (unsigned)d);
      float pi = __shfl_up(Si[q], (unsigned)d);
      if (lane >= d) {
        Sr[q] = fmaf(Mr[q], pr, fmaf(-Mi[q], pi, Sr[q]));
        Si[q] = fmaf(Mr[q], pi, fmaf(Mi[q], pr, Si[q]));
      }
      if (dd < 5) {
        float t = fmaf(Mr[q], Mr[q], -Mi[q] * Mi[q]);
        Mi[q] = 2.f * Mr[q] * Mi[q];
        Mr[q] = t;
      }
    }
  }
#pragma unroll
  for (int q = 0; q < 8; ++q) {
    float pr = __shfl_up(Sr[q], 1u);
    float pi = __shfl_up(Si[q], 1u);
    Sr[q] = (lane == 0) ? 0.f : pr;
    Si[q] = (lane == 0) ? 0.f : pi;
  }
#pragma unroll
  for (int q = 0; q < 8; ++q) {
    int n = w * 8 + q;
    unsigned short hr = f2bf(Sr[q]), hi_ = f2bf(Si[q]);
    unsigned hiw = (unsigned)hr | ((unsigned)hi_ << 16);
    unsigned low = (unsigned)f2bf(Sr[q] - bf2f(hr)) |
                   ((unsigned)f2bf(Si[q] - bf2f(hi_)) << 16);
    int boff = c * 128 + (((n >> 2) ^ (c & 7)) << 4) + (((2 * n) & 7) << 1);
    *(unsigned*)(ShiL + boff) = hiw;
    *(unsigned*)(SloL + boff) = low;
  }
#pragma unroll
  for (int i = 0; i < 2; ++i) {
    ((uint4*)TtL)[tid + (i << 8)]  = wst[i];
    ((uint4*)WinL)[tid + (i << 8)] = wst[i + 2];
  }
  __syncthreads();

#pragma unroll
  for (int ks = 0; ks < 2; ++ks) {
    int ca = w * 16 + lc;
    int u = ks * 4 + rg;
    bf16x8 Ah = *(const bf16x8*)(ShiL + ca * 128 + ((u ^ (ca & 7)) << 4));
    bf16x8 Al = *(const bf16x8*)(SloL + ca * 128 + ((u ^ (ca & 7)) << 4));
#pragma unroll
    for (int nb = 0; nb < 4; ++nb) {
      int col = nb * 16 + lc;
      bf16x8 Wh = *(const bf16x8*)(TtL + col * 128 + ((u ^ (col & 7)) << 4));
      bf16x8 Wl2 = *(const bf16x8*)(WinL + col * 128 + ((u ^ (col & 7)) << 4));
      accY[nb] = __builtin_amdgcn_mfma_f32_16x16x32_bf16(Ah, Wh, accY[nb], 0, 0, 0);
      accY[nb] = __builtin_amdgcn_mfma_f32_16x16x32_bf16(Al, Wh, accY[nb], 0, 0, 0);
      accY[nb] = __builtin_amdgcn_mfma_f32_16x16x32_bf16(Ah, Wl2, accY[nb], 0, 0, 0);
    }
  }
  __syncthreads();

  float dsk = Dsk[layer * H_ + hh];
  unsigned short* Yl = (unsigned short*)(smem + 24576);
#pragma unroll
  for (int nb = 0; nb < 4; ++nb) {
#pragma unroll
    for (int reg = 0; reg < 4; ++reg) {
      int cc = w * 16 + rg * 4 + reg;
      int i = nb * 16 + lc;
      unsigned short ub = *(unsigned short*)(
          Ul + cc * 128 + (((i >> 3) ^ (cc & 7)) << 4) + (i & 7) * 2);
      float yv = fmaf(dsk, bf2f(ub), accY[nb][reg]);
      float ge = 0.5f * yv * (1.f + erff(yv * 0.70710678118f));
      Yl[cc * 64 + i] = f2bf(ge);
    }
  }
  __syncthreads();
  unsigned short* Gr = G + ((size_t)(b * H_ + hh)) * LSEQ;
#pragma unroll
  for (int it = 0; it < 2; ++it) {
    int idx = tid + (it << 8);
    *(uint4*)(Gr + idx * 8) = ((uint4*)Yl)[idx];
  }
}

// ---------------------------------------------------------------------------
// GLU via bf16 MFMA + fused residual + LayerNorm; h now bf16
// ---------------------------------------------------------------------------
__global__ __launch_bounds__(512, 4) void k_glu(
    const unsigned short* __restrict__ Wb, const unsigned short* __restrict__ G,
    unsigned short* __restrict__ h, const float* __restrict__ gb,
    const float* __restrict__ lng, const float* __restrict__ lnb, int layer)
{
  extern __shared__ char smem[];
  char* WlB = smem;
  char* GlB = smem + 65536;
  float2* Red = (float2*)(smem + 65536 + 8192);

  int tid = threadIdx.x;
  int w = tid >> 6, lane = tid & 63;
  int b  = blockIdx.x >> 6;
  int l0 = (blockIdx.x & 63) << 6;
  int rgrp = lane >> 4, lc = lane & 15;

  f32x4 acc[4][4];
#pragma unroll
  for (int m = 0; m < 4; ++m)
#pragma unroll
    for (int n = 0; n < 4; ++n) acc[m][n] = (f32x4){0.f, 0.f, 0.f, 0.f};

  const unsigned short* wsrc = Wb + (size_t)(layer * 4) * 512 * 64;

  for (int kc4 = 0; kc4 < 4; ++kc4) {
    if (kc4) __syncthreads();
    const unsigned short* wc = wsrc + (size_t)kc4 * 512 * 64;
#pragma unroll
    for (int i = 0; i < 8; ++i) {
      int off = w * 8192 + i * 1024 + lane * 16;
      uint4 v = *(const uint4*)((const char*)wc + off);
      *(uint4*)(WlB + off) = v;
    }
    {
      int col = lane;
      int kc = kc4 * 64;
      size_t base = (size_t)(b * H_ + kc + w * 8) * LSEQ + l0 + col;
      unsigned v0 = G[base];
      unsigned v1 = G[base + (size_t)1 * LSEQ];
      unsigned v2 = G[base + (size_t)2 * LSEQ];
      unsigned v3 = G[base + (size_t)3 * LSEQ];
      unsigned v4 = G[base + (size_t)4 * LSEQ];
      unsigned v5 = G[base + (size_t)5 * LSEQ];
      unsigned v6 = G[base + (size_t)6 * LSEQ];
      unsigned v7 = G[base + (size_t)7 * LSEQ];
      unsigned pk0 = v0 | (v1 << 16), pk1 = v2 | (v3 << 16);
      unsigned pk2 = v4 | (v5 << 16), pk3 = v6 | (v7 << 16);
      *(uint4*)(GlB + col * 128 + ((w ^ (col & 7)) << 4)) =
          make_uint4(pk0, pk1, pk2, pk3);
    }
    __syncthreads();
#pragma unroll
    for (int ks = 0; ks < 2; ++ks) {
      int u = ks * 4 + rgrp;
      bf16x8 af[4], bff[4];
#pragma unroll
      for (int m = 0; m < 4; ++m) {
        int grow = ((m < 2) ? (w * 32 + m * 16) : (256 + w * 32 + (m - 2) * 16)) + lc;
        af[m] = *(const bf16x8*)(WlB + grow * 128 + ((u ^ (grow & 7)) << 4));
      }
#pragma unroll
      for (int n = 0; n < 4; ++n) {
        int gcol = n * 16 + lc;
        bff[n] = *(const bf16x8*)(GlB + gcol * 128 + ((u ^ (gcol & 7)) << 4));
      }
#pragma unroll
      for (int m = 0; m < 4; ++m)
#pragma unroll
        for (int n = 0; n < 4; ++n)
          acc[m][n] = __builtin_amdgcn_mfma_f32_16x16x32_bf16(
              af[m], bff[n], acc[m][n], 0, 0, 0);
    }
  }

  const float* gbL = gb + layer * 2 * H_;
  float out[2][4][4];
  float s[4], ss[4];
#pragma unroll
  for (int n = 0; n < 4; ++n) { s[n] = 0.f; ss[n] = 0.f; }
#pragma unroll
  for (int mA = 0; mA < 2; ++mA) {
#pragma unroll
    for (int reg = 0; reg < 4; ++reg) {
      int ch = w * 32 + mA * 16 + rgrp * 4 + reg;
      float ba = gbL[ch], bg = gbL[ch + H_];
#pragma unroll
      for (int n = 0; n < 4; ++n) {
        int col = n * 16 + lc;
        size_t off = (size_t)(b * H_ + ch) * LSEQ + l0 + col;
        float a = acc[mA][n][reg] + ba;
        float gv = acc[mA + 2][n][reg] + bg;
        float sg = 1.f / (1.f + expf(-gv));
        float o = fmaf(a, sg, bf2f(h[off]));
        out[mA][n][reg] = o;
        s[n] += o; ss[n] = fmaf(o, o, ss[n]);
      }
    }
  }
#pragma unroll
  for (int n = 0; n < 4; ++n) {
    s[n]  += __shfl_xor(s[n], 16);  s[n]  += __shfl_xor(s[n], 32);
    ss[n] += __shfl_xor(ss[n], 16); ss[n] += __shfl_xor(ss[n], 32);
  }
  if (lane < 16) {
#pragma unroll
    for (int n = 0; n < 4; ++n)
      Red[w * 64 + n * 16 + lane] = make_float2(s[n], ss[n]);
  }
  __syncthreads();
  float mu[4], rs[4];
#pragma unroll
  for (int n = 0; n < 4; ++n) {
    int col = n * 16 + lc;
    float ts = 0.f, tss = 0.f;
#pragma unroll
    for (int ww = 0; ww < 8; ++ww) {
      float2 v = Red[ww * 64 + col];
      ts += v.x; tss += v.y;
    }
    mu[n] = ts * (1.f / H_);
    rs[n] = rsqrtf(tss * (1.f / H_) - mu[n] * mu[n] + LN_EPSF);
  }
#pragma unroll
  for (int mA = 0; mA < 2; ++mA) {
#pragma unroll
    for (int reg = 0; reg < 4; ++reg) {
      int ch = w * 32 + mA * 16 + rgrp * 4 + reg;
      float lg = lng[layer * H_ + ch], lb = lnb[layer * H_ + ch];
#pragma unroll
      for (int n = 0; n < 4; ++n) {
        int col = n * 16 + lc;
        size_t off = (size_t)(b * H_ + ch) * LSEQ + l0 + col;
        h[off] = f2bf((out[mA][n][reg] - mu[n]) * rs[n] * lg + lb);
      }
    }
  }
}

// ---------------------------------------------------------------------------
// k_pool: mean over L per (b,h) row (bf16 input). One wave per row.
// ---------------------------------------------------------------------------
__global__ __launch_bounds__(256) void k_pool(
    const unsigned short* __restrict__ h, float* __restrict__ P)
{
  int row = blockIdx.x * 4 + (threadIdx.x >> 6);    // b*H + ch
  int lane = threadIdx.x & 63;
  const uint4* src = (const uint4*)(h + (size_t)row * LSEQ);
  float s = 0.f;
#pragma unroll
  for (int i = 0; i < 8; ++i) {
    uint4 v = src[lane + i * 64];
    unsigned ws[4] = {v.x, v.y, v.z, v.w};
#pragma unroll
    for (int j = 0; j < 4; ++j) {
      s += bf2f((unsigned short)(ws[j] & 0xFFFFu));
      s += bf2f((unsigned short)(ws[j] >> 16));
    }
  }
#pragma unroll
  for (int d = 1; d < 64; d <<= 1) s += __shfl_xor(s, d);
  if (lane == 0) P[row] = s * (1.f / LSEQ);
}

// ---------------------------------------------------------------------------
// k_dec: decode (256->2) + softmax from pooled P. grid B, block 64.
// ---------------------------------------------------------------------------
__global__ __launch_bounds__(64) void k_dec(
    const float* __restrict__ P, const float* __restrict__ dw,
    const float* __restrict__ db, float* __restrict__ out)
{
  int b = blockIdx.x, lane = threadIdx.x;
  float z0 = 0.f, z1 = 0.f;
#pragma unroll
  for (int i = 0; i < 4; ++i) {
    int k = lane + i * 64;
    float p = P[b * H_ + k];
    z0 = fmaf(p, dw[k * DOUT + 0], z0);
    z1 = fmaf(p, dw[k * DOUT + 1], z1);
  }
#pragma unroll
  for (int d = 1; d < 64; d <<= 1) {
    z0 += __shfl_xor(z0, d);
    z1 += __shfl_xor(z1, d);
  }
  if (lane == 0) {
    z0 += db[0]; z1 += db[1];
    float m = fmaxf(z0, z1);
    float e0 = expf(z0 - m), e1 = expf(z1 - m);
    float inv = 1.f / (e0 + e1);
    out[b * 2 + 0] = e0 * inv;
    out[b * 2 + 1] = e1 * inv;
  }
}

// ---------------------------------------------------------------------------
extern "C" void kernel_launch(void* const* d_in, const int* in_sizes, int n_in,
                              void* d_out, int out_size, void* d_ws, size_t ws_size,
                              hipStream_t stream) {
  (void)in_sizes; (void)n_in; (void)out_size; (void)ws_size;
  const float* x      = (const float*)d_in[0];
  const float* enc_w  = (const float*)d_in[1];
  const float* enc_b  = (const float*)d_in[2];
  const float* log_dt = (const float*)d_in[3];
  const float* Cri    = (const float*)d_in[4];
  const float* lAr    = (const float*)d_in[5];
  const float* Aim    = (const float*)d_in[6];
  const float* Dsk    = (const float*)d_in[7];
  const float* glu_w  = (const float*)d_in[8];
  const float* glu_b  = (const float*)d_in[9];
  const float* ln_g   = (const float*)d_in[10];
  const float* ln_b   = (const float*)d_in[11];
  const float* dec_w  = (const float*)d_in[12];
  const float* dec_b  = (const float*)d_in[13];
  float* out = (float*)d_out;

  unsigned short* h   = (unsigned short*)d_ws;               // 64 MB bf16
  unsigned short* G   = h + (size_t)B_ * H_ * LSEQ;          // 64 MB bf16
  unsigned short* Wb  = G + (size_t)B_ * H_ * LSEQ;          // 1 MB
  unsigned short* TtG = Wb + 524288;                         // 8 MB
  unsigned short* WinG = TtG + 4194304;                      // 8 MB
  unsigned short* WhiG = WinG + 4194304;                     // 8 MB
  unsigned short* WloG = WhiG + 4194304;                     // 8 MB
  float2* AQG = (float2*)(WloG + 4194304);                   // 256 KB
  float* P    = (float*)(AQG + NL_ * H_ * N2_);              // 32 KB

  k_wconv<<<256, 256, 0, stream>>>(glu_w, Wb);
  k_prep<<<NL_ * H_, 64, 0, stream>>>(log_dt, Cri, lAr, Aim, TtG, WinG, WhiG, WloG, AQG);
  k_encoder<<<B_ * (LSEQ / 32), 256, 0, stream>>>(x, enc_w, enc_b, h);
  for (int i = 0; i < NL_; ++i) {
    k_chunk<<<H_ * B_, 256, 0, stream>>>(h, G, TtG, WinG, WhiG, WloG,
                                         AQG, Dsk, i);
    k_glu<<<B_ * (LSEQ / 64), 512, 77824, stream>>>(Wb, G, h, glu_b, ln_g, ln_b, i);
  }
  k_pool<<<(B_ * H_) / 4, 256, 0, stream>>>(h, P);
  k_dec<<<B_, 64, 0, stream>>>(P, dec_w, dec_b, out);
}

// Round 11
// 868.334 us; speedup vs baseline: 4.1868x; 1.0883x over previous
//
#include <hip/hip_runtime.h>
#include <math.h>

#define B_    32
#define DIN   64
#define LSEQ  4096
#define H_    256
#define N2_   32
#define NL_   4
#define DOUT  2
#define LN_EPSF 1e-5f

typedef __bf16 bf16x8 __attribute__((ext_vector_type(8)));
typedef float  f32x4  __attribute__((ext_vector_type(4)));

__device__ inline unsigned short f2bf(float f) {
  unsigned u = __builtin_bit_cast(unsigned, f);
  u += 0x7FFFu + ((u >> 16) & 1u);
  return (unsigned short)(u >> 16);
}
__device__ inline float bf2f(unsigned short u) {
  return __builtin_bit_cast(float, ((unsigned)u) << 16);
}

// async 16B global->LDS copy: lds base must be wave-uniform (HW adds lane*16)
__device__ inline void gl_lds16(const void* g, void* l) {
  __builtin_amdgcn_global_load_lds(
      (const __attribute__((address_space(1))) void*)g,
      (__attribute__((address_space(3))) void*)l, 16, 0, 0);
}

// A&S 7.1.26 erf, |err| <= 1.5e-7
__device__ inline float erf_fast(float x) {
  float ax = fabsf(x);
  float t = __builtin_amdgcn_rcpf(fmaf(0.3275911f, ax, 1.f));
  float p = fmaf(1.061405429f, t, -1.453152027f);
  p = fmaf(p, t, 1.421413741f);
  p = fmaf(p, t, -0.284496736f);
  p = fmaf(p, t, 0.254829592f);
  float e = __expf(-ax * ax);
  float r = 1.f - p * t * e;
  return copysignf(r, x);
}

// ZOH discretization params for mode n of (layer, hh)
__device__ inline void mode_params(const float* log_dt, const float* Cri,
                                   const float* lAr, const float* Aim,
                                   int layer, int hh, int n, float dt,
                                   float& dr, float& di, float& ctr, float& cti) {
  int idx = (layer * H_ + hh) * N2_ + n;
  float Are = -expf(lAr[idx]);
  float Aimv = Aim[idx];
  dr = Are * dt; di = Aimv * dt;
  float er = expf(dr), sn, cs;
  sincosf(di, &sn, &cs);
  float arr = er * cs, aii = er * sn;
  float nr = arr - 1.f, ni = aii;
  float inv = 1.f / (Are * Are + Aimv * Aimv);
  float qr = (nr * Are + ni * Aimv) * inv;
  float qi = (ni * Are - nr * Aimv) * inv;
  float Cr = Cri[2 * idx], Ci = Cri[2 * idx + 1];
  ctr = 2.f * (Cr * qr - Ci * qi);
  cti = 2.f * (Cr * qi + Ci * qr);
}

// ---------------------------------------------------------------------------
// k_prep: pre-swizzled bf16 images + a^64 table. D-skip folded into Tt diag.
// ---------------------------------------------------------------------------
__global__ __launch_bounds__(64) void k_prep(
    const float* __restrict__ log_dt, const float* __restrict__ Cri,
    const float* __restrict__ lAr, const float* __restrict__ Aim,
    const float* __restrict__ Dsk,
    unsigned short* __restrict__ TtG, unsigned short* __restrict__ WinG,
    unsigned short* __restrict__ WhiG, unsigned short* __restrict__ WloG,
    float2* __restrict__ AQG)
{
  int bid = blockIdx.x;
  int layer = bid >> 8, hh = bid & 255;
  int lane = threadIdx.x;
  __shared__ float Kf[64];
  float dt = expf(log_dt[layer * H_ + hh]);
  float dsk = Dsk[layer * H_ + hh];

  float kd = 0.f;
  for (int n = 0; n < N2_; ++n) {
    float dr, di, ctr, cti;
    mode_params(log_dt, Cri, lAr, Aim, layer, hh, n, dt, dr, di, ctr, cti);
    float er = expf(dr * (float)lane), sn, cs;
    sincosf(di * (float)lane, &sn, &cs);
    kd += ctr * (er * cs) - cti * (er * sn);
  }
  Kf[lane] = kd;
  if (lane < N2_) {
    int idx = (layer * H_ + hh) * N2_ + lane;
    float dr64 = -expf(lAr[idx]) * dt * 64.f;
    float di64 = Aim[idx] * dt * 64.f;
    float er = expf(dr64), sn, cs;
    sincosf(di64, &sn, &cs);
    AQG[bid * N2_ + lane] = make_float2(er * cs, er * sn);
  }
  __syncthreads();

  size_t base = (size_t)bid * 4096;
  for (int t = 0; t < 64; ++t) {
    float v = (t <= lane) ? (Kf[lane - t] + ((t == lane) ? dsk : 0.f)) : 0.f;
    TtG[base + lane * 64 + (((t >> 3) ^ (lane & 7)) << 3) + (t & 7)] = f2bf(v);
  }
  {
    int n = lane >> 1, im = lane & 1;
    float dr, di, ctr, cti;
    mode_params(log_dt, Cri, lAr, Aim, layer, hh, n, dt, dr, di, ctr, cti);
    for (int t = 0; t < 64; ++t) {
      float e = (float)(63 - t);
      float er = expf(dr * e), sn, cs;
      sincosf(di * e, &sn, &cs);
      float v = im ? (er * sn) : (er * cs);
      WinG[base + lane * 64 + (((t >> 3) ^ (lane & 7)) << 3) + (t & 7)] = f2bf(v);
    }
  }
  for (int r = 0; r < 64; ++r) {
    int n = r >> 1;
    float dr, di, ctr, cti;
    mode_params(log_dt, Cri, lAr, Aim, layer, hh, n, dt, dr, di, ctr, cti);
    float e = (float)(lane + 1);
    float er = expf(dr * e), sn, cs;
    sincosf(di * e, &sn, &cs);
    float wre = ctr * (er * cs) - cti * (er * sn);
    float wim = ctr * (er * sn) + cti * (er * cs);
    float v = (r & 1) ? -wim : wre;
    unsigned short hi = f2bf(v);
    float lo = v - bf2f(hi);
    size_t off = base + lane * 64 + (((r >> 3) ^ (lane & 7)) << 3) + (r & 7);
    WhiG[off] = hi;
    WloG[off] = f2bf(lo);
  }
}

// ---------------------------------------------------------------------------
// k_wconv: glu_w fp32 -> bf16 pre-swizzled (unchanged)
// ---------------------------------------------------------------------------
__global__ __launch_bounds__(256) void k_wconv(
    const float* __restrict__ gw, unsigned short* __restrict__ wb)
{
  int t = blockIdx.x * 256 + threadIdx.x;
  int uu = t & 7;
  int r  = (t >> 3) & 511;
  int l4 = t >> 12;
  int layer = l4 >> 2, kc4 = l4 & 3;
  int ksrc = kc4 * 64 + ((uu ^ (r & 7)) << 3);
  const float* src = gw + ((size_t)(layer * 512 + r)) * H_ + ksrc;
  unsigned short* dst = wb + (size_t)t * 8;
#pragma unroll
  for (int j = 0; j < 8; ++j) dst[j] = f2bf(src[j]);
}

// ---------------------------------------------------------------------------
// Encoder: writes bf16 h PRE-SWIZZLED (chunk-unit xor swizzle in global)
// ---------------------------------------------------------------------------
__global__ __launch_bounds__(256) void k_encoder(
    const float* __restrict__ x, const float* __restrict__ ew,
    const float* __restrict__ eb, unsigned short* __restrict__ h)
{
  __shared__ __align__(16) float Wl[32][256];
  __shared__ __align__(16) float Xl[32][32];
  int tid = threadIdx.x;
  int blk = blockIdx.x;
  int b  = blk >> 7;
  int l0 = (blk & 127) << 5;
  int ty = tid >> 3;
  int tx = tid & 7;
  float acc[8][4];
#pragma unroll
  for (int i = 0; i < 8; ++i)
#pragma unroll
    for (int j = 0; j < 4; ++j) acc[i][j] = 0.f;

  for (int kc = 0; kc < DIN; kc += 32) {
    const float4* ew4 = (const float4*)(ew + kc * H_);
#pragma unroll
    for (int it = 0; it < 8; ++it) {
      int idx = tid + (it << 8);
      ((float4*)&Wl[0][0])[idx] = ew4[idx];
    }
    {
      int c = tid >> 3, p = (tid & 7) << 2;
      *(float4*)&Xl[c][p] =
          *(const float4*)(x + ((size_t)(b * DIN + kc + c)) * LSEQ + l0 + p);
    }
    __syncthreads();
#pragma unroll
    for (int k = 0; k < 32; ++k) {
      float4 w0 = *(float4*)&Wl[k][ty * 8];
      float4 w1 = *(float4*)&Wl[k][ty * 8 + 4];
      float4 xv = *(float4*)&Xl[k][tx * 4];
      float wvv[8] = {w0.x, w0.y, w0.z, w0.w, w1.x, w1.y, w1.z, w1.w};
      float xs[4]  = {xv.x, xv.y, xv.z, xv.w};
#pragma unroll
      for (int i = 0; i < 8; ++i)
#pragma unroll
        for (int j = 0; j < 4; ++j) acc[i][j] = fmaf(wvv[i], xs[j], acc[i][j]);
    }
    __syncthreads();
  }
  // swizzled store: l = l0 + tx*4 (4 elems within one 8-elem unit)
  int l = l0 + tx * 4;
  int cch = l >> 6;
  int uu  = (l & 63) >> 3;
  int j8  = l & 7;
  size_t soff = (cch << 6) + (((uu ^ (cch & 7))) << 3) + j8;
#pragma unroll
  for (int i = 0; i < 8; ++i) {
    int d = ty * 8 + i;
    float bia = eb[d];
    ushort4 o;
    o.x = f2bf(acc[i][0] + bia); o.y = f2bf(acc[i][1] + bia);
    o.z = f2bf(acc[i][2] + bia); o.w = f2bf(acc[i][3] + bia);
    *(ushort4*)(h + ((size_t)(b * H_ + d)) * LSEQ + soff) = o;
  }
}

// ---------------------------------------------------------------------------
// k_chunk v5: pre-swizzled h -> pure global_load_lds staging; D-skip folded
// into Tt; fast-erf GELU epilogue (no U re-read).
// ---------------------------------------------------------------------------
__global__ __launch_bounds__(256, 4) void k_chunk(
    const unsigned short* __restrict__ hin, unsigned short* __restrict__ G,
    const unsigned short* __restrict__ TtG, const unsigned short* __restrict__ WinG,
    const unsigned short* __restrict__ WhiG, const unsigned short* __restrict__ WloG,
    const float2* __restrict__ AQG, int layer)
{
  __shared__ __align__(16) char smem[40960];
  char* Ul    = smem;                      // 8KB bf16 [c][t] swz
  char* TtL   = smem + 8192;               // 8KB: Tt -> Whi
  char* WinL  = smem + 16384;              // 8KB: Win -> Wlo
  float* BstT = (float*)(smem + 24576);    // 16KB f32 [r][c^((r&7)<<2)]
  char* ShiL  = smem + 24576;              // 8KB (after scan)
  char* SloL  = smem + 32768;              // 8KB

  int tid = threadIdx.x;
  int w = tid >> 6, lane = tid & 63;
  int rg = lane >> 4, lc = lane & 15;
  int bid = blockIdx.x;
  int hh = bid >> 5, b = bid & 31;
  size_t wbase = ((size_t)(layer * H_ + hh)) * 4096;
  const unsigned short* Urow = hin + ((size_t)(b * H_ + hh)) * LSEQ;

  // ---- stage U/Tt/Win via async DMA (all linear copies) ----
#pragma unroll
  for (int it = 0; it < 2; ++it) {
    int idx = tid + (it << 8);                 // per-lane global index
    int ubase = (w * 64 + (it << 8)) * 16;     // wave-uniform LDS byte base
    gl_lds16(((const uint4*)Urow) + idx, Ul + ubase);
    gl_lds16(((const uint4*)(TtG + wbase)) + idx, TtL + ubase);
    gl_lds16(((const uint4*)(WinG + wbase)) + idx, WinL + ubase);
  }
  __syncthreads();

  // ---- phase 1 GEMMs: Yloc = U@Tt', Bst = U@Win' ----
  f32x4 accY[4], accB[4];
#pragma unroll
  for (int nb = 0; nb < 4; ++nb) {
    accY[nb] = (f32x4){0.f, 0.f, 0.f, 0.f};
    accB[nb] = (f32x4){0.f, 0.f, 0.f, 0.f};
  }
#pragma unroll
  for (int ks = 0; ks < 2; ++ks) {
    int ca = w * 16 + lc;
    int u = ks * 4 + rg;
    bf16x8 A = *(const bf16x8*)(Ul + ca * 128 + ((u ^ (ca & 7)) << 4));
#pragma unroll
    for (int nb = 0; nb < 4; ++nb) {
      int col = nb * 16 + lc;
      bf16x8 Bt = *(const bf16x8*)(TtL + col * 128 + ((u ^ (col & 7)) << 4));
      bf16x8 Bw = *(const bf16x8*)(WinL + col * 128 + ((u ^ (col & 7)) << 4));
      accY[nb] = __builtin_amdgcn_mfma_f32_16x16x32_bf16(A, Bt, accY[nb], 0, 0, 0);
      accB[nb] = __builtin_amdgcn_mfma_f32_16x16x32_bf16(A, Bw, accB[nb], 0, 0, 0);
    }
  }
#pragma unroll
  for (int nb = 0; nb < 4; ++nb)
#pragma unroll
    for (int reg = 0; reg < 4; ++reg) {
      int r = nb * 16 + lc;
      int cc = w * 16 + rg * 4 + reg;
      BstT[r * 64 + (cc ^ ((r & 7) << 2))] = accB[nb][reg];
    }
  __syncthreads();

  // ---- issue Whi/Wlo DMA into TtL/WinL (lands during scan) ----
#pragma unroll
  for (int it = 0; it < 2; ++it) {
    int idx = tid + (it << 8);
    int ubase = (w * 64 + (it << 8)) * 16;
    gl_lds16(((const uint4*)(WhiG + wbase)) + idx, TtL + ubase);
    gl_lds16(((const uint4*)(WloG + wbase)) + idx, WinL + ubase);
  }

  // ---- phase 2: wave-parallel chunk scan ----
  float Sr[8], Si[8], Mr[8], Mi[8];
  int c = lane;
  {
    const float2* aqb = AQG + (size_t)(layer * H_ + hh) * N2_ + w * 8;
#pragma unroll
    for (int q = 0; q < 8; ++q) {
      float2 aq = aqb[q];
      Mr[q] = aq.x; Mi[q] = aq.y;
      int r0 = (w * 8 + q) * 2, r1 = r0 + 1;
      Sr[q] = BstT[r0 * 64 + (c ^ ((r0 & 7) << 2))];
      Si[q] = BstT[r1 * 64 + (c ^ ((r1 & 7) << 2))];
    }
  }
  __syncthreads();   // BstT reads done before Shi/Slo overwrite

#pragma unroll
  for (int dd = 0; dd < 6; ++dd) {
    int d = 1 << dd;
#pragma unroll
    for (int q = 0; q < 8; ++q) {
      float pr = __shfl_up(Sr[q], (unsigned)d);
      float pi = __shfl_up(Si[q], (unsigned)d);
      if (lane >= d) {
        Sr[q] = fmaf(Mr[q], pr, fmaf(-Mi[q], pi, Sr[q]));
        Si[q] = fmaf(Mr[q], pi, fmaf(Mi[q], pr, Si[q]));
      }
      if (dd < 5) {
        float t = fmaf(Mr[q], Mr[q], -Mi[q] * Mi[q]);
        Mi[q] = 2.f * Mr[q] * Mi[q];
        Mr[q] = t;
      }
    }
  }
#pragma unroll
  for (int q = 0; q < 8; ++q) {
    float pr = __shfl_up(Sr[q], 1u);
    float pi = __shfl_up(Si[q], 1u);
    Sr[q] = (lane == 0) ? 0.f : pr;
    Si[q] = (lane == 0) ? 0.f : pi;
  }
#pragma unroll
  for (int q = 0; q < 8; ++q) {
    int n = w * 8 + q;
    unsigned short hr = f2bf(Sr[q]), hi_ = f2bf(Si[q]);
    unsigned hiw = (unsigned)hr | ((unsigned)hi_ << 16);
    unsigned low = (unsigned)f2bf(Sr[q] - bf2f(hr)) |
                   ((unsigned)f2bf(Si[q] - bf2f(hi_)) << 16);
    int boff = c * 128 + (((n >> 2) ^ (c & 7)) << 4) + (((2 * n) & 7) << 1);
    *(unsigned*)(ShiL + boff) = hiw;
    *(unsigned*)(SloL + boff) = low;
  }
  __syncthreads();   // drains Whi/Wlo DMA + Shi/Slo writes

  // ---- phase 3: correction GEMMs ----
#pragma unroll
  for (int ks = 0; ks < 2; ++ks) {
    int ca = w * 16 + lc;
    int u = ks * 4 + rg;
    bf16x8 Ah = *(const bf16x8*)(ShiL + ca * 128 + ((u ^ (ca & 7)) << 4));
    bf16x8 Al = *(const bf16x8*)(SloL + ca * 128 + ((u ^ (ca & 7)) << 4));
#pragma unroll
    for (int nb = 0; nb < 4; ++nb) {
      int col = nb * 16 + lc;
      bf16x8 Wh = *(const bf16x8*)(TtL + col * 128 + ((u ^ (col & 7)) << 4));
      bf16x8 Wl2 = *(const bf16x8*)(WinL + col * 128 + ((u ^ (col & 7)) << 4));
      accY[nb] = __builtin_amdgcn_mfma_f32_16x16x32_bf16(Ah, Wh, accY[nb], 0, 0, 0);
      accY[nb] = __builtin_amdgcn_mfma_f32_16x16x32_bf16(Al, Wh, accY[nb], 0, 0, 0);
      accY[nb] = __builtin_amdgcn_mfma_f32_16x16x32_bf16(Ah, Wl2, accY[nb], 0, 0, 0);
    }
  }
  __syncthreads();   // phase3 LDS reads done before Yl overwrites Shi

  // ---- epilogue: GELU (D-skip already in Tt), pack, coalesced write ----
  unsigned short* Yl = (unsigned short*)(smem + 24576);
#pragma unroll
  for (int nb = 0; nb < 4; ++nb) {
#pragma unroll
    for (int reg = 0; reg < 4; ++reg) {
      int cc = w * 16 + rg * 4 + reg;
      int i = nb * 16 + lc;
      float yv = accY[nb][reg];
      float ge = 0.5f * yv * (1.f + erf_fast(yv * 0.70710678118f));
      Yl[cc * 64 + i] = f2bf(ge);
    }
  }
  __syncthreads();
  unsigned short* Gr = G + ((size_t)(b * H_ + hh)) * LSEQ;
#pragma unroll
  for (int it = 0; it < 2; ++it) {
    int idx = tid + (it << 8);
    *(uint4*)(Gr + idx * 8) = ((uint4*)Yl)[idx];
  }
}

// ---------------------------------------------------------------------------
// GLU MFMA + residual + LN; W stage via DMA; fast sigmoid; swizzled h access
// ---------------------------------------------------------------------------
__global__ __launch_bounds__(512, 4) void k_glu(
    const unsigned short* __restrict__ Wb, const unsigned short* __restrict__ G,
    unsigned short* __restrict__ h, const float* __restrict__ gb,
    const float* __restrict__ lng, const float* __restrict__ lnb, int layer)
{
  extern __shared__ char smem[];
  char* WlB = smem;
  char* GlB = smem + 65536;
  float2* Red = (float2*)(smem + 65536 + 8192);

  int tid = threadIdx.x;
  int w = tid >> 6, lane = tid & 63;
  int b  = blockIdx.x >> 6;
  int l0 = (blockIdx.x & 63) << 6;
  int rgrp = lane >> 4, lc = lane & 15;
  int cch = l0 >> 6, cs7 = cch & 7;

  f32x4 acc[4][4];
#pragma unroll
  for (int m = 0; m < 4; ++m)
#pragma unroll
    for (int n = 0; n < 4; ++n) acc[m][n] = (f32x4){0.f, 0.f, 0.f, 0.f};

  const unsigned short* wsrc = Wb + (size_t)(layer * 4) * 512 * 64;

  for (int kc4 = 0; kc4 < 4; ++kc4) {
    if (kc4) __syncthreads();
    const unsigned short* wc = wsrc + (size_t)kc4 * 512 * 64;
#pragma unroll
    for (int i = 0; i < 8; ++i) {
      int base = w * 8192 + i * 1024;           // wave-uniform
      gl_lds16((const char*)wc + base + lane * 16, WlB + base);
    }
    {
      int col = lane;
      int kc = kc4 * 64;
      size_t base = (size_t)(b * H_ + kc + w * 8) * LSEQ + l0 + col;
      unsigned v0 = G[base];
      unsigned v1 = G[base + (size_t)1 * LSEQ];
      unsigned v2 = G[base + (size_t)2 * LSEQ];
      unsigned v3 = G[base + (size_t)3 * LSEQ];
      unsigned v4 = G[base + (size_t)4 * LSEQ];
      unsigned v5 = G[base + (size_t)5 * LSEQ];
      unsigned v6 = G[base + (size_t)6 * LSEQ];
      unsigned v7 = G[base + (size_t)7 * LSEQ];
      unsigned pk0 = v0 | (v1 << 16), pk1 = v2 | (v3 << 16);
      unsigned pk2 = v4 | (v5 << 16), pk3 = v6 | (v7 << 16);
      *(uint4*)(GlB + col * 128 + ((w ^ (col & 7)) << 4)) =
          make_uint4(pk0, pk1, pk2, pk3);
    }
    __syncthreads();
#pragma unroll
    for (int ks = 0; ks < 2; ++ks) {
      int u = ks * 4 + rgrp;
      bf16x8 af[4], bff[4];
#pragma unroll
      for (int m = 0; m < 4; ++m) {
        int grow = ((m < 2) ? (w * 32 + m * 16) : (256 + w * 32 + (m - 2) * 16)) + lc;
        af[m] = *(const bf16x8*)(WlB + grow * 128 + ((u ^ (grow & 7)) << 4));
      }
#pragma unroll
      for (int n = 0; n < 4; ++n) {
        int gcol = n * 16 + lc;
        bff[n] = *(const bf16x8*)(GlB + gcol * 128 + ((u ^ (gcol & 7)) << 4));
      }
#pragma unroll
      for (int m = 0; m < 4; ++m)
#pragma unroll
        for (int n = 0; n < 4; ++n)
          acc[m][n] = __builtin_amdgcn_mfma_f32_16x16x32_bf16(
              af[m], bff[n], acc[m][n], 0, 0, 0);
    }
  }

  // swizzled column index for h (pre-swizzled global layout)
  int colS[4];
#pragma unroll
  for (int n = 0; n < 4; ++n) {
    int col = n * 16 + lc;
    colS[n] = ((((col >> 3) ^ cs7)) << 3) | (col & 7);
  }

  const float* gbL = gb + layer * 2 * H_;
  float out[2][4][4];
  float s[4], ss[4];
#pragma unroll
  for (int n = 0; n < 4; ++n) { s[n] = 0.f; ss[n] = 0.f; }
#pragma unroll
  for (int mA = 0; mA < 2; ++mA) {
#pragma unroll
    for (int reg = 0; reg < 4; ++reg) {
      int ch = w * 32 + mA * 16 + rgrp * 4 + reg;
      float ba = gbL[ch], bg = gbL[ch + H_];
#pragma unroll
      for (int n = 0; n < 4; ++n) {
        size_t off = (size_t)(b * H_ + ch) * LSEQ + l0 + colS[n];
        float a = acc[mA][n][reg] + ba;
        float gv = acc[mA + 2][n][reg] + bg;
        float sg = __builtin_amdgcn_rcpf(1.f + __expf(-gv));
        float o = fmaf(a, sg, bf2f(h[off]));
        out[mA][n][reg] = o;
        s[n] += o; ss[n] = fmaf(o, o, ss[n]);
      }
    }
  }
#pragma unroll
  for (int n = 0; n < 4; ++n) {
    s[n]  += __shfl_xor(s[n], 16);  s[n]  += __shfl_xor(s[n], 32);
    ss[n] += __shfl_xor(ss[n], 16); ss[n] += __shfl_xor(ss[n], 32);
  }
  if (lane < 16) {
#pragma unroll
    for (int n = 0; n < 4; ++n)
      Red[w * 64 + n * 16 + lane] = make_float2(s[n], ss[n]);
  }
  __syncthreads();
  float mu[4], rs[4];
#pragma unroll
  for (int n = 0; n < 4; ++n) {
    int col = n * 16 + lc;
    float ts = 0.f, tss = 0.f;
#pragma unroll
    for (int ww = 0; ww < 8; ++ww) {
      float2 v = Red[ww * 64 + col];
      ts += v.x; tss += v.y;
    }
    mu[n] = ts * (1.f / H_);
    rs[n] = rsqrtf(tss * (1.f / H_) - mu[n] * mu[n] + LN_EPSF);
  }
#pragma unroll
  for (int mA = 0; mA < 2; ++mA) {
#pragma unroll
    for (int reg = 0; reg < 4; ++reg) {
      int ch = w * 32 + mA * 16 + rgrp * 4 + reg;
      float lg = lng[layer * H_ + ch], lb = lnb[layer * H_ + ch];
#pragma unroll
      for (int n = 0; n < 4; ++n) {
        size_t off = (size_t)(b * H_ + ch) * LSEQ + l0 + colS[n];
        h[off] = f2bf((out[mA][n][reg] - mu[n]) * rs[n] * lg + lb);
      }
    }
  }
}

// ---------------------------------------------------------------------------
// k_pool: mean over L per (b,h) row (bf16, order-invariant vs swizzle)
// ---------------------------------------------------------------------------
__global__ __launch_bounds__(256) void k_pool(
    const unsigned short* __restrict__ h, float* __restrict__ P)
{
  int row = blockIdx.x * 4 + (threadIdx.x >> 6);
  int lane = threadIdx.x & 63;
  const uint4* src = (const uint4*)(h + (size_t)row * LSEQ);
  float s = 0.f;
#pragma unroll
  for (int i = 0; i < 8; ++i) {
    uint4 v = src[lane + i * 64];
    unsigned ws[4] = {v.x, v.y, v.z, v.w};
#pragma unroll
    for (int j = 0; j < 4; ++j) {
      s += bf2f((unsigned short)(ws[j] & 0xFFFFu));
      s += bf2f((unsigned short)(ws[j] >> 16));
    }
  }
#pragma unroll
  for (int d = 1; d < 64; d <<= 1) s += __shfl_xor(s, d);
  if (lane == 0) P[row] = s * (1.f / LSEQ);
}

// ---------------------------------------------------------------------------
// k_dec: decode (256->2) + softmax. grid B, block 64.
// ---------------------------------------------------------------------------
__global__ __launch_bounds__(64) void k_dec(
    const float* __restrict__ P, const float* __restrict__ dw,
    const float* __restrict__ db, float* __restrict__ out)
{
  int b = blockIdx.x, lane = threadIdx.x;
  float z0 = 0.f, z1 = 0.f;
#pragma unroll
  for (int i = 0; i < 4; ++i) {
    int k = lane + i * 64;
    float p = P[b * H_ + k];
    z0 = fmaf(p, dw[k * DOUT + 0], z0);
    z1 = fmaf(p, dw[k * DOUT + 1], z1);
  }
#pragma unroll
  for (int d = 1; d < 64; d <<= 1) {
    z0 += __shfl_xor(z0, d);
    z1 += __shfl_xor(z1, d);
  }
  if (lane == 0) {
    z0 += db[0]; z1 += db[1];
    float m = fmaxf(z0, z1);
    float e0 = expf(z0 - m), e1 = expf(z1 - m);
    float inv = 1.f / (e0 + e1);
    out[b * 2 + 0] = e0 * inv;
    out[b * 2 + 1] = e1 * inv;
  }
}

// ---------------------------------------------------------------------------
extern "C" void kernel_launch(void* const* d_in, const int* in_sizes, int n_in,
                              void* d_out, int out_size, void* d_ws, size_t ws_size,
                              hipStream_t stream) {
  (void)in_sizes; (void)n_in; (void)out_size; (void)ws_size;
  const float* x      = (const float*)d_in[0];
  const float* enc_w  = (const float*)d_in[1];
  const float* enc_b  = (const float*)d_in[2];
  const float* log_dt = (const float*)d_in[3];
  const float* Cri    = (const float*)d_in[4];
  const float* lAr    = (const float*)d_in[5];
  const float* Aim    = (const float*)d_in[6];
  const float* Dsk    = (const float*)d_in[7];
  const float* glu_w  = (const float*)d_in[8];
  const float* glu_b  = (const float*)d_in[9];
  const float* ln_g   = (const float*)d_in[10];
  const float* ln_b   = (const float*)d_in[11];
  const float* dec_w  = (const float*)d_in[12];
  const float* dec_b  = (const float*)d_in[13];
  float* out = (float*)d_out;

  unsigned short* h   = (unsigned short*)d_ws;               // 64 MB bf16 (swizzled)
  unsigned short* G   = h + (size_t)B_ * H_ * LSEQ;          // 64 MB bf16
  unsigned short* Wb  = G + (size_t)B_ * H_ * LSEQ;          // 1 MB
  unsigned short* TtG = Wb + 524288;                         // 8 MB
  unsigned short* WinG = TtG + 4194304;                      // 8 MB
  unsigned short* WhiG = WinG + 4194304;                     // 8 MB
  unsigned short* WloG = WhiG + 4194304;                     // 8 MB
  float2* AQG = (float2*)(WloG + 4194304);                   // 256 KB
  float* P    = (float*)(AQG + NL_ * H_ * N2_);              // 32 KB

  k_wconv<<<256, 256, 0, stream>>>(glu_w, Wb);
  k_prep<<<NL_ * H_, 64, 0, stream>>>(log_dt, Cri, lAr, Aim, Dsk,
                                      TtG, WinG, WhiG, WloG, AQG);
  k_encoder<<<B_ * (LSEQ / 32), 256, 0, stream>>>(x, enc_w, enc_b, h);
  for (int i = 0; i < NL_; ++i) {
    k_chunk<<<H_ * B_, 256, 0, stream>>>(h, G, TtG, WinG, WhiG, WloG, AQG, i);
    k_glu<<<B_ * (LSEQ / 64), 512, 77824, stream>>>(Wb, G, h, glu_b, ln_g, ln_b, i);
  }
  k_pool<<<(B_ * H_) / 4, 256, 0, stream>>>(h, P);
  k_dec<<<B_, 64, 0, stream>>>(P, dec_w, dec_b, out);
}

// Round 12
// 786.365 us; speedup vs baseline: 4.6233x; 1.1042x over previous
//
#include <hip/hip_runtime.h>
#include <math.h>

#define B_    32
#define DIN   64
#define LSEQ  4096
#define H_    256
#define N2_   32
#define NL_   4
#define DOUT  2
#define LN_EPSF 1e-5f

typedef __bf16 bf16x8 __attribute__((ext_vector_type(8)));
typedef float  f32x4  __attribute__((ext_vector_type(4)));

__device__ inline unsigned short f2bf(float f) {
  unsigned u = __builtin_bit_cast(unsigned, f);
  u += 0x7FFFu + ((u >> 16) & 1u);
  return (unsigned short)(u >> 16);
}
__device__ inline float bf2f(unsigned short u) {
  return __builtin_bit_cast(float, ((unsigned)u) << 16);
}
__device__ inline void cmul(float& xr, float& xi, float yr, float yi) {
  float t = fmaf(xr, yr, -xi * yi);
  xi = fmaf(xr, yi, xi * yr);
  xr = t;
}

// async 16B global->LDS copy: lds base must be wave-uniform (HW adds lane*16)
__device__ inline void gl_lds16(const void* g, void* l) {
  __builtin_amdgcn_global_load_lds(
      (const __attribute__((address_space(1))) void*)g,
      (__attribute__((address_space(3))) void*)l, 16, 0, 0);
}

// A&S 7.1.26 erf, |err| <= 1.5e-7
__device__ inline float erf_fast(float x) {
  float ax = fabsf(x);
  float t = __builtin_amdgcn_rcpf(fmaf(0.3275911f, ax, 1.f));
  float p = fmaf(1.061405429f, t, -1.453152027f);
  p = fmaf(p, t, 1.421413741f);
  p = fmaf(p, t, -0.284496736f);
  p = fmaf(p, t, 0.254829592f);
  float e = __expf(-ax * ax);
  float r = 1.f - p * t * e;
  return copysignf(r, x);
}

// ZOH discretization params for mode n of (layer, hh)
__device__ inline void mode_params(const float* log_dt, const float* Cri,
                                   const float* lAr, const float* Aim,
                                   int layer, int hh, int n, float dt,
                                   float& dr, float& di, float& ctr, float& cti) {
  int idx = (layer * H_ + hh) * N2_ + n;
  float Are = -expf(lAr[idx]);
  float Aimv = Aim[idx];
  dr = Are * dt; di = Aimv * dt;
  float er = expf(dr), sn, cs;
  sincosf(di, &sn, &cs);
  float arr = er * cs, aii = er * sn;
  float nr = arr - 1.f, ni = aii;
  float inv = 1.f / (Are * Are + Aimv * Aimv);
  float qr = (nr * Are + ni * Aimv) * inv;
  float qi = (ni * Are - nr * Aimv) * inv;
  float Cr = Cri[2 * idx], Ci = Cri[2 * idx + 1];
  ctr = 2.f * (Cr * qr - Ci * qi);
  cti = 2.f * (Cr * qi + Ci * qr);
}

// ---------------------------------------------------------------------------
// k_prep v2: 256 thr/block, one block per (layer,hh). Power-combining replaces
// per-element transcendentals. D-skip folded into Tt diagonal.
// ---------------------------------------------------------------------------
__global__ __launch_bounds__(256) void k_prep(
    const float* __restrict__ log_dt, const float* __restrict__ Cri,
    const float* __restrict__ lAr, const float* __restrict__ Aim,
    const float* __restrict__ Dsk,
    unsigned short* __restrict__ TtG, unsigned short* __restrict__ WinG,
    unsigned short* __restrict__ WhiG, unsigned short* __restrict__ WloG,
    float2* __restrict__ AQG)
{
  int bid = blockIdx.x;
  int layer = bid >> 8, hh = bid & 255;
  int tid = threadIdx.x;
  __shared__ float KfP[4][64];
  __shared__ float Kf[64];
  float dt = expf(log_dt[layer * H_ + hh]);
  float dsk = Dsk[layer * H_ + hh];
  size_t base = (size_t)bid * 4096;

  // ---- Kf[d] = sum_n ctr*Re(a^d) - cti*Im(a^d), 4-way mode split ----
  {
    int d = tid & 63, q = tid >> 6;
    float acc = 0.f;
#pragma unroll
    for (int k = 0; k < 8; ++k) {
      int n = q * 8 + k;
      float dr, di, ctr, cti;
      mode_params(log_dt, Cri, lAr, Aim, layer, hh, n, dt, dr, di, ctr, cti);
      float er = expf(dr * (float)d), sn, cs;
      sincosf(di * (float)d, &sn, &cs);
      acc += ctr * (er * cs) - cti * (er * sn);
    }
    KfP[q][d] = acc;
  }
  // ---- a^64 table ----
  if (tid < N2_) {
    int idx = (layer * H_ + hh) * N2_ + tid;
    float dr64 = -expf(lAr[idx]) * dt * 64.f;
    float di64 = Aim[idx] * dt * 64.f;
    float er = expf(dr64), sn, cs;
    sincosf(di64, &sn, &cs);
    AQG[bid * N2_ + tid] = make_float2(er * cs, er * sn);
  }
  __syncthreads();
  if (tid < 64)
    Kf[tid] = (KfP[0][tid] + KfP[1][tid]) + (KfP[2][tid] + KfP[3][tid]);
  __syncthreads();

  // ---- Tt[i][t] = k[i-t] (+dsk on diag), thread = (i, 16-col group) ----
  {
    int i = tid >> 2, tg = tid & 3;
#pragma unroll
    for (int j = 0; j < 16; ++j) {
      int t = tg * 16 + j;
      float v = (t <= i) ? (Kf[i - t] + ((t == i) ? dsk : 0.f)) : 0.f;
      TtG[base + i * 64 + (((t >> 3) ^ (i & 7)) << 3) + (t & 7)] = f2bf(v);
    }
  }

  // ---- Win[r][t] = Re/Im(a_n^(63-t)), thread = (r, 16-col group) ----
  {
    int r = tid >> 2, tg = tid & 3;
    int n = r >> 1, im = r & 1;
    int idx = (layer * H_ + hh) * N2_ + n;
    float dr = -expf(lAr[idx]) * dt;
    float di = Aim[idx] * dt;
    float er = expf(dr), sn, cs;
    sincosf(di, &sn, &cs);
    float ar = er * cs, ai = er * sn;
    // powers a^16, a^32, a^48
    float a16r = ar, a16i = ai;
    cmul(a16r, a16i, a16r, a16i);   // a^2
    cmul(a16r, a16i, a16r, a16i);   // a^4
    cmul(a16r, a16i, a16r, a16i);   // a^8
    cmul(a16r, a16i, a16r, a16i);   // a^16
    float a32r = a16r, a32i = a16i;
    cmul(a32r, a32i, a16r, a16i);   // a^32
    float a48r = a32r, a48i = a32i;
    cmul(a48r, a48i, a16r, a16i);   // a^48
    float pr, pi;                    // a^(48 - tg*16)
    if (tg == 0)      { pr = a48r; pi = a48i; }
    else if (tg == 1) { pr = a32r; pi = a32i; }
    else if (tg == 2) { pr = a16r; pi = a16i; }
    else              { pr = 1.f;  pi = 0.f;  }
#pragma unroll
    for (int j = 15; j >= 0; --j) {
      int t = tg * 16 + j;          // e = 63 - t, ascending as j descends
      float v = im ? pi : pr;
      WinG[base + r * 64 + (((t >> 3) ^ (r & 7)) << 3) + (t & 7)] = f2bf(v);
      cmul(pr, pi, ar, ai);
    }
  }

  // ---- W[i][r] hi/lo: M = ct_n a_n^(i+1), thread = (r, 16-row group) ----
  {
    int r = tid & 63, ig = tid >> 6;
    int n = r >> 1;
    float dr, di, ctr, cti;
    mode_params(log_dt, Cri, lAr, Aim, layer, hh, n, dt, dr, di, ctr, cti);
    float er = expf(dr), sn, cs;
    sincosf(di, &sn, &cs);
    float ar = er * cs, ai = er * sn;
    float a16r = ar, a16i = ai;
    cmul(a16r, a16i, a16r, a16i);
    cmul(a16r, a16i, a16r, a16i);
    cmul(a16r, a16i, a16r, a16i);
    cmul(a16r, a16i, a16r, a16i);   // a^16
    float a32r = a16r, a32i = a16i;
    cmul(a32r, a32i, a16r, a16i);   // a^32
    float a48r = a32r, a48i = a32i;
    cmul(a48r, a48i, a16r, a16i);   // a^48
    float pr, pi;                    // a^(ig*16)
    if (ig == 0)      { pr = 1.f;  pi = 0.f;  }
    else if (ig == 1) { pr = a16r; pi = a16i; }
    else if (ig == 2) { pr = a32r; pi = a32i; }
    else              { pr = a48r; pi = a48i; }
    cmul(pr, pi, ar, ai);            // a^(ig*16+1)
#pragma unroll
    for (int j = 0; j < 16; ++j) {
      int i = ig * 16 + j;
      float wre = fmaf(ctr, pr, -cti * pi);
      float wim = fmaf(ctr, pi,  cti * pr);
      float v = (r & 1) ? -wim : wre;
      unsigned short hi = f2bf(v);
      float lo = v - bf2f(hi);
      size_t off = base + i * 64 + (((r >> 3) ^ (i & 7)) << 3) + (r & 7);
      WhiG[off] = hi;
      WloG[off] = f2bf(lo);
      cmul(pr, pi, ar, ai);
    }
  }
}

// ---------------------------------------------------------------------------
// k_wconv: glu_w fp32 -> bf16 pre-swizzled (unchanged)
// ---------------------------------------------------------------------------
__global__ __launch_bounds__(256) void k_wconv(
    const float* __restrict__ gw, unsigned short* __restrict__ wb)
{
  int t = blockIdx.x * 256 + threadIdx.x;
  int uu = t & 7;
  int r  = (t >> 3) & 511;
  int l4 = t >> 12;
  int layer = l4 >> 2, kc4 = l4 & 3;
  int ksrc = kc4 * 64 + ((uu ^ (r & 7)) << 3);
  const float* src = gw + ((size_t)(layer * 512 + r)) * H_ + ksrc;
  unsigned short* dst = wb + (size_t)t * 8;
#pragma unroll
  for (int j = 0; j < 8; ++j) dst[j] = f2bf(src[j]);
}

// ---------------------------------------------------------------------------
// Encoder: writes bf16 h PRE-SWIZZLED (chunk-unit xor swizzle in global)
// ---------------------------------------------------------------------------
__global__ __launch_bounds__(256) void k_encoder(
    const float* __restrict__ x, const float* __restrict__ ew,
    const float* __restrict__ eb, unsigned short* __restrict__ h)
{
  __shared__ __align__(16) float Wl[32][256];
  __shared__ __align__(16) float Xl[32][32];
  int tid = threadIdx.x;
  int blk = blockIdx.x;
  int b  = blk >> 7;
  int l0 = (blk & 127) << 5;
  int ty = tid >> 3;
  int tx = tid & 7;
  float acc[8][4];
#pragma unroll
  for (int i = 0; i < 8; ++i)
#pragma unroll
    for (int j = 0; j < 4; ++j) acc[i][j] = 0.f;

  for (int kc = 0; kc < DIN; kc += 32) {
    const float4* ew4 = (const float4*)(ew + kc * H_);
#pragma unroll
    for (int it = 0; it < 8; ++it) {
      int idx = tid + (it << 8);
      ((float4*)&Wl[0][0])[idx] = ew4[idx];
    }
    {
      int c = tid >> 3, p = (tid & 7) << 2;
      *(float4*)&Xl[c][p] =
          *(const float4*)(x + ((size_t)(b * DIN + kc + c)) * LSEQ + l0 + p);
    }
    __syncthreads();
#pragma unroll
    for (int k = 0; k < 32; ++k) {
      float4 w0 = *(float4*)&Wl[k][ty * 8];
      float4 w1 = *(float4*)&Wl[k][ty * 8 + 4];
      float4 xv = *(float4*)&Xl[k][tx * 4];
      float wvv[8] = {w0.x, w0.y, w0.z, w0.w, w1.x, w1.y, w1.z, w1.w};
      float xs[4]  = {xv.x, xv.y, xv.z, xv.w};
#pragma unroll
      for (int i = 0; i < 8; ++i)
#pragma unroll
        for (int j = 0; j < 4; ++j) acc[i][j] = fmaf(wvv[i], xs[j], acc[i][j]);
    }
    __syncthreads();
  }
  // swizzled store: l = l0 + tx*4 (4 elems within one 8-elem unit)
  int l = l0 + tx * 4;
  int cch = l >> 6;
  int uu  = (l & 63) >> 3;
  int j8  = l & 7;
  size_t soff = (cch << 6) + (((uu ^ (cch & 7))) << 3) + j8;
#pragma unroll
  for (int i = 0; i < 8; ++i) {
    int d = ty * 8 + i;
    float bia = eb[d];
    ushort4 o;
    o.x = f2bf(acc[i][0] + bia); o.y = f2bf(acc[i][1] + bia);
    o.z = f2bf(acc[i][2] + bia); o.w = f2bf(acc[i][3] + bia);
    *(ushort4*)(h + ((size_t)(b * H_ + d)) * LSEQ + soff) = o;
  }
}

// ---------------------------------------------------------------------------
// k_chunk v5 (unchanged from round 11)
// ---------------------------------------------------------------------------
__global__ __launch_bounds__(256, 4) void k_chunk(
    const unsigned short* __restrict__ hin, unsigned short* __restrict__ G,
    const unsigned short* __restrict__ TtG, const unsigned short* __restrict__ WinG,
    const unsigned short* __restrict__ WhiG, const unsigned short* __restrict__ WloG,
    const float2* __restrict__ AQG, int layer)
{
  __shared__ __align__(16) char smem[40960];
  char* Ul    = smem;                      // 8KB bf16 [c][t] swz
  char* TtL   = smem + 8192;               // 8KB: Tt -> Whi
  char* WinL  = smem + 16384;              // 8KB: Win -> Wlo
  float* BstT = (float*)(smem + 24576);    // 16KB f32 [r][c^((r&7)<<2)]
  char* ShiL  = smem + 24576;              // 8KB (after scan)
  char* SloL  = smem + 32768;              // 8KB

  int tid = threadIdx.x;
  int w = tid >> 6, lane = tid & 63;
  int rg = lane >> 4, lc = lane & 15;
  int bid = blockIdx.x;
  int hh = bid >> 5, b = bid & 31;
  size_t wbase = ((size_t)(layer * H_ + hh)) * 4096;
  const unsigned short* Urow = hin + ((size_t)(b * H_ + hh)) * LSEQ;

#pragma unroll
  for (int it = 0; it < 2; ++it) {
    int idx = tid + (it << 8);
    int ubase = (w * 64 + (it << 8)) * 16;
    gl_lds16(((const uint4*)Urow) + idx, Ul + ubase);
    gl_lds16(((const uint4*)(TtG + wbase)) + idx, TtL + ubase);
    gl_lds16(((const uint4*)(WinG + wbase)) + idx, WinL + ubase);
  }
  __syncthreads();

  f32x4 accY[4], accB[4];
#pragma unroll
  for (int nb = 0; nb < 4; ++nb) {
    accY[nb] = (f32x4){0.f, 0.f, 0.f, 0.f};
    accB[nb] = (f32x4){0.f, 0.f, 0.f, 0.f};
  }
#pragma unroll
  for (int ks = 0; ks < 2; ++ks) {
    int ca = w * 16 + lc;
    int u = ks * 4 + rg;
    bf16x8 A = *(const bf16x8*)(Ul + ca * 128 + ((u ^ (ca & 7)) << 4));
#pragma unroll
    for (int nb = 0; nb < 4; ++nb) {
      int col = nb * 16 + lc;
      bf16x8 Bt = *(const bf16x8*)(TtL + col * 128 + ((u ^ (col & 7)) << 4));
      bf16x8 Bw = *(const bf16x8*)(WinL + col * 128 + ((u ^ (col & 7)) << 4));
      accY[nb] = __builtin_amdgcn_mfma_f32_16x16x32_bf16(A, Bt, accY[nb], 0, 0, 0);
      accB[nb] = __builtin_amdgcn_mfma_f32_16x16x32_bf16(A, Bw, accB[nb], 0, 0, 0);
    }
  }
#pragma unroll
  for (int nb = 0; nb < 4; ++nb)
#pragma unroll
    for (int reg = 0; reg < 4; ++reg) {
      int r = nb * 16 + lc;
      int cc = w * 16 + rg * 4 + reg;
      BstT[r * 64 + (cc ^ ((r & 7) << 2))] = accB[nb][reg];
    }
  __syncthreads();

#pragma unroll
  for (int it = 0; it < 2; ++it) {
    int idx = tid + (it << 8);
    int ubase = (w * 64 + (it << 8)) * 16;
    gl_lds16(((const uint4*)(WhiG + wbase)) + idx, TtL + ubase);
    gl_lds16(((const uint4*)(WloG + wbase)) + idx, WinL + ubase);
  }

  float Sr[8], Si[8], Mr[8], Mi[8];
  int c = lane;
  {
    const float2* aqb = AQG + (size_t)(layer * H_ + hh) * N2_ + w * 8;
#pragma unroll
    for (int q = 0; q < 8; ++q) {
      float2 aq = aqb[q];
      Mr[q] = aq.x; Mi[q] = aq.y;
      int r0 = (w * 8 + q) * 2, r1 = r0 + 1;
      Sr[q] = BstT[r0 * 64 + (c ^ ((r0 & 7) << 2))];
      Si[q] = BstT[r1 * 64 + (c ^ ((r1 & 7) << 2))];
    }
  }
  __syncthreads();

#pragma unroll
  for (int dd = 0; dd < 6; ++dd) {
    int d = 1 << dd;
#pragma unroll
    for (int q = 0; q < 8; ++q) {
      float pr = __shfl_up(Sr[q], (unsigned)d);
      float pi = __shfl_up(Si[q], (unsigned)d);
      if (lane >= d) {
        Sr[q] = fmaf(Mr[q], pr, fmaf(-Mi[q], pi, Sr[q]));
        Si[q] = fmaf(Mr[q], pi, fmaf(Mi[q], pr, Si[q]));
      }
      if (dd < 5) {
        float t = fmaf(Mr[q], Mr[q], -Mi[q] * Mi[q]);
        Mi[q] = 2.f * Mr[q] * Mi[q];
        Mr[q] = t;
      }
    }
  }
#pragma unroll
  for (int q = 0; q < 8; ++q) {
    float pr = __shfl_up(Sr[q], 1u);
    float pi = __shfl_up(Si[q], 1u);
    Sr[q] = (lane == 0) ? 0.f : pr;
    Si[q] = (lane == 0) ? 0.f : pi;
  }
#pragma unroll
  for (int q = 0; q < 8; ++q) {
    int n = w * 8 + q;
    unsigned short hr = f2bf(Sr[q]), hi_ = f2bf(Si[q]);
    unsigned hiw = (unsigned)hr | ((unsigned)hi_ << 16);
    unsigned low = (unsigned)f2bf(Sr[q] - bf2f(hr)) |
                   ((unsigned)f2bf(Si[q] - bf2f(hi_)) << 16);
    int boff = c * 128 + (((n >> 2) ^ (c & 7)) << 4) + (((2 * n) & 7) << 1);
    *(unsigned*)(ShiL + boff) = hiw;
    *(unsigned*)(SloL + boff) = low;
  }
  __syncthreads();

#pragma unroll
  for (int ks = 0; ks < 2; ++ks) {
    int ca = w * 16 + lc;
    int u = ks * 4 + rg;
    bf16x8 Ah = *(const bf16x8*)(ShiL + ca * 128 + ((u ^ (ca & 7)) << 4));
    bf16x8 Al = *(const bf16x8*)(SloL + ca * 128 + ((u ^ (ca & 7)) << 4));
#pragma unroll
    for (int nb = 0; nb < 4; ++nb) {
      int col = nb * 16 + lc;
      bf16x8 Wh = *(const bf16x8*)(TtL + col * 128 + ((u ^ (col & 7)) << 4));
      bf16x8 Wl2 = *(const bf16x8*)(WinL + col * 128 + ((u ^ (col & 7)) << 4));
      accY[nb] = __builtin_amdgcn_mfma_f32_16x16x32_bf16(Ah, Wh, accY[nb], 0, 0, 0);
      accY[nb] = __builtin_amdgcn_mfma_f32_16x16x32_bf16(Al, Wh, accY[nb], 0, 0, 0);
      accY[nb] = __builtin_amdgcn_mfma_f32_16x16x32_bf16(Ah, Wl2, accY[nb], 0, 0, 0);
    }
  }
  __syncthreads();

  unsigned short* Yl = (unsigned short*)(smem + 24576);
#pragma unroll
  for (int nb = 0; nb < 4; ++nb) {
#pragma unroll
    for (int reg = 0; reg < 4; ++reg) {
      int cc = w * 16 + rg * 4 + reg;
      int i = nb * 16 + lc;
      float yv = accY[nb][reg];
      float ge = 0.5f * yv * (1.f + erf_fast(yv * 0.70710678118f));
      Yl[cc * 64 + i] = f2bf(ge);
    }
  }
  __syncthreads();
  unsigned short* Gr = G + ((size_t)(b * H_ + hh)) * LSEQ;
#pragma unroll
  for (int it = 0; it < 2; ++it) {
    int idx = tid + (it << 8);
    *(uint4*)(Gr + idx * 8) = ((uint4*)Yl)[idx];
  }
}

// ---------------------------------------------------------------------------
// GLU MFMA + residual + LN (unchanged from round 11)
// ---------------------------------------------------------------------------
__global__ __launch_bounds__(512, 4) void k_glu(
    const unsigned short* __restrict__ Wb, const unsigned short* __restrict__ G,
    unsigned short* __restrict__ h, const float* __restrict__ gb,
    const float* __restrict__ lng, const float* __restrict__ lnb, int layer)
{
  extern __shared__ char smem[];
  char* WlB = smem;
  char* GlB = smem + 65536;
  float2* Red = (float2*)(smem + 65536 + 8192);

  int tid = threadIdx.x;
  int w = tid >> 6, lane = tid & 63;
  int b  = blockIdx.x >> 6;
  int l0 = (blockIdx.x & 63) << 6;
  int rgrp = lane >> 4, lc = lane & 15;
  int cch = l0 >> 6, cs7 = cch & 7;

  f32x4 acc[4][4];
#pragma unroll
  for (int m = 0; m < 4; ++m)
#pragma unroll
    for (int n = 0; n < 4; ++n) acc[m][n] = (f32x4){0.f, 0.f, 0.f, 0.f};

  const unsigned short* wsrc = Wb + (size_t)(layer * 4) * 512 * 64;

  for (int kc4 = 0; kc4 < 4; ++kc4) {
    if (kc4) __syncthreads();
    const unsigned short* wc = wsrc + (size_t)kc4 * 512 * 64;
#pragma unroll
    for (int i = 0; i < 8; ++i) {
      int base = w * 8192 + i * 1024;
      gl_lds16((const char*)wc + base + lane * 16, WlB + base);
    }
    {
      int col = lane;
      int kc = kc4 * 64;
      size_t base = (size_t)(b * H_ + kc + w * 8) * LSEQ + l0 + col;
      unsigned v0 = G[base];
      unsigned v1 = G[base + (size_t)1 * LSEQ];
      unsigned v2 = G[base + (size_t)2 * LSEQ];
      unsigned v3 = G[base + (size_t)3 * LSEQ];
      unsigned v4 = G[base + (size_t)4 * LSEQ];
      unsigned v5 = G[base + (size_t)5 * LSEQ];
      unsigned v6 = G[base + (size_t)6 * LSEQ];
      unsigned v7 = G[base + (size_t)7 * LSEQ];
      unsigned pk0 = v0 | (v1 << 16), pk1 = v2 | (v3 << 16);
      unsigned pk2 = v4 | (v5 << 16), pk3 = v6 | (v7 << 16);
      *(uint4*)(GlB + col * 128 + ((w ^ (col & 7)) << 4)) =
          make_uint4(pk0, pk1, pk2, pk3);
    }
    __syncthreads();
#pragma unroll
    for (int ks = 0; ks < 2; ++ks) {
      int u = ks * 4 + rgrp;
      bf16x8 af[4], bff[4];
#pragma unroll
      for (int m = 0; m < 4; ++m) {
        int grow = ((m < 2) ? (w * 32 + m * 16) : (256 + w * 32 + (m - 2) * 16)) + lc;
        af[m] = *(const bf16x8*)(WlB + grow * 128 + ((u ^ (grow & 7)) << 4));
      }
#pragma unroll
      for (int n = 0; n < 4; ++n) {
        int gcol = n * 16 + lc;
        bff[n] = *(const bf16x8*)(GlB + gcol * 128 + ((u ^ (gcol & 7)) << 4));
      }
#pragma unroll
      for (int m = 0; m < 4; ++m)
#pragma unroll
        for (int n = 0; n < 4; ++n)
          acc[m][n] = __builtin_amdgcn_mfma_f32_16x16x32_bf16(
              af[m], bff[n], acc[m][n], 0, 0, 0);
    }
  }

  int colS[4];
#pragma unroll
  for (int n = 0; n < 4; ++n) {
    int col = n * 16 + lc;
    colS[n] = ((((col >> 3) ^ cs7)) << 3) | (col & 7);
  }

  const float* gbL = gb + layer * 2 * H_;
  float out[2][4][4];
  float s[4], ss[4];
#pragma unroll
  for (int n = 0; n < 4; ++n) { s[n] = 0.f; ss[n] = 0.f; }
#pragma unroll
  for (int mA = 0; mA < 2; ++mA) {
#pragma unroll
    for (int reg = 0; reg < 4; ++reg) {
      int ch = w * 32 + mA * 16 + rgrp * 4 + reg;
      float ba = gbL[ch], bg = gbL[ch + H_];
#pragma unroll
      for (int n = 0; n < 4; ++n) {
        size_t off = (size_t)(b * H_ + ch) * LSEQ + l0 + colS[n];
        float a = acc[mA][n][reg] + ba;
        float gv = acc[mA + 2][n][reg] + bg;
        float sg = __builtin_amdgcn_rcpf(1.f + __expf(-gv));
        float o = fmaf(a, sg, bf2f(h[off]));
        out[mA][n][reg] = o;
        s[n] += o; ss[n] = fmaf(o, o, ss[n]);
      }
    }
  }
#pragma unroll
  for (int n = 0; n < 4; ++n) {
    s[n]  += __shfl_xor(s[n], 16);  s[n]  += __shfl_xor(s[n], 32);
    ss[n] += __shfl_xor(ss[n], 16); ss[n] += __shfl_xor(ss[n], 32);
  }
  if (lane < 16) {
#pragma unroll
    for (int n = 0; n < 4; ++n)
      Red[w * 64 + n * 16 + lane] = make_float2(s[n], ss[n]);
  }
  __syncthreads();
  float mu[4], rs[4];
#pragma unroll
  for (int n = 0; n < 4; ++n) {
    int col = n * 16 + lc;
    float ts = 0.f, tss = 0.f;
#pragma unroll
    for (int ww = 0; ww < 8; ++ww) {
      float2 v = Red[ww * 64 + col];
      ts += v.x; tss += v.y;
    }
    mu[n] = ts * (1.f / H_);
    rs[n] = rsqrtf(tss * (1.f / H_) - mu[n] * mu[n] + LN_EPSF);
  }
#pragma unroll
  for (int mA = 0; mA < 2; ++mA) {
#pragma unroll
    for (int reg = 0; reg < 4; ++reg) {
      int ch = w * 32 + mA * 16 + rgrp * 4 + reg;
      float lg = lng[layer * H_ + ch], lb = lnb[layer * H_ + ch];
#pragma unroll
      for (int n = 0; n < 4; ++n) {
        size_t off = (size_t)(b * H_ + ch) * LSEQ + l0 + colS[n];
        h[off] = f2bf((out[mA][n][reg] - mu[n]) * rs[n] * lg + lb);
      }
    }
  }
}

// ---------------------------------------------------------------------------
// k_pool: mean over L per (b,h) row (bf16, order-invariant vs swizzle)
// ---------------------------------------------------------------------------
__global__ __launch_bounds__(256) void k_pool(
    const unsigned short* __restrict__ h, float* __restrict__ P)
{
  int row = blockIdx.x * 4 + (threadIdx.x >> 6);
  int lane = threadIdx.x & 63;
  const uint4* src = (const uint4*)(h + (size_t)row * LSEQ);
  float s = 0.f;
#pragma unroll
  for (int i = 0; i < 8; ++i) {
    uint4 v = src[lane + i * 64];
    unsigned ws[4] = {v.x, v.y, v.z, v.w};
#pragma unroll
    for (int j = 0; j < 4; ++j) {
      s += bf2f((unsigned short)(ws[j] & 0xFFFFu));
      s += bf2f((unsigned short)(ws[j] >> 16));
    }
  }
#pragma unroll
  for (int d = 1; d < 64; d <<= 1) s += __shfl_xor(s, d);
  if (lane == 0) P[row] = s * (1.f / LSEQ);
}

// ---------------------------------------------------------------------------
// k_dec: decode (256->2) + softmax. grid B, block 64.
// ---------------------------------------------------------------------------
__global__ __launch_bounds__(64) void k_dec(
    const float* __restrict__ P, const float* __restrict__ dw,
    const float* __restrict__ db, float* __restrict__ out)
{
  int b = blockIdx.x, lane = threadIdx.x;
  float z0 = 0.f, z1 = 0.f;
#pragma unroll
  for (int i = 0; i < 4; ++i) {
    int k = lane + i * 64;
    float p = P[b * H_ + k];
    z0 = fmaf(p, dw[k * DOUT + 0], z0);
    z1 = fmaf(p, dw[k * DOUT + 1], z1);
  }
#pragma unroll
  for (int d = 1; d < 64; d <<= 1) {
    z0 += __shfl_xor(z0, d);
    z1 += __shfl_xor(z1, d);
  }
  if (lane == 0) {
    z0 += db[0]; z1 += db[1];
    float m = fmaxf(z0, z1);
    float e0 = expf(z0 - m), e1 = expf(z1 - m);
    float inv = 1.f / (e0 + e1);
    out[b * 2 + 0] = e0 * inv;
    out[b * 2 + 1] = e1 * inv;
  }
}

// ---------------------------------------------------------------------------
extern "C" void kernel_launch(void* const* d_in, const int* in_sizes, int n_in,
                              void* d_out, int out_size, void* d_ws, size_t ws_size,
                              hipStream_t stream) {
  (void)in_sizes; (void)n_in; (void)out_size; (void)ws_size;
  const float* x      = (const float*)d_in[0];
  const float* enc_w  = (const float*)d_in[1];
  const float* enc_b  = (const float*)d_in[2];
  const float* log_dt = (const float*)d_in[3];
  const float* Cri    = (const float*)d_in[4];
  const float* lAr    = (const float*)d_in[5];
  const float* Aim    = (const float*)d_in[6];
  const float* Dsk    = (const float*)d_in[7];
  const float* glu_w  = (const float*)d_in[8];
  const float* glu_b  = (const float*)d_in[9];
  const float* ln_g   = (const float*)d_in[10];
  const float* ln_b   = (const float*)d_in[11];
  const float* dec_w  = (const float*)d_in[12];
  const float* dec_b  = (const float*)d_in[13];
  float* out = (float*)d_out;

  unsigned short* h   = (unsigned short*)d_ws;               // 64 MB bf16 (swizzled)
  unsigned short* G   = h + (size_t)B_ * H_ * LSEQ;          // 64 MB bf16
  unsigned short* Wb  = G + (size_t)B_ * H_ * LSEQ;          // 1 MB
  unsigned short* TtG = Wb + 524288;                         // 8 MB
  unsigned short* WinG = TtG + 4194304;                      // 8 MB
  unsigned short* WhiG = WinG + 4194304;                     // 8 MB
  unsigned short* WloG = WhiG + 4194304;                     // 8 MB
  float2* AQG = (float2*)(WloG + 4194304);                   // 256 KB
  float* P    = (float*)(AQG + NL_ * H_ * N2_);              // 32 KB

  k_wconv<<<256, 256, 0, stream>>>(glu_w, Wb);
  k_prep<<<NL_ * H_, 256, 0, stream>>>(log_dt, Cri, lAr, Aim, Dsk,
                                       TtG, WinG, WhiG, WloG, AQG);
  k_encoder<<<B_ * (LSEQ / 32), 256, 0, stream>>>(x, enc_w, enc_b, h);
  for (int i = 0; i < NL_; ++i) {
    k_chunk<<<H_ * B_, 256, 0, stream>>>(h, G, TtG, WinG, WhiG, WloG, AQG, i);
    k_glu<<<B_ * (LSEQ / 64), 512, 77824, stream>>>(Wb, G, h, glu_b, ln_g, ln_b, i);
  }
  k_pool<<<(B_ * H_) / 4, 256, 0, stream>>>(h, P);
  k_dec<<<B_, 64, 0, stream>>>(P, dec_w, dec_b, out);
}